// Round 11
// baseline (483.140 us; speedup 1.0000x reference)
//
#include <hip/hip_runtime.h>
#include <cmath>

// ---------------------------------------------------------------------------
// TimestepVisionTransformer — Round 19: conv_final via LDS staging + fdot2.
//   - k_conv_final3: stage 4x112x12 f16 strip in LDS once (coalesced),
//     taps read from LDS; 12-ch dot = 6x v_dot2_f32_f16 (no cvt, half the
//     MAC insts). Weights packed f16 [p][tap][ci] by k_wcvt4.
//   - replaces k_conv_final2 (47us: 27 scattered loads + 108 cvt + 192 FMA
//     per thread, VALU+latency bound).
// Everything else = r18 (verified, 464.7us).
// B=128, IMG=224, P=16, C_IN=1, E=96, H=4, d=24, NAX=14, N=196, M=B*N=25088
// ---------------------------------------------------------------------------

#define B_   128
#define NPATCH 196
#define M_ROWS (B_*NPATCH)     // 25088
#define E_   96

typedef _Float16 half8 __attribute__((ext_vector_type(8)));
typedef _Float16 half4v __attribute__((ext_vector_type(4)));
typedef _Float16 half2v __attribute__((ext_vector_type(2)));
typedef float f32x4 __attribute__((ext_vector_type(4)));

// ---------------------------------------------------------------------------
// time embedding
// ---------------------------------------------------------------------------
__global__ void k_time(const float* __restrict__ ts,
                       const float* __restrict__ Wt1, const float* __restrict__ bt1,
                       const float* __restrict__ Wt2, const float* __restrict__ bt2,
                       float* __restrict__ timev)
{
    __shared__ float h[128];
    float e = 0.69314718055994530942f * ts[0];
    float sv = sinf(e), cv = cosf(e);
    int t = threadIdx.x;
    float z = sv * Wt1[t] + cv * Wt1[128 + t] + bt1[t];
    h[t] = z / (1.f + expf(-z));
    __syncthreads();
    if (t < 96) {
        float acc = bt2[t];
        for (int j = 0; j < 128; ++j) acc += h[j] * Wt2[j * 96 + t];
        timev[t] = acc;
    }
}

// ---------------------------------------------------------------------------
// zero LN partial-stat table (21504 floats)
// ---------------------------------------------------------------------------
__global__ void __launch_bounds__(256) k_zstat(float* __restrict__ stat)
{
    int i = blockIdx.x * 256 + threadIdx.x;
    if (i < 21504) stat[i] = 0.f;
}

// ---------------------------------------------------------------------------
// weight repack (fp32 per-parity taps). L4 slice [96768,96960) feeds k_wcvt4;
// other slices overwritten by f16 packs.
// ---------------------------------------------------------------------------
__global__ void __launch_bounds__(256) k_repack(const float* __restrict__ w1,
                                                const float* __restrict__ w2,
                                                const float* __restrict__ w3,
                                                const float* __restrict__ w4f,
                                                float* __restrict__ wr)
{
    int i = blockIdx.x * 256 + threadIdx.x;
    const float* src; int CIN, COUT, e; float* dst;
    if      (i < 73728) { src = w1;  CIN = 96; COUT = 48; e = i;          dst = wr; }
    else if (i < 92160) { src = w2;  CIN = 48; COUT = 24; e = i - 73728;  dst = wr + 73728; }
    else if (i < 96768) { src = w3;  CIN = 24; COUT = 12; e = i - 92160;  dst = wr + 92160; }
    else if (i < 96960) { src = w4f; CIN = 12; COUT = 1;  e = i - 96768;  dst = wr + 96768; }
    else return;
    int per = CIN * COUT * 4;
    int par = e / per, rem = e % per;
    int ci = rem / (COUT * 4);
    int o  = (rem >> 2) % COUT;
    int j  = rem & 3;
    int ry = par >> 1, rx = par & 1;
    int wy = (j < 2)  ? (3 - ry) : (1 - ry);
    int wx = (j & 1)  ? (1 - rx) : (3 - rx);
    dst[e] = src[(ci * COUT + o) * 16 + wy * 4 + wx];
}

// ---------------------------------------------------------------------------
// conv_final weights -> f16 wcf[p][j][ci] (192 halves) from fp32 [p][ci][j]
// ---------------------------------------------------------------------------
__global__ void k_wcvt4(const float* __restrict__ wr4,
                        _Float16* __restrict__ wcf)
{
    int i = threadIdx.x;
    if (i >= 192) return;
    int p = i / 48, rem = i % 48;
    int j = rem / 12, ci = rem % 12;
    wcf[(p * 4 + j) * 12 + ci] = (_Float16)wr4[p * 48 + ci * 4 + j];
}

// ---------------------------------------------------------------------------
// conv1 weights -> f16 B-layout Wc[p][o][k=tap*96+ci]
// ---------------------------------------------------------------------------
__global__ void __launch_bounds__(256) k_wcvtc(const float* __restrict__ w1,
                                               _Float16* __restrict__ wc)
{
    int i = blockIdx.x * 256 + threadIdx.x;
    if (i >= 4 * 48 * 384) return;
    int p = i / 18432, rem = i % 18432;
    int o = rem / 384, k = rem % 384;
    int tap = k / 96, ci = k % 96;
    int ry = p >> 1, rx = p & 1;
    int wy = (tap < 2) ? (3 - ry) : (1 - ry);
    int wx = (tap & 1) ? (1 - rx) : (3 - rx);
    wc[i] = (_Float16)w1[(ci * 48 + o) * 16 + wy * 4 + wx];
}

// ---------------------------------------------------------------------------
// conv2 weights -> f16 B-layout Wc2[p][o(32, o>=24 zero)][k=tap*48+ci]
// ---------------------------------------------------------------------------
__global__ void __launch_bounds__(256) k_wcvt2(const float* __restrict__ w2,
                                               _Float16* __restrict__ wc2)
{
    int i = blockIdx.x * 256 + threadIdx.x;
    if (i >= 4 * 32 * 192) return;
    int p = i / 6144, rem = i % 6144;
    int o = rem / 192, k = rem % 192;
    int tap = k / 48, ci = k % 48;
    int ry = p >> 1, rx = p & 1;
    int wy = (tap < 2) ? (3 - ry) : (1 - ry);
    int wx = (tap & 1) ? (1 - rx) : (3 - rx);
    wc2[i] = (o < 24) ? (_Float16)w2[(ci * 24 + o) * 16 + wy * 4 + wx]
                      : (_Float16)0.f;
}

// ---------------------------------------------------------------------------
// conv3 weights -> f16 B-layout Wc3[p][o(16, o>=12 zero)][k=tap*24+ci]
// ---------------------------------------------------------------------------
__global__ void __launch_bounds__(256) k_wcvt3(const float* __restrict__ w3,
                                               _Float16* __restrict__ wc3)
{
    int i = blockIdx.x * 256 + threadIdx.x;
    if (i >= 4 * 16 * 96) return;
    int p = i / 1536, rem = i % 1536;
    int o = rem / 96, k = rem % 96;
    int tap = k / 24, ci = k % 24;
    int ry = p >> 1, rx = p & 1;
    int wy = (tap < 2) ? (3 - ry) : (1 - ry);
    int wx = (tap & 1) ? (1 - rx) : (3 - rx);
    wc3[i] = (o < 12) ? (_Float16)w3[(ci * 12 + o) * 16 + wy * 4 + wx]
                      : (_Float16)0.f;
}

// ---------------------------------------------------------------------------
// transformer weight convert+transpose to half: Wt[n][k] = W[k][n]
// ---------------------------------------------------------------------------
__global__ void __launch_bounds__(256) k_wcvt(const float* __restrict__ qkv0,
                                              const float* __restrict__ qkv1,
                                              const float* __restrict__ wo0,
                                              const float* __restrict__ wo1,
                                              const float* __restrict__ wm0,
                                              const float* __restrict__ wm1,
                                              const float* __restrict__ wm2,
                                              _Float16* __restrict__ wh)
{
    int i = blockIdx.x * 256 + threadIdx.x;
    const float* src; int N; int e;
    if      (i < 27648)  { src = qkv0; N = 288; e = i; }
    else if (i < 55296)  { src = qkv1; N = 288; e = i - 27648; }
    else if (i < 64512)  { src = wo0;  N = 96;  e = i - 55296; }
    else if (i < 73728)  { src = wo1;  N = 96;  e = i - 64512; }
    else if (i < 82944)  { src = wm0;  N = 96;  e = i - 73728; }
    else if (i < 92160)  { src = wm1;  N = 96;  e = i - 82944; }
    else if (i < 101376) { src = wm2;  N = 96;  e = i - 92160; }
    else return;
    int n = e / 96, k = e % 96;
    wh[i] = (_Float16)src[k * N + n];
}

// ---------------------------------------------------------------------------
// zero the borders of xinh NHWC f16 [b][16][16][96]
// ---------------------------------------------------------------------------
__global__ void __launch_bounds__(256) k_zb_h(_Float16* __restrict__ xinh)
{
    int i = blockIdx.x * 256 + threadIdx.x;
    if (i >= 128 * 60 * 96) return;
    int b = i / 5760, r = i % 5760;
    int pos = r / 96, ch = r % 96;
    int py, px;
    if      (pos < 16) { py = 0;        px = pos; }
    else if (pos < 32) { py = 15;       px = pos - 16; }
    else if (pos < 46) { py = pos - 31; px = 0; }
    else               { py = pos - 45; px = 15; }
    xinh[((size_t)(b * 256) + py * 16 + px) * 96 + ch] = (_Float16)0.f;
}

// ---------------------------------------------------------------------------
// patch embed GEMM via f16 MFMA (r16 lean version, verified)
// ---------------------------------------------------------------------------
__global__ void __launch_bounds__(256) k_patch_mfma(const float* __restrict__ x,
                                                    const float* __restrict__ Wp,
                                                    const float* __restrict__ bp,
                                                    float* __restrict__ out)
{
    __shared__ __align__(16) _Float16 Ah[64 * 136];
    __shared__ __align__(16) _Float16 Wh[96 * 136];
    int t = threadIdx.x;
    int p0 = blockIdx.x * 64;
    int wave = t >> 6, lane = t & 63;
    int lm = lane & 15, quad = lane >> 4;
    f32x4 acc[6];
    #pragma unroll
    for (int nt = 0; nt < 6; ++nt) acc[nt] = (f32x4){0.f, 0.f, 0.f, 0.f};

    for (int kc = 0; kc < 2; ++kc) {
        __syncthreads();
        for (int i = t; i < 512; i += 256) {
            int lp = i >> 3, pyl = i & 7;
            int patch = p0 + lp;
            int b = patch / NPATCH, n = patch % NPATCH;
            int ny = n / 14, nx = n % 14;
            const float4* s4 = (const float4*)(x +
                ((size_t)(b * 224) + ny * 16 + kc * 8 + pyl) * 224 + nx * 16);
            float4 v0 = s4[0], v1 = s4[1], v2 = s4[2], v3 = s4[3];
            half8 h0, h1;
            h0[0]=(_Float16)v0.x; h0[1]=(_Float16)v0.y; h0[2]=(_Float16)v0.z; h0[3]=(_Float16)v0.w;
            h0[4]=(_Float16)v1.x; h0[5]=(_Float16)v1.y; h0[6]=(_Float16)v1.z; h0[7]=(_Float16)v1.w;
            h1[0]=(_Float16)v2.x; h1[1]=(_Float16)v2.y; h1[2]=(_Float16)v2.z; h1[3]=(_Float16)v2.w;
            h1[4]=(_Float16)v3.x; h1[5]=(_Float16)v3.y; h1[6]=(_Float16)v3.z; h1[7]=(_Float16)v3.w;
            *(half8*)&Ah[lp * 136 + pyl * 16]     = h0;
            *(half8*)&Ah[lp * 136 + pyl * 16 + 8] = h1;
        }
        for (int i = t; i < 1536; i += 256) {
            int e = i >> 4, s = i & 15;
            const float4* s4 = (const float4*)(Wp + e * 256 + kc * 128 + s * 8);
            float4 v0 = s4[0], v1 = s4[1];
            half8 h0;
            h0[0]=(_Float16)v0.x; h0[1]=(_Float16)v0.y; h0[2]=(_Float16)v0.z; h0[3]=(_Float16)v0.w;
            h0[4]=(_Float16)v1.x; h0[5]=(_Float16)v1.y; h0[6]=(_Float16)v1.z; h0[7]=(_Float16)v1.w;
            *(half8*)&Wh[e * 136 + s * 8] = h0;
        }
        __syncthreads();
        half8 af[4];
        #pragma unroll
        for (int ks = 0; ks < 4; ++ks)
            af[ks] = *(const half8*)&Ah[(wave * 16 + lm) * 136 + ks * 32 + quad * 8];
        #pragma unroll
        for (int ks = 0; ks < 4; ++ks) {
            #pragma unroll
            for (int nt = 0; nt < 6; ++nt) {
                half8 bf = *(const half8*)&Wh[(nt * 16 + lm) * 136 + ks * 32 + quad * 8];
                acc[nt] = __builtin_amdgcn_mfma_f32_16x16x32_f16(af[ks], bf, acc[nt], 0, 0, 0);
            }
        }
    }

    #pragma unroll
    for (int nt = 0; nt < 6; ++nt) {
        #pragma unroll
        for (int r = 0; r < 4; ++r) {
            int e = nt * 16 + lm;
            int lp = wave * 16 + quad * 4 + r;
            int patch = p0 + lp;
            int n = patch % NPATCH;
            int ny = n / 14, nx = n % 14;
            float yx = (float)(ny + nx);
            float v = acc[nt][r] + bp[e];
            float other = __shfl_xor(v, 1);
            float fi = (float)(e >> 1);
            float theta = expf(fi * (-2.f / 96.f) * 9.210340371976184f);
            float ang = theta * yx;
            float c = cosf(ang), s = sinf(ang);
            float outv = (lm & 1) ? (other * s + v * c) : (v * c - other * s);
            out[(size_t)patch * 96 + e] = outv;
        }
    }
}

// ---------------------------------------------------------------------------
// row LayerNorm over 96, wave per row — writes f16.
// ---------------------------------------------------------------------------
__global__ void __launch_bounds__(256) k_ln_row(const float* __restrict__ x,
                                                const float* __restrict__ g,
                                                const float* __restrict__ bv,
                                                _Float16* __restrict__ out, int M)
{
    int lane = threadIdx.x & 63;
    int gw = (blockIdx.x * 256 + threadIdx.x) >> 6;
    int nw = (gridDim.x * 256) >> 6;
    float g0 = g[lane], b0 = bv[lane];
    float g1 = 0.f, b1 = 0.f;
    if (lane < 32) { g1 = g[64 + lane]; b1 = bv[64 + lane]; }
    for (int r = gw; r < M; r += nw) {
        const float* xr = x + (size_t)r * 96;
        float a = xr[lane];
        float c = (lane < 32) ? xr[64 + lane] : 0.f;
        float s = a + c, q = a * a + c * c;
        #pragma unroll
        for (int off = 32; off; off >>= 1) {
            s += __shfl_xor(s, off);
            q += __shfl_xor(q, off);
        }
        float mu = s * (1.f / 96.f);
        float rstd = rsqrtf(q * (1.f / 96.f) - mu * mu + 1e-5f);
        _Float16* orow = out + (size_t)r * 96;
        orow[lane] = (_Float16)((a - mu) * rstd * g0 + b0);
        if (lane < 32) orow[64 + lane] = (_Float16)((c - mu) * rstd * g1 + b1);
    }
}

// ---------------------------------------------------------------------------
// MFMA row GEMM (r16, verified). AHALF: A f16. OUTMODE: 0=fp32, 1=f16.
// Chunks over blockIdx.y.
// ---------------------------------------------------------------------------
template<int NCHUNKS, int OUTMODE, bool SILU, bool RES, bool ADDTIME, bool AHALF>
__global__ void __launch_bounds__(256) k_gemm_mfma(const void* __restrict__ A,
                                                   const _Float16* __restrict__ Wt,
                                                   const float* __restrict__ bias,
                                                   const float* __restrict__ res,
                                                   const float* __restrict__ timev,
                                                   void* __restrict__ outp)
{
    __shared__ __align__(16) _Float16 Ah[64 * 96];
    __shared__ __align__(16) _Float16 Wh[96 * 96];
    constexpr int NTOT = NCHUNKS * 96;
    int t = threadIdx.x;
    size_t row0 = (size_t)blockIdx.x * 64;

    if constexpr (AHALF) {
        const uint4* a4 = (const uint4*)((const _Float16*)A + row0 * 96);
        uint4* dst = (uint4*)Ah;
        for (int i = t; i < 768; i += 256) dst[i] = a4[i];
    } else {
        const float4* a4 = (const float4*)((const float*)A + row0 * 96);
        for (int i = t; i < 1536; i += 256) {
            float4 v = a4[i];
            half4v hv;
            hv[0] = (_Float16)v.x; hv[1] = (_Float16)v.y;
            hv[2] = (_Float16)v.z; hv[3] = (_Float16)v.w;
            *(half4v*)&Ah[i * 4] = hv;
        }
    }

    int wave = t >> 6, lane = t & 63;
    int lm = lane & 15, quad = lane >> 4;
    const f32x4 vzero = {0.f, 0.f, 0.f, 0.f};

    for (int ch = blockIdx.y; ch < NCHUNKS; ch += gridDim.y) {
        __syncthreads();
        {
            const uint4* src = (const uint4*)(Wt + (size_t)ch * 9216);
            uint4* dst = (uint4*)Wh;
            for (int i = t; i < 1152; i += 256) dst[i] = src[i];
        }
        __syncthreads();

        half8 af[3];
        #pragma unroll
        for (int ks = 0; ks < 3; ++ks)
            af[ks] = *(const half8*)&Ah[(wave * 16 + lm) * 96 + ks * 32 + quad * 8];

        f32x4 acc[6];
        #pragma unroll
        for (int ct = 0; ct < 6; ++ct) acc[ct] = vzero;

        #pragma unroll
        for (int ct = 0; ct < 6; ++ct) {
            #pragma unroll
            for (int ks = 0; ks < 3; ++ks) {
                half8 bf = *(const half8*)&Wh[(ct * 16 + lm) * 96 + ks * 32 + quad * 8];
                acc[ct] = __builtin_amdgcn_mfma_f32_16x16x32_f16(af[ks], bf, acc[ct], 0, 0, 0);
            }
        }

        #pragma unroll
        for (int ct = 0; ct < 6; ++ct) {
            #pragma unroll
            for (int r = 0; r < 4; ++r) {
                int lr = wave * 16 + quad * 4 + r;
                size_t row = row0 + lr;
                int lc = ct * 16 + lm;
                int col = ch * 96 + lc;
                float v = acc[ct][r] + bias[col];
                if constexpr (RES)     v += res[row * 96 + lc];
                if constexpr (ADDTIME) v += timev[lc];
                if constexpr (SILU)    v = v / (1.f + __expf(-v));
                if constexpr (OUTMODE == 0) {
                    ((float*)outp)[row * NTOT + col] = v;
                } else {
                    ((_Float16*)outp)[row * NTOT + col] = (_Float16)v;
                }
            }
        }
    }
}

// ---------------------------------------------------------------------------
// fused MLP (f16 input): 3 chained 96x96 GEMMs + silu, one kernel.
// ---------------------------------------------------------------------------
__global__ void __launch_bounds__(256) k_mlp_fused(const _Float16* __restrict__ A,
                                                   const _Float16* __restrict__ W,
                                                   const float* __restrict__ b0,
                                                   const float* __restrict__ b1,
                                                   const float* __restrict__ b2,
                                                   _Float16* __restrict__ outh)
{
    __shared__ __align__(16) _Float16 Ah[2][64 * 96];
    __shared__ __align__(16) _Float16 Wh[3][96 * 96];
    int t = threadIdx.x;
    size_t row0 = (size_t)blockIdx.x * 64;

    {
        const uint4* a4 = (const uint4*)(A + row0 * 96);
        uint4* dst = (uint4*)&Ah[0][0];
        for (int i = t; i < 768; i += 256) dst[i] = a4[i];
    }
    {
        const uint4* src = (const uint4*)W;
        uint4* dst = (uint4*)&Wh[0][0];
        for (int i = t; i < 3456; i += 256) dst[i] = src[i];
    }

    int wave = t >> 6, lane = t & 63;
    int lm = lane & 15, quad = lane >> 4;
    const float* biases[3] = { b0, b1, b2 };
    int cur = 0;

    #pragma unroll
    for (int s = 0; s < 3; ++s) {
        __syncthreads();
        half8 af[3];
        #pragma unroll
        for (int ks = 0; ks < 3; ++ks)
            af[ks] = *(const half8*)&Ah[cur][(wave * 16 + lm) * 96 + ks * 32 + quad * 8];

        f32x4 acc[6];
        #pragma unroll
        for (int ct = 0; ct < 6; ++ct) acc[ct] = (f32x4){0.f, 0.f, 0.f, 0.f};

        #pragma unroll
        for (int ct = 0; ct < 6; ++ct) {
            #pragma unroll
            for (int ks = 0; ks < 3; ++ks) {
                half8 bf = *(const half8*)&Wh[s][(ct * 16 + lm) * 96 + ks * 32 + quad * 8];
                acc[ct] = __builtin_amdgcn_mfma_f32_16x16x32_f16(af[ks], bf, acc[ct], 0, 0, 0);
            }
        }

        const float* bias = biases[s];
        if (s < 2) {
            #pragma unroll
            for (int ct = 0; ct < 6; ++ct) {
                #pragma unroll
                for (int r = 0; r < 4; ++r) {
                    int lr = wave * 16 + quad * 4 + r;
                    int lc = ct * 16 + lm;
                    float v = acc[ct][r] + bias[lc];
                    v = v / (1.f + __expf(-v));
                    Ah[cur ^ 1][lr * 96 + lc] = (_Float16)v;
                }
            }
            cur ^= 1;
        } else {
            #pragma unroll
            for (int ct = 0; ct < 6; ++ct) {
                #pragma unroll
                for (int r = 0; r < 4; ++r) {
                    int lr = wave * 16 + quad * 4 + r;
                    size_t row = row0 + lr;
                    int lc = ct * 16 + lm;
                    float v = acc[ct][r] + bias[lc];
                    v = v / (1.f + __expf(-v));
                    size_t b = row / NPATCH; int n = (int)(row % NPATCH);
                    int ny = n / 14, nx = n % 14;
                    outh[((b * 256) + (1 + ny) * 16 + (1 + nx)) * 96 + lc] = (_Float16)v;
                }
            }
        }
    }
}

// ---------------------------------------------------------------------------
// MFMA attention (r11 structure): qkv input f16, output f16.
// ---------------------------------------------------------------------------
__global__ void __launch_bounds__(256) k_attn_mfma(const _Float16* __restrict__ qkv,
                                                   _Float16* __restrict__ o)
{
    __shared__ __align__(16) _Float16 Qs[208 * 40];
    __shared__ __align__(16) _Float16 Ks[208 * 40];
    __shared__ __align__(16) _Float16 Vt[32 * 232];
    __shared__ __align__(16) _Float16 Pw[4][16 * 232];

    int t = threadIdx.x;
    int bh = blockIdx.x;
    int b = bh >> 2, h = bh & 3;
    const _Float16* base = qkv + (size_t)b * NPATCH * 288 + h * 24;

    {
        const int4 z = {0, 0, 0, 0};
        int4* q4 = (int4*)Qs; int4* k4 = (int4*)Ks;
        for (int i = t; i < 1040; i += 256) { q4[i] = z; k4[i] = z; }
        int4* v4 = (int4*)Vt;
        for (int i = t; i < 928; i += 256) v4[i] = z;
        int4* p4 = (int4*)&Pw[0][0];
        for (int i = t; i < 1856; i += 256) p4[i] = z;
    }
    __syncthreads();

    for (int i = t; i < NPATCH * 24; i += 256) {
        int r = i / 24, d = i % 24;
        const _Float16* row = base + (size_t)r * 288;
        Qs[r * 40 + d]   = row[d];
        Ks[r * 40 + d]   = row[96 + d];
        Vt[d * 232 + r]  = row[192 + d];
    }
    __syncthreads();

    int wave = t >> 6, lane = t & 63;
    int lm = lane & 15, quad = lane >> 4;
    const float scale = 0.2041241452319315f;

    half8 bk[13];
    #pragma unroll
    for (int ct = 0; ct < 13; ++ct)
        bk[ct] = *(const half8*)&Ks[(ct * 16 + lm) * 40 + quad * 8];

    _Float16* pw = &Pw[wave][0];

    for (int rt = wave; rt < 13; rt += 4) {
        half8 aq = *(const half8*)&Qs[(rt * 16 + lm) * 40 + quad * 8];
        float rsum[4] = {0.f, 0.f, 0.f, 0.f};

        #pragma unroll
        for (int ct = 0; ct < 13; ++ct) {
            f32x4 s = (f32x4){0.f, 0.f, 0.f, 0.f};
            s = __builtin_amdgcn_mfma_f32_16x16x32_f16(aq, bk[ct], s, 0, 0, 0);
            #pragma unroll
            for (int r = 0; r < 4; ++r) {
                float p = __expf(fminf(s[r] * scale, 60.f));
                if (ct == 12 && lm >= 4) p = 0.f;   // keys 196..207 invalid
                rsum[r] += p;
                pw[(quad * 4 + r) * 232 + ct * 16 + lm] = (_Float16)p;
            }
        }

        #pragma unroll
        for (int r = 0; r < 4; ++r) {
            float s = rsum[r];
            s += __shfl_xor(s, 1);
            s += __shfl_xor(s, 2);
            s += __shfl_xor(s, 4);
            s += __shfl_xor(s, 8);
            rsum[r] = 1.f / s;
        }

        f32x4 ov0 = (f32x4){0.f, 0.f, 0.f, 0.f};
        f32x4 ov1 = (f32x4){0.f, 0.f, 0.f, 0.f};
        #pragma unroll
        for (int ks = 0; ks < 7; ++ks) {
            half8 ap = *(const half8*)&pw[lm * 232 + ks * 32 + quad * 8];
            half8 bv0 = *(const half8*)&Vt[(lm) * 232 + ks * 32 + quad * 8];
            half8 bv1 = *(const half8*)&Vt[(16 + lm) * 232 + ks * 32 + quad * 8];
            ov0 = __builtin_amdgcn_mfma_f32_16x16x32_f16(ap, bv0, ov0, 0, 0, 0);
            ov1 = __builtin_amdgcn_mfma_f32_16x16x32_f16(ap, bv1, ov1, 0, 0, 0);
        }

        #pragma unroll
        for (int r = 0; r < 4; ++r) {
            int row = rt * 16 + quad * 4 + r;
            if (row < NPATCH) {
                _Float16* orow = o + ((size_t)b * NPATCH + row) * 96 + h * 24;
                orow[lm] = (_Float16)(ov0[r] * rsum[r]);
                if (lm < 8) orow[16 + lm] = (_Float16)(ov1[r] * rsum[r]);
            }
        }
    }
}

// ---------------------------------------------------------------------------
// conv L1, tile-resident + fused LN partial stats (r16, verified).
// ---------------------------------------------------------------------------
__global__ void __launch_bounds__(256) k_conv1_tile(const _Float16* __restrict__ xinh,
                                                    const _Float16* __restrict__ wc,
                                                    const float* __restrict__ bias,
                                                    _Float16* __restrict__ c1,
                                                    float* __restrict__ pstat1)
{
    __shared__ __align__(16) _Float16 Xs[4 * 16 * 104];   // 13.3 KB
    __shared__ float bins[96];
    int t = threadIdx.x;
    int blk = blockIdx.x;
    int b = blk / 7, s = blk % 7;

    if (t < 96) bins[t] = 0.f;

    for (int i = t; i < 768; i += 256) {
        int r = i / 192, rem = i % 192;
        int c = rem / 12, ch = (rem % 12) * 8;
        *(uint4*)&Xs[(r * 16 + c) * 104 + ch] =
            *(const uint4*)(xinh + ((size_t)(b * 256) + (2 * s + r) * 16 + c) * 96 + ch);
    }

    int wave = t >> 6, lane = t & 63;
    int lm = lane & 15, quad = lane >> 4;
    int ry = wave >> 1, rx = wave & 1;

    __syncthreads();

    for (int nt = 0; nt < 3; ++nt) {
        half8 bf[12];
        #pragma unroll
        for (int ks = 0; ks < 12; ++ks)
            bf[ks] = *(const half8*)&wc[((size_t)(wave * 48 + nt * 16 + lm)) * 384
                                        + ks * 32 + quad * 8];

        float sl = 0.f, ql = 0.f;
        #pragma unroll
        for (int rt = 0; rt < 2; ++rt) {
            int pp = rt * 16 + lm;
            int ppc = pp < 28 ? pp : 27;
            int pyl = ppc / 14, px = ppc % 14;

            half8 af[12];
            #pragma unroll
            for (int ks = 0; ks < 12; ++ks) {
                int k0 = ks * 32 + quad * 8;
                int tap = k0 / 96, off = k0 % 96;
                int dy = tap >> 1, dx = tap & 1;
                af[ks] = *(const half8*)&Xs[((pyl + ry + dy) * 16 + (px + rx + dx)) * 104 + off];
            }

            f32x4 acc = (f32x4){0.f, 0.f, 0.f, 0.f};
            #pragma unroll
            for (int ks = 0; ks < 12; ++ks)
                acc = __builtin_amdgcn_mfma_f32_16x16x32_f16(af[ks], bf[ks], acc, 0, 0, 0);

            #pragma unroll
            for (int r = 0; r < 4; ++r) {
                int pw = rt * 16 + quad * 4 + r;
                if (pw < 28) {
                    int pylw = pw / 14, pxw = pw % 14;
                    int oy = 2 * (2 * s + pylw) + ry, ox = 2 * pxw + rx;
                    float v = acc[r] + bias[nt * 16 + lm];
                    sl += v; ql += v * v;
                    c1[((size_t)(b * 28 + oy) * 28 + ox) * 48 + nt * 16 + lm] = (_Float16)v;
                }
            }
        }
        atomicAdd(&bins[(nt * 16 + lm) * 2],     sl);
        atomicAdd(&bins[(nt * 16 + lm) * 2 + 1], ql);
    }
    __syncthreads();
    if (t < 96) atomicAdd(&pstat1[(size_t)b * 96 + t], bins[t]);
}

// ---------------------------------------------------------------------------
// L1 LN apply (r16, verified).
// ---------------------------------------------------------------------------
__global__ void __launch_bounds__(256) k_ln1_apply(const _Float16* __restrict__ c1,
                                                   const float* __restrict__ pstat1,
                                                   const float* __restrict__ g,
                                                   const float* __restrict__ bv,
                                                   _Float16* __restrict__ xh)
{
    int i4 = blockIdx.x * 256 + threadIdx.x;
    int idx = i4 * 4;
    int ch = idx % 48;
    int t2 = idx / 48;
    int pos = t2 % 900;
    int b = t2 / 900;
    int py = pos / 30, px = pos % 30;
    half4v hv = (half4v){(_Float16)0.f, (_Float16)0.f, (_Float16)0.f, (_Float16)0.f};
    if (py >= 1 && py <= 28 && px >= 1 && px <= 28) {
        int j = (py - 1) * 28 + (px - 1);
        half4v v = *(const half4v*)&c1[((size_t)b * 784 + j) * 48 + ch];
        const float* ps = pstat1 + (size_t)b * 96 + ch * 2;
        float gj = g[j], bj = bv[j];
        #pragma unroll
        for (int k = 0; k < 4; ++k) {
            float mu = ps[2 * k] * (1.f / 784.f);
            float rstd = rsqrtf(ps[2 * k + 1] * (1.f / 784.f) - mu * mu + 1e-5f);
            float u = ((float)v[k] - mu) * rstd * gj + bj;
            hv[k] = (_Float16)(u / (1.f + __expf(-u)));
        }
    }
    *(half4v*)&xh[idx] = hv;
}

// ---------------------------------------------------------------------------
// conv L2, tile-resident + fused LN partial stats (r16, verified).
// ---------------------------------------------------------------------------
__global__ void __launch_bounds__(256) k_conv2_tile(const _Float16* __restrict__ xh,
                                                    const _Float16* __restrict__ wc,
                                                    const float* __restrict__ bias,
                                                    _Float16* __restrict__ c2,
                                                    float* __restrict__ pstat2)
{
    __shared__ __align__(16) _Float16 Xs[4 * 30 * 56];   // 13.1 KB
    __shared__ float bins[48];
    int t = threadIdx.x;
    int blk = blockIdx.x;
    int b = blk / 14, s = blk % 14;

    if (t < 48) bins[t] = 0.f;

    for (int i = t; i < 720; i += 256) {
        int r = i / 180, rem = i % 180;
        int c = rem / 6, ch = (rem % 6) * 8;
        *(uint4*)&Xs[(r * 30 + c) * 56 + ch] =
            *(const uint4*)(xh + ((size_t)(b * 900) + (2 * s + r) * 30 + c) * 48 + ch);
    }

    int wave = t >> 6, lane = t & 63;
    int lm = lane & 15, quad = lane >> 4;
    int ry = wave >> 1, rx = wave & 1;

    half8 bf0[6], bf1[6];
    #pragma unroll
    for (int ks = 0; ks < 6; ++ks) {
        bf0[ks] = *(const half8*)&wc[((size_t)(wave * 32 + lm)) * 192 + ks * 32 + quad * 8];
        bf1[ks] = *(const half8*)&wc[((size_t)(wave * 32 + 16 + lm)) * 192 + ks * 32 + quad * 8];
    }

    __syncthreads();

    float s0l = 0.f, q0l = 0.f, s1l = 0.f, q1l = 0.f;
    #pragma unroll
    for (int rt = 0; rt < 4; ++rt) {
        int pp = rt * 16 + lm;
        int ppc = pp < 56 ? pp : 55;
        int pyl = ppc / 28, px = ppc % 28;

        half8 af[6];
        #pragma unroll
        for (int ks = 0; ks < 6; ++ks) {
            int k0 = ks * 32 + quad * 8;
            int tap = k0 / 48, off = k0 % 48;
            int dy = tap >> 1, dx = tap & 1;
            af[ks] = *(const half8*)&Xs[((pyl + ry + dy) * 30 + (px + rx + dx)) * 56 + off];
        }

        f32x4 acc0 = (f32x4){0.f, 0.f, 0.f, 0.f};
        f32x4 acc1 = (f32x4){0.f, 0.f, 0.f, 0.f};
        #pragma unroll
        for (int ks = 0; ks < 6; ++ks) {
            acc0 = __builtin_amdgcn_mfma_f32_16x16x32_f16(af[ks], bf0[ks], acc0, 0, 0, 0);
            acc1 = __builtin_amdgcn_mfma_f32_16x16x32_f16(af[ks], bf1[ks], acc1, 0, 0, 0);
        }

        #pragma unroll
        for (int r = 0; r < 4; ++r) {
            int pw = rt * 16 + quad * 4 + r;
            if (pw < 56) {
                int pylw = pw / 28, pxw = pw % 28;
                int oy = 2 * (2 * s + pylw) + ry, ox = 2 * pxw + rx;
                _Float16* orow = c2 + ((size_t)(b * 56 + oy) * 56 + ox) * 24;
                float v0 = acc0[r] + bias[lm];
                orow[lm] = (_Float16)v0;
                s0l += v0; q0l += v0 * v0;
                if (lm < 8) {
                    float v1 = acc1[r] + bias[16 + lm];
                    orow[16 + lm] = (_Float16)v1;
                    s1l += v1; q1l += v1 * v1;
                }
            }
        }
    }
    atomicAdd(&bins[lm * 2],     s0l);
    atomicAdd(&bins[lm * 2 + 1], q0l);
    if (lm < 8) {
        atomicAdd(&bins[(16 + lm) * 2],     s1l);
        atomicAdd(&bins[(16 + lm) * 2 + 1], q1l);
    }
    __syncthreads();
    if (t < 48) atomicAdd(&pstat2[(size_t)b * 48 + t], bins[t]);
}

// ---------------------------------------------------------------------------
// L2 LN apply (r16, verified).
// ---------------------------------------------------------------------------
__global__ void __launch_bounds__(256) k_ln2_apply(const _Float16* __restrict__ c2,
                                                   const float* __restrict__ pstat2,
                                                   const float* __restrict__ g,
                                                   const float* __restrict__ bv,
                                                   _Float16* __restrict__ xh)
{
    int i4 = blockIdx.x * 256 + threadIdx.x;
    int idx = i4 * 4;
    int ch = idx % 24;
    int t2 = idx / 24;
    int pos = t2 % 3364;
    int b = t2 / 3364;
    int py = pos / 58, px = pos % 58;
    half4v hv = (half4v){(_Float16)0.f, (_Float16)0.f, (_Float16)0.f, (_Float16)0.f};
    if (py >= 1 && py <= 56 && px >= 1 && px <= 56) {
        int j = (py - 1) * 56 + (px - 1);
        half4v v = *(const half4v*)&c2[((size_t)b * 3136 + j) * 24 + ch];
        const float* ps = pstat2 + (size_t)b * 48 + ch * 2;
        float gj = g[j], bj = bv[j];
        #pragma unroll
        for (int k = 0; k < 4; ++k) {
            float mu = ps[2 * k] * (1.f / 3136.f);
            float rstd = rsqrtf(ps[2 * k + 1] * (1.f / 3136.f) - mu * mu + 1e-5f);
            float u = ((float)v[k] - mu) * rstd * gj + bj;
            hv[k] = (_Float16)(u / (1.f + __expf(-u)));
        }
    }
    *(half4v*)&xh[idx] = hv;
}

// ---------------------------------------------------------------------------
// conv L3, tile-resident + fused LN partial stats (r16, verified).
// ---------------------------------------------------------------------------
__global__ void __launch_bounds__(256) k_conv3_tile(const _Float16* __restrict__ xh,
                                                    const _Float16* __restrict__ wc,
                                                    const float* __restrict__ bias,
                                                    _Float16* __restrict__ c3,
                                                    float* __restrict__ pstat3)
{
    __shared__ __align__(16) _Float16 Xs[3 * 58 * 40];   // 13.6 KB
    __shared__ float bins[24];
    int t = threadIdx.x;
    int blk = blockIdx.x;
    int b = blk / 56, s = blk % 56;

    if (t < 24) bins[t] = 0.f;

    for (int i = t; i < 522; i += 256) {
        int r = i / 174, rem = i % 174;
        int c = rem / 3, ch = (rem % 3) * 8;
        *(uint4*)&Xs[(r * 58 + c) * 40 + ch] =
            *(const uint4*)(xh + ((size_t)(b * 3364) + (s + r) * 58 + c) * 24 + ch);
    }

    int wave = t >> 6, lane = t & 63;
    int lm = lane & 15, quad = lane >> 4;
    int ry = wave >> 1, rx = wave & 1;

    half8 bf[3];
    #pragma unroll
    for (int ks = 0; ks < 3; ++ks)
        bf[ks] = *(const half8*)&wc[((size_t)(wave * 16 + lm)) * 96 + ks * 32 + quad * 8];

    __syncthreads();

    float sl = 0.f, ql = 0.f;
    #pragma unroll
    for (int rt = 0; rt < 4; ++rt) {
        int px = rt * 16 + lm;
        int pxc = px < 56 ? px : 55;

        half8 af[3];
        #pragma unroll
        for (int ks = 0; ks < 3; ++ks) {
            int k0 = ks * 32 + quad * 8;
            int tap = k0 / 24, off = k0 % 24;
            int dy = tap >> 1, dx = tap & 1;
            af[ks] = *(const half8*)&Xs[((ry + dy) * 58 + (pxc + rx + dx)) * 40 + off];
        }

        f32x4 acc = (f32x4){0.f, 0.f, 0.f, 0.f};
        #pragma unroll
        for (int ks = 0; ks < 3; ++ks)
            acc = __builtin_amdgcn_mfma_f32_16x16x32_f16(af[ks], bf[ks], acc, 0, 0, 0);

        if (lm < 12) {
            #pragma unroll
            for (int r = 0; r < 4; ++r) {
                int pw = rt * 16 + quad * 4 + r;
                if (pw < 56) {
                    int oy = 2 * s + ry, ox = 2 * pw + rx;
                    float v = acc[r] + bias[lm];
                    sl += v; ql += v * v;
                    c3[((size_t)(b * 112 + oy) * 112 + ox) * 12 + lm] = (_Float16)v;
                }
            }
        }
    }
    if (lm < 12) {
        atomicAdd(&bins[lm * 2],     sl);
        atomicAdd(&bins[lm * 2 + 1], ql);
    }
    __syncthreads();
    if (t < 24) atomicAdd(&pstat3[(size_t)b * 24 + t], bins[t]);
}

// ---------------------------------------------------------------------------
// L3 LN apply (r16, verified).
// ---------------------------------------------------------------------------
__global__ void __launch_bounds__(256) k_ln3_apply(const _Float16* __restrict__ c3,
                                                   const float* __restrict__ pstat3,
                                                   const float* __restrict__ g,
                                                   const float* __restrict__ bv,
                                                   _Float16* __restrict__ xh4)
{
    int i4 = blockIdx.x * 256 + threadIdx.x;
    int idx = i4 * 4;
    int ch = idx % 12;
    int t2 = idx / 12;
    int pix = t2 % 12544;
    int b = t2 / 12544;
    half4v v = *(const half4v*)&c3[idx];
    const float* ps = pstat3 + (size_t)b * 24 + ch * 2;
    float gp = g[pix], bp = bv[pix];
    half4v hv;
    #pragma unroll
    for (int k = 0; k < 4; ++k) {
        float mu = ps[2 * k] * (1.f / 12544.f);
        float rstd = rsqrtf(ps[2 * k + 1] * (1.f / 12544.f) - mu * mu + 1e-5f);
        float u = ((float)v[k] - mu) * rstd * gp + bp;
        hv[k] = (_Float16)(u / (1.f + __expf(-u)));
    }
    *(half4v*)&xh4[idx] = hv;
}

// ---------------------------------------------------------------------------
// final convT 12->1 via LDS staging + fdot2. Block = (image, 2 output-row
// pairs): stage rows py0-1..py0+2 x 112 x 12 f16 in LDS (col -1 wraps to
// slot 113, zero-padded), weights f16 in LDS (192 halves). Each active
// thread (t<224) computes 2x2 outputs with 96 v_dot2_f32_f16.
// grid 128*56 = 7168.
// ---------------------------------------------------------------------------
__global__ void __launch_bounds__(256) k_conv_final3(const _Float16* __restrict__ x,
                                                     const _Float16* __restrict__ wcf,
                                                     const float* __restrict__ bias,
                                                     float* __restrict__ out)
{
    constexpr int HIN = 112, CIN = 12;
    __shared__ __align__(16) _Float16 Xs[4 * 114 * 12];   // 10.9 KB
    __shared__ __align__(16) _Float16 Wl[192];
    int t = threadIdx.x;
    int blk = blockIdx.x;
    int b = blk / 56, s = blk % 56;
    int py0 = 2 * s;

    // zero LDS (incl. pad cols 112,113 and out-of-range rows)
    {
        const int4 z = {0, 0, 0, 0};
        int4* p4 = (int4*)Xs;
        for (int i = t; i < 684; i += 256) p4[i] = z;
        if (t < 24) *(int4*)&Wl[t * 8] = *(const int4*)&wcf[t * 8];
    }
    __syncthreads();
    // stage rows py0-1 .. py0+2 (cols 0..111 at slots 0..111)
    for (int i = t; i < 672; i += 256) {
        int r = i / 168, rem = i % 168;
        int row = py0 - 1 + r;
        if (row >= 0 && row < HIN) {
            *(uint4*)&Xs[(size_t)r * 1368 + rem * 8] =
                *(const uint4*)(x + ((size_t)b * HIN * HIN + (size_t)row * HIN) * CIN + rem * 8);
        }
    }
    __syncthreads();

    if (t >= 224) return;
    int pyl = t / 112;               // 0 or 1
    int px = t % 112;
    int py = py0 + pyl;

    // load 9 taps from LDS as packed f16 pairs
    half2v tvp[9][6];
    #pragma unroll
    for (int a = 0; a < 3; ++a) {
        int lr = pyl + a;            // local row (input row py-1+a)
        #pragma unroll
        for (int c = 0; c < 3; ++c) {
            int col = px - 1 + c;
            int cs = (col < 0) ? 113 : col;   // slot 113 = zero pad; col 112 also zero
            const _Float16* p = &Xs[((size_t)lr * 114 + cs) * 12];
            half4v h0 = *(const half4v*)&p[0];
            half4v h1 = *(const half4v*)&p[4];
            half4v h2 = *(const half4v*)&p[8];
            int ti = a * 3 + c;
            tvp[ti][0] = (half2v){h0[0], h0[1]};
            tvp[ti][1] = (half2v){h0[2], h0[3]};
            tvp[ti][2] = (half2v){h1[0], h1[1]};
            tvp[ti][3] = (half2v){h1[2], h1[3]};
            tvp[ti][4] = (half2v){h2[0], h2[1]};
            tvp[ti][5] = (half2v){h2[2], h2[3]};
        }
    }

    float bb = bias[0];
    float* ob = out + (size_t)b * 50176;
    #pragma unroll
    for (int ry = 0; ry < 2; ++ry) {
        float res[2];
        #pragma unroll
        for (int rx = 0; rx < 2; ++rx) {
            int p = ry * 2 + rx;
            float acc = 0.f;
            #pragma unroll
            for (int dy = 0; dy < 2; ++dy) {
                #pragma unroll
                for (int dx = 0; dx < 2; ++dx) {
                    int j = dy * 2 + dx;
                    int ti = (ry + dy) * 3 + (rx + dx);
                    const half2v* wp = (const half2v*)&Wl[(p * 4 + j) * 12];
                    #pragma unroll
                    for (int k = 0; k < 6; ++k)
                        acc = __builtin_amdgcn_fdot2(tvp[ti][k], wp[k], acc, false);
                }
            }
            float u = acc + bb;
            u = u / (1.f + __expf(-u));
            res[rx] = fminf(fmaxf(u, 0.f), 1.f);
        }
        float2 v; v.x = res[0]; v.y = res[1];
        *(float2*)(ob + (size_t)(2 * py + ry) * 224 + 2 * px) = v;
    }
}

// ---------------------------------------------------------------------------
// launch
// ---------------------------------------------------------------------------
extern "C" void kernel_launch(void* const* d_in, const int* in_sizes, int n_in,
                              void* d_out, int out_size, void* d_ws, size_t ws_size,
                              hipStream_t stream)
{
    const float* x       = (const float*)d_in[0];
    const float* ts      = (const float*)d_in[1];
    const float* Wp      = (const float*)d_in[2];
    const float* bp      = (const float*)d_in[3];
    const float* Wt1     = (const float*)d_in[4];
    const float* bt1     = (const float*)d_in[5];
    const float* Wt2     = (const float*)d_in[6];
    const float* bt2     = (const float*)d_in[7];
    const float* a0_g    = (const float*)d_in[8];
    const float* a0_b    = (const float*)d_in[9];
    const float* a0_Wqkv = (const float*)d_in[10];
    const float* a0_bqkv = (const float*)d_in[11];
    const float* a0_Wo   = (const float*)d_in[12];
    const float* a0_bo   = (const float*)d_in[13];
    const float* a1_g    = (const float*)d_in[14];
    const float* a1_b    = (const float*)d_in[15];
    const float* a1_Wqkv = (const float*)d_in[16];
    const float* a1_bqkv = (const float*)d_in[17];
    const float* a1_Wo   = (const float*)d_in[18];
    const float* a1_bo   = (const float*)d_in[19];
    const float* Wm0     = (const float*)d_in[20];
    const float* bm0     = (const float*)d_in[21];
    const float* Wm1     = (const float*)d_in[22];
    const float* bm1     = (const float*)d_in[23];
    const float* Wm2     = (const float*)d_in[24];
    const float* bm2     = (const float*)d_in[25];
    const float* Wd1     = (const float*)d_in[26];
    const float* bd1     = (const float*)d_in[27];
    const float* l1g     = (const float*)d_in[28];
    const float* l1b     = (const float*)d_in[29];
    const float* Wd2     = (const float*)d_in[30];
    const float* bd2     = (const float*)d_in[31];
    const float* l2g     = (const float*)d_in[32];
    const float* l2b     = (const float*)d_in[33];
    const float* Wd3     = (const float*)d_in[34];
    const float* bd3     = (const float*)d_in[35];
    const float* l3g     = (const float*)d_in[36];
    const float* l3b     = (const float*)d_in[37];
    const float* Wd4     = (const float*)d_in[38];
    const float* bd4     = (const float*)d_in[39];
    float* out = (float*)d_out;

    // arena (floats); R = 25088*96
    const size_t R = 2408448;
    float* ws   = (float*)d_ws;
    float* tvec = ws;                          // 96
    float* p0   = ws + 512;                    // R (fp32 residual; f16 alias p0h)
    _Float16* p0h  = (_Float16*)(ws + 512);           // f16 wo1 out (p0 region)
    _Float16* hh   = (_Float16*)(ws + 512 + R);       // f16 LN out (h region)
    _Float16* qkvh = (_Float16*)(ws + 512 + 2 * R);   // f16 qkv [M][288]
    _Float16* obh  = (_Float16*)(ws + 512 + 5 * R);   // f16 attn out (ob region)
    float* p1   = ws + 512 + 6 * R;            // R
    // decoder aliases:
    _Float16* xinh = (_Float16*)(ws + 512 + 2 * R);   // f16 NHWC (qkv region)
    _Float16* C1h  = (_Float16*)(ws + 512 + 5 * R);   // f16 NHWC [b][28][28][48]
    _Float16* xh2  = (_Float16*)(ws + 512 + 7 * R);   // f16 NHWC padded [b][30][30][48]
    _Float16* C2h  = (_Float16*)(ws + 512);           // f16 NHWC [b][56][56][24]
    _Float16* xh3  = (_Float16*)(ws + 512 + 7 * R + 5529600); // f16 padded [b][58][58][24]
    _Float16* C3h  = (_Float16*)(ws + 512);           // f16 NHWC [b][112][112][12]
    _Float16* xh4  = (_Float16*)(ws + 512 + 7 * R + 5529600); // f16 [b][112][112][12]
    float* Wr   = ws + 512 + 7 * R + 5529600 + 10334208;  // 96,960 floats
    _Float16* WH = (_Float16*)(Wr + 96960);                // 101,376 halves
    _Float16* Wc  = (_Float16*)Wr;
    _Float16* Wc2 = (_Float16*)(Wr + 36864);
    _Float16* Wc3 = (_Float16*)(Wr + 49152);
    float* stat = Wr + 96960 + 50688;          // 21,504 floats (raw LN sums)
    float* stat1 = stat;                       // 128*96
    float* stat2 = stat + 12288;               // 128*48
    float* stat3 = stat + 18432;               // 128*24
    _Float16* Wcf = (_Float16*)(stat + 21504); // 192 halves (conv_final f16 w)
    const size_t NEED = (512 + 7 * R + 5529600 + 10334208 + 96960 + 50688 + 21504 + 128)
                        * sizeof(float);
    if (ws_size < NEED) return;

    _Float16* WHqkv0 = WH;
    _Float16* WHqkv1 = WH + 27648;
    _Float16* WHwo0  = WH + 55296;
    _Float16* WHwo1  = WH + 64512;
    _Float16* WHwm0  = WH + 73728;   // wm0,wm1,wm2 consecutive

    k_time<<<1, 128, 0, stream>>>(ts, Wt1, bt1, Wt2, bt2, tvec);
    k_zstat<<<84, 256, 0, stream>>>(stat);
    k_repack<<<379, 256, 0, stream>>>(Wd1, Wd2, Wd3, Wd4, Wr);
    k_wcvt4<<<1, 192, 0, stream>>>(Wr + 96768, Wcf);
    k_wcvtc<<<288, 256, 0, stream>>>(Wd1, Wc);
    k_wcvt2<<<96, 256, 0, stream>>>(Wd2, Wc2);
    k_wcvt3<<<24, 256, 0, stream>>>(Wd3, Wc3);
    k_wcvt<<<396, 256, 0, stream>>>(a0_Wqkv, a1_Wqkv, a0_Wo, a1_Wo,
                                    Wm0, Wm1, Wm2, WH);
    k_patch_mfma<<<M_ROWS / 64, 256, 0, stream>>>(x, Wp, bp, p0);

    // MHSA block 0
    k_ln_row<<<1024, 256, 0, stream>>>(p0, a0_g, a0_b, hh, M_ROWS);
    k_gemm_mfma<3, 1, false, false, false, true><<<dim3(M_ROWS / 64, 3), 256, 0, stream>>>(
        hh, WHqkv0, a0_bqkv, nullptr, nullptr, qkvh);
    k_attn_mfma<<<B_ * 4, 256, 0, stream>>>(qkvh, obh);
    k_gemm_mfma<1, 0, false, true, false, true><<<dim3(M_ROWS / 64, 1), 256, 0, stream>>>(
        obh, WHwo0, a0_bo, p0, nullptr, p1);

    // MHSA block 1 (+time)
    k_ln_row<<<1024, 256, 0, stream>>>(p1, a1_g, a1_b, hh, M_ROWS);
    k_gemm_mfma<3, 1, false, false, false, true><<<dim3(M_ROWS / 64, 3), 256, 0, stream>>>(
        hh, WHqkv1, a1_bqkv, nullptr, nullptr, qkvh);
    k_attn_mfma<<<B_ * 4, 256, 0, stream>>>(qkvh, obh);
    // wo1 + residual + time -> f16 p0h (only consumer: MLP)
    k_gemm_mfma<1, 1, false, true, true, true><<<dim3(M_ROWS / 64, 1), 256, 0, stream>>>(
        obh, WHwo1, a1_bo, p1, tvec, p0h);

    // qkv region free: zero xinh borders before MLP writes interior
    k_zb_h<<<2880, 256, 0, stream>>>(xinh);

    // fused MLP x3 (silu); writes f16 NHWC padded xinh
    k_mlp_fused<<<M_ROWS / 64, 256, 0, stream>>>(p0h, WHwm0, bm0, bm1, bm2, xinh);

    // decoder: all-NHWC f16 chain, tile-resident convs with fused LN stats
    k_conv1_tile<<<B_ * 7, 256, 0, stream>>>(xinh, Wc, bd1, C1h, stat1);
    k_ln1_apply<<<5400, 256, 0, stream>>>(C1h, stat1, l1g, l1b, xh2);
    k_conv2_tile<<<B_ * 14, 256, 0, stream>>>(xh2, Wc2, bd2, C2h, stat2);
    k_ln2_apply<<<10092, 256, 0, stream>>>(C2h, stat2, l2g, l2b, xh3);
    k_conv3_tile<<<B_ * 56, 256, 0, stream>>>(xh3, Wc3, bd3, C3h, stat3);
    k_ln3_apply<<<18816, 256, 0, stream>>>(C3h, stat3, l3g, l3b, xh4);
    k_conv_final3<<<7168, 256, 0, stream>>>(xh4, Wcf, bd4, out);
}

// Round 12
// 430.963 us; speedup vs baseline: 1.1211x; 1.1211x over previous
//
#include <hip/hip_runtime.h>
#include <cmath>

// ---------------------------------------------------------------------------
// TimestepVisionTransformer — Round 20: occupancy-fixed patch embed.
//   - k_patch_mfma: 32 patches/block (784 blocks, ~3/CU vs 392 @1.5/CU,
//     occupancy 16%->~40%), wave=(row-tile, col-half), LDS 34.8KB.
//   - k_wcvtp pre-converts Wp to f16 ONCE in the LDS tile layout ->
//     weight staging is a pure uint4 copy (no per-block converts).
// Everything else = r19 (conv_final3 verified; r19's 483 includes patch
// at 56us latency-bound — this attacks that).
// B=128, IMG=224, P=16, C_IN=1, E=96, H=4, d=24, NAX=14, N=196, M=B*N=25088
// ---------------------------------------------------------------------------

#define B_   128
#define NPATCH 196
#define M_ROWS (B_*NPATCH)     // 25088
#define E_   96

typedef _Float16 half8 __attribute__((ext_vector_type(8)));
typedef _Float16 half4v __attribute__((ext_vector_type(4)));
typedef _Float16 half2v __attribute__((ext_vector_type(2)));
typedef float f32x4 __attribute__((ext_vector_type(4)));

// ---------------------------------------------------------------------------
// time embedding
// ---------------------------------------------------------------------------
__global__ void k_time(const float* __restrict__ ts,
                       const float* __restrict__ Wt1, const float* __restrict__ bt1,
                       const float* __restrict__ Wt2, const float* __restrict__ bt2,
                       float* __restrict__ timev)
{
    __shared__ float h[128];
    float e = 0.69314718055994530942f * ts[0];
    float sv = sinf(e), cv = cosf(e);
    int t = threadIdx.x;
    float z = sv * Wt1[t] + cv * Wt1[128 + t] + bt1[t];
    h[t] = z / (1.f + expf(-z));
    __syncthreads();
    if (t < 96) {
        float acc = bt2[t];
        for (int j = 0; j < 128; ++j) acc += h[j] * Wt2[j * 96 + t];
        timev[t] = acc;
    }
}

// ---------------------------------------------------------------------------
// zero LN partial-stat table (21504 floats)
// ---------------------------------------------------------------------------
__global__ void __launch_bounds__(256) k_zstat(float* __restrict__ stat)
{
    int i = blockIdx.x * 256 + threadIdx.x;
    if (i < 21504) stat[i] = 0.f;
}

// ---------------------------------------------------------------------------
// weight repack (fp32 per-parity taps). L4 slice [96768,96960) feeds k_wcvt4;
// other slices overwritten by f16 packs.
// ---------------------------------------------------------------------------
__global__ void __launch_bounds__(256) k_repack(const float* __restrict__ w1,
                                                const float* __restrict__ w2,
                                                const float* __restrict__ w3,
                                                const float* __restrict__ w4f,
                                                float* __restrict__ wr)
{
    int i = blockIdx.x * 256 + threadIdx.x;
    const float* src; int CIN, COUT, e; float* dst;
    if      (i < 73728) { src = w1;  CIN = 96; COUT = 48; e = i;          dst = wr; }
    else if (i < 92160) { src = w2;  CIN = 48; COUT = 24; e = i - 73728;  dst = wr + 73728; }
    else if (i < 96768) { src = w3;  CIN = 24; COUT = 12; e = i - 92160;  dst = wr + 92160; }
    else if (i < 96960) { src = w4f; CIN = 12; COUT = 1;  e = i - 96768;  dst = wr + 96768; }
    else return;
    int per = CIN * COUT * 4;
    int par = e / per, rem = e % per;
    int ci = rem / (COUT * 4);
    int o  = (rem >> 2) % COUT;
    int j  = rem & 3;
    int ry = par >> 1, rx = par & 1;
    int wy = (j < 2)  ? (3 - ry) : (1 - ry);
    int wx = (j & 1)  ? (1 - rx) : (3 - rx);
    dst[e] = src[(ci * COUT + o) * 16 + wy * 4 + wx];
}

// ---------------------------------------------------------------------------
// conv_final weights -> f16 wcf[p][j][ci] (192 halves) from fp32 [p][ci][j]
// ---------------------------------------------------------------------------
__global__ void k_wcvt4(const float* __restrict__ wr4,
                        _Float16* __restrict__ wcf)
{
    int i = threadIdx.x;
    if (i >= 192) return;
    int p = i / 48, rem = i % 48;
    int j = rem / 12, ci = rem % 12;
    wcf[(p * 4 + j) * 12 + ci] = (_Float16)wr4[p * 48 + ci * 4 + j];
}

// ---------------------------------------------------------------------------
// patch weights -> f16 wph[kc][e][k] (24576 halves), k in [0,128)
// ---------------------------------------------------------------------------
__global__ void __launch_bounds__(256) k_wcvtp(const float* __restrict__ Wp,
                                               _Float16* __restrict__ wph)
{
    int i = blockIdx.x * 256 + threadIdx.x;
    if (i >= 24576) return;
    int kc = i / 12288, rem = i % 12288;
    int e = rem / 128, k = rem % 128;
    wph[i] = (_Float16)Wp[e * 256 + kc * 128 + k];
}

// ---------------------------------------------------------------------------
// conv1 weights -> f16 B-layout Wc[p][o][k=tap*96+ci]
// ---------------------------------------------------------------------------
__global__ void __launch_bounds__(256) k_wcvtc(const float* __restrict__ w1,
                                               _Float16* __restrict__ wc)
{
    int i = blockIdx.x * 256 + threadIdx.x;
    if (i >= 4 * 48 * 384) return;
    int p = i / 18432, rem = i % 18432;
    int o = rem / 384, k = rem % 384;
    int tap = k / 96, ci = k % 96;
    int ry = p >> 1, rx = p & 1;
    int wy = (tap < 2) ? (3 - ry) : (1 - ry);
    int wx = (tap & 1) ? (1 - rx) : (3 - rx);
    wc[i] = (_Float16)w1[(ci * 48 + o) * 16 + wy * 4 + wx];
}

// ---------------------------------------------------------------------------
// conv2 weights -> f16 B-layout Wc2[p][o(32, o>=24 zero)][k=tap*48+ci]
// ---------------------------------------------------------------------------
__global__ void __launch_bounds__(256) k_wcvt2(const float* __restrict__ w2,
                                               _Float16* __restrict__ wc2)
{
    int i = blockIdx.x * 256 + threadIdx.x;
    if (i >= 4 * 32 * 192) return;
    int p = i / 6144, rem = i % 6144;
    int o = rem / 192, k = rem % 192;
    int tap = k / 48, ci = k % 48;
    int ry = p >> 1, rx = p & 1;
    int wy = (tap < 2) ? (3 - ry) : (1 - ry);
    int wx = (tap & 1) ? (1 - rx) : (3 - rx);
    wc2[i] = (o < 24) ? (_Float16)w2[(ci * 24 + o) * 16 + wy * 4 + wx]
                      : (_Float16)0.f;
}

// ---------------------------------------------------------------------------
// conv3 weights -> f16 B-layout Wc3[p][o(16, o>=12 zero)][k=tap*24+ci]
// ---------------------------------------------------------------------------
__global__ void __launch_bounds__(256) k_wcvt3(const float* __restrict__ w3,
                                               _Float16* __restrict__ wc3)
{
    int i = blockIdx.x * 256 + threadIdx.x;
    if (i >= 4 * 16 * 96) return;
    int p = i / 1536, rem = i % 1536;
    int o = rem / 96, k = rem % 96;
    int tap = k / 24, ci = k % 24;
    int ry = p >> 1, rx = p & 1;
    int wy = (tap < 2) ? (3 - ry) : (1 - ry);
    int wx = (tap & 1) ? (1 - rx) : (3 - rx);
    wc3[i] = (o < 12) ? (_Float16)w3[(ci * 12 + o) * 16 + wy * 4 + wx]
                      : (_Float16)0.f;
}

// ---------------------------------------------------------------------------
// transformer weight convert+transpose to half: Wt[n][k] = W[k][n]
// ---------------------------------------------------------------------------
__global__ void __launch_bounds__(256) k_wcvt(const float* __restrict__ qkv0,
                                              const float* __restrict__ qkv1,
                                              const float* __restrict__ wo0,
                                              const float* __restrict__ wo1,
                                              const float* __restrict__ wm0,
                                              const float* __restrict__ wm1,
                                              const float* __restrict__ wm2,
                                              _Float16* __restrict__ wh)
{
    int i = blockIdx.x * 256 + threadIdx.x;
    const float* src; int N; int e;
    if      (i < 27648)  { src = qkv0; N = 288; e = i; }
    else if (i < 55296)  { src = qkv1; N = 288; e = i - 27648; }
    else if (i < 64512)  { src = wo0;  N = 96;  e = i - 55296; }
    else if (i < 73728)  { src = wo1;  N = 96;  e = i - 64512; }
    else if (i < 82944)  { src = wm0;  N = 96;  e = i - 73728; }
    else if (i < 92160)  { src = wm1;  N = 96;  e = i - 82944; }
    else if (i < 101376) { src = wm2;  N = 96;  e = i - 92160; }
    else return;
    int n = e / 96, k = e % 96;
    wh[i] = (_Float16)src[k * N + n];
}

// ---------------------------------------------------------------------------
// zero the borders of xinh NHWC f16 [b][16][16][96]
// ---------------------------------------------------------------------------
__global__ void __launch_bounds__(256) k_zb_h(_Float16* __restrict__ xinh)
{
    int i = blockIdx.x * 256 + threadIdx.x;
    if (i >= 128 * 60 * 96) return;
    int b = i / 5760, r = i % 5760;
    int pos = r / 96, ch = r % 96;
    int py, px;
    if      (pos < 16) { py = 0;        px = pos; }
    else if (pos < 32) { py = 15;       px = pos - 16; }
    else if (pos < 46) { py = pos - 31; px = 0; }
    else               { py = pos - 45; px = 15; }
    xinh[((size_t)(b * 256) + py * 16 + px) * 96 + ch] = (_Float16)0.f;
}

// ---------------------------------------------------------------------------
// patch embed GEMM, occupancy-fixed: 32 patches/block, 784 blocks.
// wave = (row-tile rt=wave>>1, col-half nh=wave&1); per chunk 4ks x 3nt MFMA.
// W staged from preconverted f16 wph (pure uint4 copy). LDS 34.8 KB.
// ---------------------------------------------------------------------------
__global__ void __launch_bounds__(256) k_patch_mfma(const float* __restrict__ x,
                                                    const _Float16* __restrict__ wph,
                                                    const float* __restrict__ bp,
                                                    float* __restrict__ out)
{
    __shared__ __align__(16) _Float16 Ah[32 * 136];
    __shared__ __align__(16) _Float16 Wh[96 * 136];
    int t = threadIdx.x;
    int p0 = blockIdx.x * 32;
    int wave = t >> 6, lane = t & 63;
    int lm = lane & 15, quad = lane >> 4;
    int rt = wave >> 1, nh = wave & 1;
    f32x4 acc[3];
    #pragma unroll
    for (int nt = 0; nt < 3; ++nt) acc[nt] = (f32x4){0.f, 0.f, 0.f, 0.f};

    for (int kc = 0; kc < 2; ++kc) {
        __syncthreads();
        {
            // stage A: 32 patches x 8 rows (1 item/thread)
            int lp = t >> 3, pyl = t & 7;
            int patch = p0 + lp;
            int b = patch / NPATCH, n = patch % NPATCH;
            int ny = n / 14, nx = n % 14;
            const float4* s4 = (const float4*)(x +
                ((size_t)(b * 224) + ny * 16 + kc * 8 + pyl) * 224 + nx * 16);
            float4 v0 = s4[0], v1 = s4[1], v2 = s4[2], v3 = s4[3];
            half8 h0, h1;
            h0[0]=(_Float16)v0.x; h0[1]=(_Float16)v0.y; h0[2]=(_Float16)v0.z; h0[3]=(_Float16)v0.w;
            h0[4]=(_Float16)v1.x; h0[5]=(_Float16)v1.y; h0[6]=(_Float16)v1.z; h0[7]=(_Float16)v1.w;
            h1[0]=(_Float16)v2.x; h1[1]=(_Float16)v2.y; h1[2]=(_Float16)v2.z; h1[3]=(_Float16)v2.w;
            h1[4]=(_Float16)v3.x; h1[5]=(_Float16)v3.y; h1[6]=(_Float16)v3.z; h1[7]=(_Float16)v3.w;
            *(half8*)&Ah[lp * 136 + pyl * 16]     = h0;
            *(half8*)&Ah[lp * 136 + pyl * 16 + 8] = h1;
        }
        {
            // stage W: pure uint4 copy from preconverted f16 (6 items/thread)
            const uint4* src = (const uint4*)(wph + (size_t)kc * 12288);
            for (int i = t; i < 1536; i += 256) {
                int e = i >> 4, s = i & 15;
                *(uint4*)&Wh[e * 136 + s * 8] = src[i];
            }
        }
        __syncthreads();
        half8 af[4];
        #pragma unroll
        for (int ks = 0; ks < 4; ++ks)
            af[ks] = *(const half8*)&Ah[(rt * 16 + lm) * 136 + ks * 32 + quad * 8];
        #pragma unroll
        for (int ks = 0; ks < 4; ++ks) {
            #pragma unroll
            for (int nt = 0; nt < 3; ++nt) {
                half8 bf = *(const half8*)&Wh[((nh * 3 + nt) * 16 + lm) * 136 + ks * 32 + quad * 8];
                acc[nt] = __builtin_amdgcn_mfma_f32_16x16x32_f16(af[ks], bf, acc[nt], 0, 0, 0);
            }
        }
    }

    #pragma unroll
    for (int nt = 0; nt < 3; ++nt) {
        #pragma unroll
        for (int r = 0; r < 4; ++r) {
            int e = (nh * 3 + nt) * 16 + lm;
            int lp = rt * 16 + quad * 4 + r;
            int patch = p0 + lp;
            int n = patch % NPATCH;
            int ny = n / 14, nx = n % 14;
            float yx = (float)(ny + nx);
            float v = acc[nt][r] + bp[e];
            float other = __shfl_xor(v, 1);
            float fi = (float)(e >> 1);
            float theta = expf(fi * (-2.f / 96.f) * 9.210340371976184f);
            float ang = theta * yx;
            float c = cosf(ang), s = sinf(ang);
            float outv = (lm & 1) ? (other * s + v * c) : (v * c - other * s);
            out[(size_t)patch * 96 + e] = outv;
        }
    }
}

// ---------------------------------------------------------------------------
// row LayerNorm over 96, wave per row — writes f16.
// ---------------------------------------------------------------------------
__global__ void __launch_bounds__(256) k_ln_row(const float* __restrict__ x,
                                                const float* __restrict__ g,
                                                const float* __restrict__ bv,
                                                _Float16* __restrict__ out, int M)
{
    int lane = threadIdx.x & 63;
    int gw = (blockIdx.x * 256 + threadIdx.x) >> 6;
    int nw = (gridDim.x * 256) >> 6;
    float g0 = g[lane], b0 = bv[lane];
    float g1 = 0.f, b1 = 0.f;
    if (lane < 32) { g1 = g[64 + lane]; b1 = bv[64 + lane]; }
    for (int r = gw; r < M; r += nw) {
        const float* xr = x + (size_t)r * 96;
        float a = xr[lane];
        float c = (lane < 32) ? xr[64 + lane] : 0.f;
        float s = a + c, q = a * a + c * c;
        #pragma unroll
        for (int off = 32; off; off >>= 1) {
            s += __shfl_xor(s, off);
            q += __shfl_xor(q, off);
        }
        float mu = s * (1.f / 96.f);
        float rstd = rsqrtf(q * (1.f / 96.f) - mu * mu + 1e-5f);
        _Float16* orow = out + (size_t)r * 96;
        orow[lane] = (_Float16)((a - mu) * rstd * g0 + b0);
        if (lane < 32) orow[64 + lane] = (_Float16)((c - mu) * rstd * g1 + b1);
    }
}

// ---------------------------------------------------------------------------
// MFMA row GEMM (r16, verified). AHALF: A f16. OUTMODE: 0=fp32, 1=f16.
// Chunks over blockIdx.y.
// ---------------------------------------------------------------------------
template<int NCHUNKS, int OUTMODE, bool SILU, bool RES, bool ADDTIME, bool AHALF>
__global__ void __launch_bounds__(256) k_gemm_mfma(const void* __restrict__ A,
                                                   const _Float16* __restrict__ Wt,
                                                   const float* __restrict__ bias,
                                                   const float* __restrict__ res,
                                                   const float* __restrict__ timev,
                                                   void* __restrict__ outp)
{
    __shared__ __align__(16) _Float16 Ah[64 * 96];
    __shared__ __align__(16) _Float16 Wh[96 * 96];
    constexpr int NTOT = NCHUNKS * 96;
    int t = threadIdx.x;
    size_t row0 = (size_t)blockIdx.x * 64;

    if constexpr (AHALF) {
        const uint4* a4 = (const uint4*)((const _Float16*)A + row0 * 96);
        uint4* dst = (uint4*)Ah;
        for (int i = t; i < 768; i += 256) dst[i] = a4[i];
    } else {
        const float4* a4 = (const float4*)((const float*)A + row0 * 96);
        for (int i = t; i < 1536; i += 256) {
            float4 v = a4[i];
            half4v hv;
            hv[0] = (_Float16)v.x; hv[1] = (_Float16)v.y;
            hv[2] = (_Float16)v.z; hv[3] = (_Float16)v.w;
            *(half4v*)&Ah[i * 4] = hv;
        }
    }

    int wave = t >> 6, lane = t & 63;
    int lm = lane & 15, quad = lane >> 4;
    const f32x4 vzero = {0.f, 0.f, 0.f, 0.f};

    for (int ch = blockIdx.y; ch < NCHUNKS; ch += gridDim.y) {
        __syncthreads();
        {
            const uint4* src = (const uint4*)(Wt + (size_t)ch * 9216);
            uint4* dst = (uint4*)Wh;
            for (int i = t; i < 1152; i += 256) dst[i] = src[i];
        }
        __syncthreads();

        half8 af[3];
        #pragma unroll
        for (int ks = 0; ks < 3; ++ks)
            af[ks] = *(const half8*)&Ah[(wave * 16 + lm) * 96 + ks * 32 + quad * 8];

        f32x4 acc[6];
        #pragma unroll
        for (int ct = 0; ct < 6; ++ct) acc[ct] = vzero;

        #pragma unroll
        for (int ct = 0; ct < 6; ++ct) {
            #pragma unroll
            for (int ks = 0; ks < 3; ++ks) {
                half8 bf = *(const half8*)&Wh[(ct * 16 + lm) * 96 + ks * 32 + quad * 8];
                acc[ct] = __builtin_amdgcn_mfma_f32_16x16x32_f16(af[ks], bf, acc[ct], 0, 0, 0);
            }
        }

        #pragma unroll
        for (int ct = 0; ct < 6; ++ct) {
            #pragma unroll
            for (int r = 0; r < 4; ++r) {
                int lr = wave * 16 + quad * 4 + r;
                size_t row = row0 + lr;
                int lc = ct * 16 + lm;
                int col = ch * 96 + lc;
                float v = acc[ct][r] + bias[col];
                if constexpr (RES)     v += res[row * 96 + lc];
                if constexpr (ADDTIME) v += timev[lc];
                if constexpr (SILU)    v = v / (1.f + __expf(-v));
                if constexpr (OUTMODE == 0) {
                    ((float*)outp)[row * NTOT + col] = v;
                } else {
                    ((_Float16*)outp)[row * NTOT + col] = (_Float16)v;
                }
            }
        }
    }
}

// ---------------------------------------------------------------------------
// fused MLP (f16 input): 3 chained 96x96 GEMMs + silu, one kernel.
// ---------------------------------------------------------------------------
__global__ void __launch_bounds__(256) k_mlp_fused(const _Float16* __restrict__ A,
                                                   const _Float16* __restrict__ W,
                                                   const float* __restrict__ b0,
                                                   const float* __restrict__ b1,
                                                   const float* __restrict__ b2,
                                                   _Float16* __restrict__ outh)
{
    __shared__ __align__(16) _Float16 Ah[2][64 * 96];
    __shared__ __align__(16) _Float16 Wh[3][96 * 96];
    int t = threadIdx.x;
    size_t row0 = (size_t)blockIdx.x * 64;

    {
        const uint4* a4 = (const uint4*)(A + row0 * 96);
        uint4* dst = (uint4*)&Ah[0][0];
        for (int i = t; i < 768; i += 256) dst[i] = a4[i];
    }
    {
        const uint4* src = (const uint4*)W;
        uint4* dst = (uint4*)&Wh[0][0];
        for (int i = t; i < 3456; i += 256) dst[i] = src[i];
    }

    int wave = t >> 6, lane = t & 63;
    int lm = lane & 15, quad = lane >> 4;
    const float* biases[3] = { b0, b1, b2 };
    int cur = 0;

    #pragma unroll
    for (int s = 0; s < 3; ++s) {
        __syncthreads();
        half8 af[3];
        #pragma unroll
        for (int ks = 0; ks < 3; ++ks)
            af[ks] = *(const half8*)&Ah[cur][(wave * 16 + lm) * 96 + ks * 32 + quad * 8];

        f32x4 acc[6];
        #pragma unroll
        for (int ct = 0; ct < 6; ++ct) acc[ct] = (f32x4){0.f, 0.f, 0.f, 0.f};

        #pragma unroll
        for (int ct = 0; ct < 6; ++ct) {
            #pragma unroll
            for (int ks = 0; ks < 3; ++ks) {
                half8 bf = *(const half8*)&Wh[s][(ct * 16 + lm) * 96 + ks * 32 + quad * 8];
                acc[ct] = __builtin_amdgcn_mfma_f32_16x16x32_f16(af[ks], bf, acc[ct], 0, 0, 0);
            }
        }

        const float* bias = biases[s];
        if (s < 2) {
            #pragma unroll
            for (int ct = 0; ct < 6; ++ct) {
                #pragma unroll
                for (int r = 0; r < 4; ++r) {
                    int lr = wave * 16 + quad * 4 + r;
                    int lc = ct * 16 + lm;
                    float v = acc[ct][r] + bias[lc];
                    v = v / (1.f + __expf(-v));
                    Ah[cur ^ 1][lr * 96 + lc] = (_Float16)v;
                }
            }
            cur ^= 1;
        } else {
            #pragma unroll
            for (int ct = 0; ct < 6; ++ct) {
                #pragma unroll
                for (int r = 0; r < 4; ++r) {
                    int lr = wave * 16 + quad * 4 + r;
                    size_t row = row0 + lr;
                    int lc = ct * 16 + lm;
                    float v = acc[ct][r] + bias[lc];
                    v = v / (1.f + __expf(-v));
                    size_t b = row / NPATCH; int n = (int)(row % NPATCH);
                    int ny = n / 14, nx = n % 14;
                    outh[((b * 256) + (1 + ny) * 16 + (1 + nx)) * 96 + lc] = (_Float16)v;
                }
            }
        }
    }
}

// ---------------------------------------------------------------------------
// MFMA attention (r11 structure): qkv input f16, output f16.
// ---------------------------------------------------------------------------
__global__ void __launch_bounds__(256) k_attn_mfma(const _Float16* __restrict__ qkv,
                                                   _Float16* __restrict__ o)
{
    __shared__ __align__(16) _Float16 Qs[208 * 40];
    __shared__ __align__(16) _Float16 Ks[208 * 40];
    __shared__ __align__(16) _Float16 Vt[32 * 232];
    __shared__ __align__(16) _Float16 Pw[4][16 * 232];

    int t = threadIdx.x;
    int bh = blockIdx.x;
    int b = bh >> 2, h = bh & 3;
    const _Float16* base = qkv + (size_t)b * NPATCH * 288 + h * 24;

    {
        const int4 z = {0, 0, 0, 0};
        int4* q4 = (int4*)Qs; int4* k4 = (int4*)Ks;
        for (int i = t; i < 1040; i += 256) { q4[i] = z; k4[i] = z; }
        int4* v4 = (int4*)Vt;
        for (int i = t; i < 928; i += 256) v4[i] = z;
        int4* p4 = (int4*)&Pw[0][0];
        for (int i = t; i < 1856; i += 256) p4[i] = z;
    }
    __syncthreads();

    for (int i = t; i < NPATCH * 24; i += 256) {
        int r = i / 24, d = i % 24;
        const _Float16* row = base + (size_t)r * 288;
        Qs[r * 40 + d]   = row[d];
        Ks[r * 40 + d]   = row[96 + d];
        Vt[d * 232 + r]  = row[192 + d];
    }
    __syncthreads();

    int wave = t >> 6, lane = t & 63;
    int lm = lane & 15, quad = lane >> 4;
    const float scale = 0.2041241452319315f;

    half8 bk[13];
    #pragma unroll
    for (int ct = 0; ct < 13; ++ct)
        bk[ct] = *(const half8*)&Ks[(ct * 16 + lm) * 40 + quad * 8];

    _Float16* pw = &Pw[wave][0];

    for (int rt = wave; rt < 13; rt += 4) {
        half8 aq = *(const half8*)&Qs[(rt * 16 + lm) * 40 + quad * 8];
        float rsum[4] = {0.f, 0.f, 0.f, 0.f};

        #pragma unroll
        for (int ct = 0; ct < 13; ++ct) {
            f32x4 s = (f32x4){0.f, 0.f, 0.f, 0.f};
            s = __builtin_amdgcn_mfma_f32_16x16x32_f16(aq, bk[ct], s, 0, 0, 0);
            #pragma unroll
            for (int r = 0; r < 4; ++r) {
                float p = __expf(fminf(s[r] * scale, 60.f));
                if (ct == 12 && lm >= 4) p = 0.f;   // keys 196..207 invalid
                rsum[r] += p;
                pw[(quad * 4 + r) * 232 + ct * 16 + lm] = (_Float16)p;
            }
        }

        #pragma unroll
        for (int r = 0; r < 4; ++r) {
            float s = rsum[r];
            s += __shfl_xor(s, 1);
            s += __shfl_xor(s, 2);
            s += __shfl_xor(s, 4);
            s += __shfl_xor(s, 8);
            rsum[r] = 1.f / s;
        }

        f32x4 ov0 = (f32x4){0.f, 0.f, 0.f, 0.f};
        f32x4 ov1 = (f32x4){0.f, 0.f, 0.f, 0.f};
        #pragma unroll
        for (int ks = 0; ks < 7; ++ks) {
            half8 ap = *(const half8*)&pw[lm * 232 + ks * 32 + quad * 8];
            half8 bv0 = *(const half8*)&Vt[(lm) * 232 + ks * 32 + quad * 8];
            half8 bv1 = *(const half8*)&Vt[(16 + lm) * 232 + ks * 32 + quad * 8];
            ov0 = __builtin_amdgcn_mfma_f32_16x16x32_f16(ap, bv0, ov0, 0, 0, 0);
            ov1 = __builtin_amdgcn_mfma_f32_16x16x32_f16(ap, bv1, ov1, 0, 0, 0);
        }

        #pragma unroll
        for (int r = 0; r < 4; ++r) {
            int row = rt * 16 + quad * 4 + r;
            if (row < NPATCH) {
                _Float16* orow = o + ((size_t)b * NPATCH + row) * 96 + h * 24;
                orow[lm] = (_Float16)(ov0[r] * rsum[r]);
                if (lm < 8) orow[16 + lm] = (_Float16)(ov1[r] * rsum[r]);
            }
        }
    }
}

// ---------------------------------------------------------------------------
// conv L1, tile-resident + fused LN partial stats (r16, verified).
// ---------------------------------------------------------------------------
__global__ void __launch_bounds__(256) k_conv1_tile(const _Float16* __restrict__ xinh,
                                                    const _Float16* __restrict__ wc,
                                                    const float* __restrict__ bias,
                                                    _Float16* __restrict__ c1,
                                                    float* __restrict__ pstat1)
{
    __shared__ __align__(16) _Float16 Xs[4 * 16 * 104];   // 13.3 KB
    __shared__ float bins[96];
    int t = threadIdx.x;
    int blk = blockIdx.x;
    int b = blk / 7, s = blk % 7;

    if (t < 96) bins[t] = 0.f;

    for (int i = t; i < 768; i += 256) {
        int r = i / 192, rem = i % 192;
        int c = rem / 12, ch = (rem % 12) * 8;
        *(uint4*)&Xs[(r * 16 + c) * 104 + ch] =
            *(const uint4*)(xinh + ((size_t)(b * 256) + (2 * s + r) * 16 + c) * 96 + ch);
    }

    int wave = t >> 6, lane = t & 63;
    int lm = lane & 15, quad = lane >> 4;
    int ry = wave >> 1, rx = wave & 1;

    __syncthreads();

    for (int nt = 0; nt < 3; ++nt) {
        half8 bf[12];
        #pragma unroll
        for (int ks = 0; ks < 12; ++ks)
            bf[ks] = *(const half8*)&wc[((size_t)(wave * 48 + nt * 16 + lm)) * 384
                                        + ks * 32 + quad * 8];

        float sl = 0.f, ql = 0.f;
        #pragma unroll
        for (int rt = 0; rt < 2; ++rt) {
            int pp = rt * 16 + lm;
            int ppc = pp < 28 ? pp : 27;
            int pyl = ppc / 14, px = ppc % 14;

            half8 af[12];
            #pragma unroll
            for (int ks = 0; ks < 12; ++ks) {
                int k0 = ks * 32 + quad * 8;
                int tap = k0 / 96, off = k0 % 96;
                int dy = tap >> 1, dx = tap & 1;
                af[ks] = *(const half8*)&Xs[((pyl + ry + dy) * 16 + (px + rx + dx)) * 104 + off];
            }

            f32x4 acc = (f32x4){0.f, 0.f, 0.f, 0.f};
            #pragma unroll
            for (int ks = 0; ks < 12; ++ks)
                acc = __builtin_amdgcn_mfma_f32_16x16x32_f16(af[ks], bf[ks], acc, 0, 0, 0);

            #pragma unroll
            for (int r = 0; r < 4; ++r) {
                int pw = rt * 16 + quad * 4 + r;
                if (pw < 28) {
                    int pylw = pw / 14, pxw = pw % 14;
                    int oy = 2 * (2 * s + pylw) + ry, ox = 2 * pxw + rx;
                    float v = acc[r] + bias[nt * 16 + lm];
                    sl += v; ql += v * v;
                    c1[((size_t)(b * 28 + oy) * 28 + ox) * 48 + nt * 16 + lm] = (_Float16)v;
                }
            }
        }
        atomicAdd(&bins[(nt * 16 + lm) * 2],     sl);
        atomicAdd(&bins[(nt * 16 + lm) * 2 + 1], ql);
    }
    __syncthreads();
    if (t < 96) atomicAdd(&pstat1[(size_t)b * 96 + t], bins[t]);
}

// ---------------------------------------------------------------------------
// L1 LN apply (r16, verified).
// ---------------------------------------------------------------------------
__global__ void __launch_bounds__(256) k_ln1_apply(const _Float16* __restrict__ c1,
                                                   const float* __restrict__ pstat1,
                                                   const float* __restrict__ g,
                                                   const float* __restrict__ bv,
                                                   _Float16* __restrict__ xh)
{
    int i4 = blockIdx.x * 256 + threadIdx.x;
    int idx = i4 * 4;
    int ch = idx % 48;
    int t2 = idx / 48;
    int pos = t2 % 900;
    int b = t2 / 900;
    int py = pos / 30, px = pos % 30;
    half4v hv = (half4v){(_Float16)0.f, (_Float16)0.f, (_Float16)0.f, (_Float16)0.f};
    if (py >= 1 && py <= 28 && px >= 1 && px <= 28) {
        int j = (py - 1) * 28 + (px - 1);
        half4v v = *(const half4v*)&c1[((size_t)b * 784 + j) * 48 + ch];
        const float* ps = pstat1 + (size_t)b * 96 + ch * 2;
        float gj = g[j], bj = bv[j];
        #pragma unroll
        for (int k = 0; k < 4; ++k) {
            float mu = ps[2 * k] * (1.f / 784.f);
            float rstd = rsqrtf(ps[2 * k + 1] * (1.f / 784.f) - mu * mu + 1e-5f);
            float u = ((float)v[k] - mu) * rstd * gj + bj;
            hv[k] = (_Float16)(u / (1.f + __expf(-u)));
        }
    }
    *(half4v*)&xh[idx] = hv;
}

// ---------------------------------------------------------------------------
// conv L2, tile-resident + fused LN partial stats (r16, verified).
// ---------------------------------------------------------------------------
__global__ void __launch_bounds__(256) k_conv2_tile(const _Float16* __restrict__ xh,
                                                    const _Float16* __restrict__ wc,
                                                    const float* __restrict__ bias,
                                                    _Float16* __restrict__ c2,
                                                    float* __restrict__ pstat2)
{
    __shared__ __align__(16) _Float16 Xs[4 * 30 * 56];   // 13.1 KB
    __shared__ float bins[48];
    int t = threadIdx.x;
    int blk = blockIdx.x;
    int b = blk / 14, s = blk % 14;

    if (t < 48) bins[t] = 0.f;

    for (int i = t; i < 720; i += 256) {
        int r = i / 180, rem = i % 180;
        int c = rem / 6, ch = (rem % 6) * 8;
        *(uint4*)&Xs[(r * 30 + c) * 56 + ch] =
            *(const uint4*)(xh + ((size_t)(b * 900) + (2 * s + r) * 30 + c) * 48 + ch);
    }

    int wave = t >> 6, lane = t & 63;
    int lm = lane & 15, quad = lane >> 4;
    int ry = wave >> 1, rx = wave & 1;

    half8 bf0[6], bf1[6];
    #pragma unroll
    for (int ks = 0; ks < 6; ++ks) {
        bf0[ks] = *(const half8*)&wc[((size_t)(wave * 32 + lm)) * 192 + ks * 32 + quad * 8];
        bf1[ks] = *(const half8*)&wc[((size_t)(wave * 32 + 16 + lm)) * 192 + ks * 32 + quad * 8];
    }

    __syncthreads();

    float s0l = 0.f, q0l = 0.f, s1l = 0.f, q1l = 0.f;
    #pragma unroll
    for (int rt = 0; rt < 4; ++rt) {
        int pp = rt * 16 + lm;
        int ppc = pp < 56 ? pp : 55;
        int pyl = ppc / 28, px = ppc % 28;

        half8 af[6];
        #pragma unroll
        for (int ks = 0; ks < 6; ++ks) {
            int k0 = ks * 32 + quad * 8;
            int tap = k0 / 48, off = k0 % 48;
            int dy = tap >> 1, dx = tap & 1;
            af[ks] = *(const half8*)&Xs[((pyl + ry + dy) * 30 + (px + rx + dx)) * 56 + off];
        }

        f32x4 acc0 = (f32x4){0.f, 0.f, 0.f, 0.f};
        f32x4 acc1 = (f32x4){0.f, 0.f, 0.f, 0.f};
        #pragma unroll
        for (int ks = 0; ks < 6; ++ks) {
            acc0 = __builtin_amdgcn_mfma_f32_16x16x32_f16(af[ks], bf0[ks], acc0, 0, 0, 0);
            acc1 = __builtin_amdgcn_mfma_f32_16x16x32_f16(af[ks], bf1[ks], acc1, 0, 0, 0);
        }

        #pragma unroll
        for (int r = 0; r < 4; ++r) {
            int pw = rt * 16 + quad * 4 + r;
            if (pw < 56) {
                int pylw = pw / 28, pxw = pw % 28;
                int oy = 2 * (2 * s + pylw) + ry, ox = 2 * pxw + rx;
                _Float16* orow = c2 + ((size_t)(b * 56 + oy) * 56 + ox) * 24;
                float v0 = acc0[r] + bias[lm];
                orow[lm] = (_Float16)v0;
                s0l += v0; q0l += v0 * v0;
                if (lm < 8) {
                    float v1 = acc1[r] + bias[16 + lm];
                    orow[16 + lm] = (_Float16)v1;
                    s1l += v1; q1l += v1 * v1;
                }
            }
        }
    }
    atomicAdd(&bins[lm * 2],     s0l);
    atomicAdd(&bins[lm * 2 + 1], q0l);
    if (lm < 8) {
        atomicAdd(&bins[(16 + lm) * 2],     s1l);
        atomicAdd(&bins[(16 + lm) * 2 + 1], q1l);
    }
    __syncthreads();
    if (t < 48) atomicAdd(&pstat2[(size_t)b * 48 + t], bins[t]);
}

// ---------------------------------------------------------------------------
// L2 LN apply (r16, verified).
// ---------------------------------------------------------------------------
__global__ void __launch_bounds__(256) k_ln2_apply(const _Float16* __restrict__ c2,
                                                   const float* __restrict__ pstat2,
                                                   const float* __restrict__ g,
                                                   const float* __restrict__ bv,
                                                   _Float16* __restrict__ xh)
{
    int i4 = blockIdx.x * 256 + threadIdx.x;
    int idx = i4 * 4;
    int ch = idx % 24;
    int t2 = idx / 24;
    int pos = t2 % 3364;
    int b = t2 / 3364;
    int py = pos / 58, px = pos % 58;
    half4v hv = (half4v){(_Float16)0.f, (_Float16)0.f, (_Float16)0.f, (_Float16)0.f};
    if (py >= 1 && py <= 56 && px >= 1 && px <= 56) {
        int j = (py - 1) * 56 + (px - 1);
        half4v v = *(const half4v*)&c2[((size_t)b * 3136 + j) * 24 + ch];
        const float* ps = pstat2 + (size_t)b * 48 + ch * 2;
        float gj = g[j], bj = bv[j];
        #pragma unroll
        for (int k = 0; k < 4; ++k) {
            float mu = ps[2 * k] * (1.f / 3136.f);
            float rstd = rsqrtf(ps[2 * k + 1] * (1.f / 3136.f) - mu * mu + 1e-5f);
            float u = ((float)v[k] - mu) * rstd * gj + bj;
            hv[k] = (_Float16)(u / (1.f + __expf(-u)));
        }
    }
    *(half4v*)&xh[idx] = hv;
}

// ---------------------------------------------------------------------------
// conv L3, tile-resident + fused LN partial stats (r16, verified).
// ---------------------------------------------------------------------------
__global__ void __launch_bounds__(256) k_conv3_tile(const _Float16* __restrict__ xh,
                                                    const _Float16* __restrict__ wc,
                                                    const float* __restrict__ bias,
                                                    _Float16* __restrict__ c3,
                                                    float* __restrict__ pstat3)
{
    __shared__ __align__(16) _Float16 Xs[3 * 58 * 40];   // 13.6 KB
    __shared__ float bins[24];
    int t = threadIdx.x;
    int blk = blockIdx.x;
    int b = blk / 56, s = blk % 56;

    if (t < 24) bins[t] = 0.f;

    for (int i = t; i < 522; i += 256) {
        int r = i / 174, rem = i % 174;
        int c = rem / 3, ch = (rem % 3) * 8;
        *(uint4*)&Xs[(r * 58 + c) * 40 + ch] =
            *(const uint4*)(xh + ((size_t)(b * 3364) + (s + r) * 58 + c) * 24 + ch);
    }

    int wave = t >> 6, lane = t & 63;
    int lm = lane & 15, quad = lane >> 4;
    int ry = wave >> 1, rx = wave & 1;

    half8 bf[3];
    #pragma unroll
    for (int ks = 0; ks < 3; ++ks)
        bf[ks] = *(const half8*)&wc[((size_t)(wave * 16 + lm)) * 96 + ks * 32 + quad * 8];

    __syncthreads();

    float sl = 0.f, ql = 0.f;
    #pragma unroll
    for (int rt = 0; rt < 4; ++rt) {
        int px = rt * 16 + lm;
        int pxc = px < 56 ? px : 55;

        half8 af[3];
        #pragma unroll
        for (int ks = 0; ks < 3; ++ks) {
            int k0 = ks * 32 + quad * 8;
            int tap = k0 / 24, off = k0 % 24;
            int dy = tap >> 1, dx = tap & 1;
            af[ks] = *(const half8*)&Xs[((ry + dy) * 58 + (pxc + rx + dx)) * 40 + off];
        }

        f32x4 acc = (f32x4){0.f, 0.f, 0.f, 0.f};
        #pragma unroll
        for (int ks = 0; ks < 3; ++ks)
            acc = __builtin_amdgcn_mfma_f32_16x16x32_f16(af[ks], bf[ks], acc, 0, 0, 0);

        if (lm < 12) {
            #pragma unroll
            for (int r = 0; r < 4; ++r) {
                int pw = rt * 16 + quad * 4 + r;
                if (pw < 56) {
                    int oy = 2 * s + ry, ox = 2 * pw + rx;
                    float v = acc[r] + bias[lm];
                    sl += v; ql += v * v;
                    c3[((size_t)(b * 112 + oy) * 112 + ox) * 12 + lm] = (_Float16)v;
                }
            }
        }
    }
    if (lm < 12) {
        atomicAdd(&bins[lm * 2],     sl);
        atomicAdd(&bins[lm * 2 + 1], ql);
    }
    __syncthreads();
    if (t < 24) atomicAdd(&pstat3[(size_t)b * 24 + t], bins[t]);
}

// ---------------------------------------------------------------------------
// L3 LN apply (r16, verified).
// ---------------------------------------------------------------------------
__global__ void __launch_bounds__(256) k_ln3_apply(const _Float16* __restrict__ c3,
                                                   const float* __restrict__ pstat3,
                                                   const float* __restrict__ g,
                                                   const float* __restrict__ bv,
                                                   _Float16* __restrict__ xh4)
{
    int i4 = blockIdx.x * 256 + threadIdx.x;
    int idx = i4 * 4;
    int ch = idx % 12;
    int t2 = idx / 12;
    int pix = t2 % 12544;
    int b = t2 / 12544;
    half4v v = *(const half4v*)&c3[idx];
    const float* ps = pstat3 + (size_t)b * 24 + ch * 2;
    float gp = g[pix], bp = bv[pix];
    half4v hv;
    #pragma unroll
    for (int k = 0; k < 4; ++k) {
        float mu = ps[2 * k] * (1.f / 12544.f);
        float rstd = rsqrtf(ps[2 * k + 1] * (1.f / 12544.f) - mu * mu + 1e-5f);
        float u = ((float)v[k] - mu) * rstd * gp + bp;
        hv[k] = (_Float16)(u / (1.f + __expf(-u)));
    }
    *(half4v*)&xh4[idx] = hv;
}

// ---------------------------------------------------------------------------
// final convT 12->1 via LDS staging + fdot2 (r19, verified). grid 7168.
// ---------------------------------------------------------------------------
__global__ void __launch_bounds__(256) k_conv_final3(const _Float16* __restrict__ x,
                                                     const _Float16* __restrict__ wcf,
                                                     const float* __restrict__ bias,
                                                     float* __restrict__ out)
{
    constexpr int HIN = 112, CIN = 12;
    __shared__ __align__(16) _Float16 Xs[4 * 114 * 12];   // 10.9 KB
    __shared__ __align__(16) _Float16 Wl[192];
    int t = threadIdx.x;
    int blk = blockIdx.x;
    int b = blk / 56, s = blk % 56;
    int py0 = 2 * s;

    {
        const int4 z = {0, 0, 0, 0};
        int4* p4 = (int4*)Xs;
        for (int i = t; i < 684; i += 256) p4[i] = z;
        if (t < 24) *(int4*)&Wl[t * 8] = *(const int4*)&wcf[t * 8];
    }
    __syncthreads();
    for (int i = t; i < 672; i += 256) {
        int r = i / 168, rem = i % 168;
        int row = py0 - 1 + r;
        if (row >= 0 && row < HIN) {
            *(uint4*)&Xs[(size_t)r * 1368 + rem * 8] =
                *(const uint4*)(x + ((size_t)b * HIN * HIN + (size_t)row * HIN) * CIN + rem * 8);
        }
    }
    __syncthreads();

    if (t >= 224) return;
    int pyl = t / 112;
    int px = t % 112;
    int py = py0 + pyl;

    half2v tvp[9][6];
    #pragma unroll
    for (int a = 0; a < 3; ++a) {
        int lr = pyl + a;
        #pragma unroll
        for (int c = 0; c < 3; ++c) {
            int col = px - 1 + c;
            int cs = (col < 0) ? 113 : col;
            const _Float16* p = &Xs[((size_t)lr * 114 + cs) * 12];
            half4v h0 = *(const half4v*)&p[0];
            half4v h1 = *(const half4v*)&p[4];
            half4v h2 = *(const half4v*)&p[8];
            int ti = a * 3 + c;
            tvp[ti][0] = (half2v){h0[0], h0[1]};
            tvp[ti][1] = (half2v){h0[2], h0[3]};
            tvp[ti][2] = (half2v){h1[0], h1[1]};
            tvp[ti][3] = (half2v){h1[2], h1[3]};
            tvp[ti][4] = (half2v){h2[0], h2[1]};
            tvp[ti][5] = (half2v){h2[2], h2[3]};
        }
    }

    float bb = bias[0];
    float* ob = out + (size_t)b * 50176;
    #pragma unroll
    for (int ry = 0; ry < 2; ++ry) {
        float res[2];
        #pragma unroll
        for (int rx = 0; rx < 2; ++rx) {
            int p = ry * 2 + rx;
            float acc = 0.f;
            #pragma unroll
            for (int dy = 0; dy < 2; ++dy) {
                #pragma unroll
                for (int dx = 0; dx < 2; ++dx) {
                    int j = dy * 2 + dx;
                    int ti = (ry + dy) * 3 + (rx + dx);
                    const half2v* wp = (const half2v*)&Wl[(p * 4 + j) * 12];
                    #pragma unroll
                    for (int k = 0; k < 6; ++k)
                        acc = __builtin_amdgcn_fdot2(tvp[ti][k], wp[k], acc, false);
                }
            }
            float u = acc + bb;
            u = u / (1.f + __expf(-u));
            res[rx] = fminf(fmaxf(u, 0.f), 1.f);
        }
        float2 v; v.x = res[0]; v.y = res[1];
        *(float2*)(ob + (size_t)(2 * py + ry) * 224 + 2 * px) = v;
    }
}

// ---------------------------------------------------------------------------
// launch
// ---------------------------------------------------------------------------
extern "C" void kernel_launch(void* const* d_in, const int* in_sizes, int n_in,
                              void* d_out, int out_size, void* d_ws, size_t ws_size,
                              hipStream_t stream)
{
    const float* x       = (const float*)d_in[0];
    const float* ts      = (const float*)d_in[1];
    const float* Wp      = (const float*)d_in[2];
    const float* bp      = (const float*)d_in[3];
    const float* Wt1     = (const float*)d_in[4];
    const float* bt1     = (const float*)d_in[5];
    const float* Wt2     = (const float*)d_in[6];
    const float* bt2     = (const float*)d_in[7];
    const float* a0_g    = (const float*)d_in[8];
    const float* a0_b    = (const float*)d_in[9];
    const float* a0_Wqkv = (const float*)d_in[10];
    const float* a0_bqkv = (const float*)d_in[11];
    const float* a0_Wo   = (const float*)d_in[12];
    const float* a0_bo   = (const float*)d_in[13];
    const float* a1_g    = (const float*)d_in[14];
    const float* a1_b    = (const float*)d_in[15];
    const float* a1_Wqkv = (const float*)d_in[16];
    const float* a1_bqkv = (const float*)d_in[17];
    const float* a1_Wo   = (const float*)d_in[18];
    const float* a1_bo   = (const float*)d_in[19];
    const float* Wm0     = (const float*)d_in[20];
    const float* bm0     = (const float*)d_in[21];
    const float* Wm1     = (const float*)d_in[22];
    const float* bm1     = (const float*)d_in[23];
    const float* Wm2     = (const float*)d_in[24];
    const float* bm2     = (const float*)d_in[25];
    const float* Wd1     = (const float*)d_in[26];
    const float* bd1     = (const float*)d_in[27];
    const float* l1g     = (const float*)d_in[28];
    const float* l1b     = (const float*)d_in[29];
    const float* Wd2     = (const float*)d_in[30];
    const float* bd2     = (const float*)d_in[31];
    const float* l2g     = (const float*)d_in[32];
    const float* l2b     = (const float*)d_in[33];
    const float* Wd3     = (const float*)d_in[34];
    const float* bd3     = (const float*)d_in[35];
    const float* l3g     = (const float*)d_in[36];
    const float* l3b     = (const float*)d_in[37];
    const float* Wd4     = (const float*)d_in[38];
    const float* bd4     = (const float*)d_in[39];
    float* out = (float*)d_out;

    // arena (floats); R = 25088*96
    const size_t R = 2408448;
    float* ws   = (float*)d_ws;
    float* tvec = ws;                          // 96
    float* p0   = ws + 512;                    // R (fp32 residual; f16 alias p0h)
    _Float16* p0h  = (_Float16*)(ws + 512);           // f16 wo1 out (p0 region)
    _Float16* hh   = (_Float16*)(ws + 512 + R);       // f16 LN out (h region)
    _Float16* qkvh = (_Float16*)(ws + 512 + 2 * R);   // f16 qkv [M][288]
    _Float16* obh  = (_Float16*)(ws + 512 + 5 * R);   // f16 attn out (ob region)
    float* p1   = ws + 512 + 6 * R;            // R
    // decoder aliases:
    _Float16* xinh = (_Float16*)(ws + 512 + 2 * R);   // f16 NHWC (qkv region)
    _Float16* C1h  = (_Float16*)(ws + 512 + 5 * R);   // f16 NHWC [b][28][28][48]
    _Float16* xh2  = (_Float16*)(ws + 512 + 7 * R);   // f16 NHWC padded [b][30][30][48]
    _Float16* C2h  = (_Float16*)(ws + 512);           // f16 NHWC [b][56][56][24]
    _Float16* xh3  = (_Float16*)(ws + 512 + 7 * R + 5529600); // f16 padded [b][58][58][24]
    _Float16* C3h  = (_Float16*)(ws + 512);           // f16 NHWC [b][112][112][12]
    _Float16* xh4  = (_Float16*)(ws + 512 + 7 * R + 5529600); // f16 [b][112][112][12]
    float* Wr   = ws + 512 + 7 * R + 5529600 + 10334208;  // 96,960 floats
    _Float16* WH = (_Float16*)(Wr + 96960);                // 101,376 halves
    _Float16* Wc  = (_Float16*)Wr;
    _Float16* Wc2 = (_Float16*)(Wr + 36864);
    _Float16* Wc3 = (_Float16*)(Wr + 49152);
    float* stat = Wr + 96960 + 50688;          // 21,504 floats (raw LN sums)
    float* stat1 = stat;                       // 128*96
    float* stat2 = stat + 12288;               // 128*48
    float* stat3 = stat + 18432;               // 128*24
    _Float16* Wcf = (_Float16*)(stat + 21504); // 192 halves (conv_final f16 w)
    _Float16* Wph = (_Float16*)(stat + 21504 + 128); // 24576 halves (patch f16 w)
    const size_t NEED = (512 + 7 * R + 5529600 + 10334208 + 96960 + 50688 + 21504
                         + 128 + 12288 + 16) * sizeof(float);
    if (ws_size < NEED) return;

    _Float16* WHqkv0 = WH;
    _Float16* WHqkv1 = WH + 27648;
    _Float16* WHwo0  = WH + 55296;
    _Float16* WHwo1  = WH + 64512;
    _Float16* WHwm0  = WH + 73728;   // wm0,wm1,wm2 consecutive

    k_time<<<1, 128, 0, stream>>>(ts, Wt1, bt1, Wt2, bt2, tvec);
    k_zstat<<<84, 256, 0, stream>>>(stat);
    k_repack<<<379, 256, 0, stream>>>(Wd1, Wd2, Wd3, Wd4, Wr);
    k_wcvt4<<<1, 192, 0, stream>>>(Wr + 96768, Wcf);
    k_wcvtp<<<96, 256, 0, stream>>>(Wp, Wph);
    k_wcvtc<<<288, 256, 0, stream>>>(Wd1, Wc);
    k_wcvt2<<<96, 256, 0, stream>>>(Wd2, Wc2);
    k_wcvt3<<<24, 256, 0, stream>>>(Wd3, Wc3);
    k_wcvt<<<396, 256, 0, stream>>>(a0_Wqkv, a1_Wqkv, a0_Wo, a1_Wo,
                                    Wm0, Wm1, Wm2, WH);
    k_patch_mfma<<<M_ROWS / 32, 256, 0, stream>>>(x, Wph, bp, p0);

    // MHSA block 0
    k_ln_row<<<1024, 256, 0, stream>>>(p0, a0_g, a0_b, hh, M_ROWS);
    k_gemm_mfma<3, 1, false, false, false, true><<<dim3(M_ROWS / 64, 3), 256, 0, stream>>>(
        hh, WHqkv0, a0_bqkv, nullptr, nullptr, qkvh);
    k_attn_mfma<<<B_ * 4, 256, 0, stream>>>(qkvh, obh);
    k_gemm_mfma<1, 0, false, true, false, true><<<dim3(M_ROWS / 64, 1), 256, 0, stream>>>(
        obh, WHwo0, a0_bo, p0, nullptr, p1);

    // MHSA block 1 (+time)
    k_ln_row<<<1024, 256, 0, stream>>>(p1, a1_g, a1_b, hh, M_ROWS);
    k_gemm_mfma<3, 1, false, false, false, true><<<dim3(M_ROWS / 64, 3), 256, 0, stream>>>(
        hh, WHqkv1, a1_bqkv, nullptr, nullptr, qkvh);
    k_attn_mfma<<<B_ * 4, 256, 0, stream>>>(qkvh, obh);
    // wo1 + residual + time -> f16 p0h (only consumer: MLP)
    k_gemm_mfma<1, 1, false, true, true, true><<<dim3(M_ROWS / 64, 1), 256, 0, stream>>>(
        obh, WHwo1, a1_bo, p1, tvec, p0h);

    // qkv region free: zero xinh borders before MLP writes interior
    k_zb_h<<<2880, 256, 0, stream>>>(xinh);

    // fused MLP x3 (silu); writes f16 NHWC padded xinh
    k_mlp_fused<<<M_ROWS / 64, 256, 0, stream>>>(p0h, WHwm0, bm0, bm1, bm2, xinh);

    // decoder: all-NHWC f16 chain, tile-resident convs with fused LN stats
    k_conv1_tile<<<B_ * 7, 256, 0, stream>>>(xinh, Wc, bd1, C1h, stat1);
    k_ln1_apply<<<5400, 256, 0, stream>>>(C1h, stat1, l1g, l1b, xh2);
    k_conv2_tile<<<B_ * 14, 256, 0, stream>>>(xh2, Wc2, bd2, C2h, stat2);
    k_ln2_apply<<<10092, 256, 0, stream>>>(C2h, stat2, l2g, l2b, xh3);
    k_conv3_tile<<<B_ * 56, 256, 0, stream>>>(xh3, Wc3, bd3, C3h, stat3);
    k_ln3_apply<<<18816, 256, 0, stream>>>(C3h, stat3, l3g, l3b, xh4);
    k_conv_final3<<<7168, 256, 0, stream>>>(xh4, Wcf, bd4, out);
}

// Round 13
// 428.195 us; speedup vs baseline: 1.1283x; 1.0065x over previous
//
#include <hip/hip_runtime.h>
#include <cmath>

// ---------------------------------------------------------------------------
// TimestepVisionTransformer — Round 21: LN-apply fused into conv staging.
//   - conv2/conv3/conv_final3 stage DIRECTLY from C1h/C2h/C3h applying
//     LN+silu on the fly (stats ready; same f16 rounding points) ->
//     k_ln{1,2,3}_apply DELETED, xh2/xh3/xh4 buffers gone (~138MB traffic).
//   - C3h relocated to the freed xh3 slot (avoids overlap with C2h).
// Everything else = r20 (verified, 431us best).
// B=128, IMG=224, P=16, C_IN=1, E=96, H=4, d=24, NAX=14, N=196, M=B*N=25088
// ---------------------------------------------------------------------------

#define B_   128
#define NPATCH 196
#define M_ROWS (B_*NPATCH)     // 25088
#define E_   96

typedef _Float16 half8 __attribute__((ext_vector_type(8)));
typedef _Float16 half4v __attribute__((ext_vector_type(4)));
typedef _Float16 half2v __attribute__((ext_vector_type(2)));
typedef float f32x4 __attribute__((ext_vector_type(4)));

// ---------------------------------------------------------------------------
// time embedding
// ---------------------------------------------------------------------------
__global__ void k_time(const float* __restrict__ ts,
                       const float* __restrict__ Wt1, const float* __restrict__ bt1,
                       const float* __restrict__ Wt2, const float* __restrict__ bt2,
                       float* __restrict__ timev)
{
    __shared__ float h[128];
    float e = 0.69314718055994530942f * ts[0];
    float sv = sinf(e), cv = cosf(e);
    int t = threadIdx.x;
    float z = sv * Wt1[t] + cv * Wt1[128 + t] + bt1[t];
    h[t] = z / (1.f + expf(-z));
    __syncthreads();
    if (t < 96) {
        float acc = bt2[t];
        for (int j = 0; j < 128; ++j) acc += h[j] * Wt2[j * 96 + t];
        timev[t] = acc;
    }
}

// ---------------------------------------------------------------------------
// zero LN partial-stat table (21504 floats)
// ---------------------------------------------------------------------------
__global__ void __launch_bounds__(256) k_zstat(float* __restrict__ stat)
{
    int i = blockIdx.x * 256 + threadIdx.x;
    if (i < 21504) stat[i] = 0.f;
}

// ---------------------------------------------------------------------------
// weight repack (fp32 per-parity taps). L4 slice [96768,96960) feeds k_wcvt4;
// other slices overwritten by f16 packs.
// ---------------------------------------------------------------------------
__global__ void __launch_bounds__(256) k_repack(const float* __restrict__ w1,
                                                const float* __restrict__ w2,
                                                const float* __restrict__ w3,
                                                const float* __restrict__ w4f,
                                                float* __restrict__ wr)
{
    int i = blockIdx.x * 256 + threadIdx.x;
    const float* src; int CIN, COUT, e; float* dst;
    if      (i < 73728) { src = w1;  CIN = 96; COUT = 48; e = i;          dst = wr; }
    else if (i < 92160) { src = w2;  CIN = 48; COUT = 24; e = i - 73728;  dst = wr + 73728; }
    else if (i < 96768) { src = w3;  CIN = 24; COUT = 12; e = i - 92160;  dst = wr + 92160; }
    else if (i < 96960) { src = w4f; CIN = 12; COUT = 1;  e = i - 96768;  dst = wr + 96768; }
    else return;
    int per = CIN * COUT * 4;
    int par = e / per, rem = e % per;
    int ci = rem / (COUT * 4);
    int o  = (rem >> 2) % COUT;
    int j  = rem & 3;
    int ry = par >> 1, rx = par & 1;
    int wy = (j < 2)  ? (3 - ry) : (1 - ry);
    int wx = (j & 1)  ? (1 - rx) : (3 - rx);
    dst[e] = src[(ci * COUT + o) * 16 + wy * 4 + wx];
}

// ---------------------------------------------------------------------------
// conv_final weights -> f16 wcf[p][j][ci] (192 halves) from fp32 [p][ci][j]
// ---------------------------------------------------------------------------
__global__ void k_wcvt4(const float* __restrict__ wr4,
                        _Float16* __restrict__ wcf)
{
    int i = threadIdx.x;
    if (i >= 192) return;
    int p = i / 48, rem = i % 48;
    int j = rem / 12, ci = rem % 12;
    wcf[(p * 4 + j) * 12 + ci] = (_Float16)wr4[p * 48 + ci * 4 + j];
}

// ---------------------------------------------------------------------------
// patch weights -> f16 wph[kc][e][k] (24576 halves), k in [0,128)
// ---------------------------------------------------------------------------
__global__ void __launch_bounds__(256) k_wcvtp(const float* __restrict__ Wp,
                                               _Float16* __restrict__ wph)
{
    int i = blockIdx.x * 256 + threadIdx.x;
    if (i >= 24576) return;
    int kc = i / 12288, rem = i % 12288;
    int e = rem / 128, k = rem % 128;
    wph[i] = (_Float16)Wp[e * 256 + kc * 128 + k];
}

// ---------------------------------------------------------------------------
// conv1 weights -> f16 B-layout Wc[p][o][k=tap*96+ci]
// ---------------------------------------------------------------------------
__global__ void __launch_bounds__(256) k_wcvtc(const float* __restrict__ w1,
                                               _Float16* __restrict__ wc)
{
    int i = blockIdx.x * 256 + threadIdx.x;
    if (i >= 4 * 48 * 384) return;
    int p = i / 18432, rem = i % 18432;
    int o = rem / 384, k = rem % 384;
    int tap = k / 96, ci = k % 96;
    int ry = p >> 1, rx = p & 1;
    int wy = (tap < 2) ? (3 - ry) : (1 - ry);
    int wx = (tap & 1) ? (1 - rx) : (3 - rx);
    wc[i] = (_Float16)w1[(ci * 48 + o) * 16 + wy * 4 + wx];
}

// ---------------------------------------------------------------------------
// conv2 weights -> f16 B-layout Wc2[p][o(32, o>=24 zero)][k=tap*48+ci]
// ---------------------------------------------------------------------------
__global__ void __launch_bounds__(256) k_wcvt2(const float* __restrict__ w2,
                                               _Float16* __restrict__ wc2)
{
    int i = blockIdx.x * 256 + threadIdx.x;
    if (i >= 4 * 32 * 192) return;
    int p = i / 6144, rem = i % 6144;
    int o = rem / 192, k = rem % 192;
    int tap = k / 48, ci = k % 48;
    int ry = p >> 1, rx = p & 1;
    int wy = (tap < 2) ? (3 - ry) : (1 - ry);
    int wx = (tap & 1) ? (1 - rx) : (3 - rx);
    wc2[i] = (o < 24) ? (_Float16)w2[(ci * 24 + o) * 16 + wy * 4 + wx]
                      : (_Float16)0.f;
}

// ---------------------------------------------------------------------------
// conv3 weights -> f16 B-layout Wc3[p][o(16, o>=12 zero)][k=tap*24+ci]
// ---------------------------------------------------------------------------
__global__ void __launch_bounds__(256) k_wcvt3(const float* __restrict__ w3,
                                               _Float16* __restrict__ wc3)
{
    int i = blockIdx.x * 256 + threadIdx.x;
    if (i >= 4 * 16 * 96) return;
    int p = i / 1536, rem = i % 1536;
    int o = rem / 96, k = rem % 96;
    int tap = k / 24, ci = k % 24;
    int ry = p >> 1, rx = p & 1;
    int wy = (tap < 2) ? (3 - ry) : (1 - ry);
    int wx = (tap & 1) ? (1 - rx) : (3 - rx);
    wc3[i] = (o < 12) ? (_Float16)w3[(ci * 12 + o) * 16 + wy * 4 + wx]
                      : (_Float16)0.f;
}

// ---------------------------------------------------------------------------
// transformer weight convert+transpose to half: Wt[n][k] = W[k][n]
// ---------------------------------------------------------------------------
__global__ void __launch_bounds__(256) k_wcvt(const float* __restrict__ qkv0,
                                              const float* __restrict__ qkv1,
                                              const float* __restrict__ wo0,
                                              const float* __restrict__ wo1,
                                              const float* __restrict__ wm0,
                                              const float* __restrict__ wm1,
                                              const float* __restrict__ wm2,
                                              _Float16* __restrict__ wh)
{
    int i = blockIdx.x * 256 + threadIdx.x;
    const float* src; int N; int e;
    if      (i < 27648)  { src = qkv0; N = 288; e = i; }
    else if (i < 55296)  { src = qkv1; N = 288; e = i - 27648; }
    else if (i < 64512)  { src = wo0;  N = 96;  e = i - 55296; }
    else if (i < 73728)  { src = wo1;  N = 96;  e = i - 64512; }
    else if (i < 82944)  { src = wm0;  N = 96;  e = i - 73728; }
    else if (i < 92160)  { src = wm1;  N = 96;  e = i - 82944; }
    else if (i < 101376) { src = wm2;  N = 96;  e = i - 92160; }
    else return;
    int n = e / 96, k = e % 96;
    wh[i] = (_Float16)src[k * N + n];
}

// ---------------------------------------------------------------------------
// zero the borders of xinh NHWC f16 [b][16][16][96]
// ---------------------------------------------------------------------------
__global__ void __launch_bounds__(256) k_zb_h(_Float16* __restrict__ xinh)
{
    int i = blockIdx.x * 256 + threadIdx.x;
    if (i >= 128 * 60 * 96) return;
    int b = i / 5760, r = i % 5760;
    int pos = r / 96, ch = r % 96;
    int py, px;
    if      (pos < 16) { py = 0;        px = pos; }
    else if (pos < 32) { py = 15;       px = pos - 16; }
    else if (pos < 46) { py = pos - 31; px = 0; }
    else               { py = pos - 45; px = 15; }
    xinh[((size_t)(b * 256) + py * 16 + px) * 96 + ch] = (_Float16)0.f;
}

// ---------------------------------------------------------------------------
// patch embed GEMM, occupancy-fixed (r20, verified): 32 patches/block.
// ---------------------------------------------------------------------------
__global__ void __launch_bounds__(256) k_patch_mfma(const float* __restrict__ x,
                                                    const _Float16* __restrict__ wph,
                                                    const float* __restrict__ bp,
                                                    float* __restrict__ out)
{
    __shared__ __align__(16) _Float16 Ah[32 * 136];
    __shared__ __align__(16) _Float16 Wh[96 * 136];
    int t = threadIdx.x;
    int p0 = blockIdx.x * 32;
    int wave = t >> 6, lane = t & 63;
    int lm = lane & 15, quad = lane >> 4;
    int rt = wave >> 1, nh = wave & 1;
    f32x4 acc[3];
    #pragma unroll
    for (int nt = 0; nt < 3; ++nt) acc[nt] = (f32x4){0.f, 0.f, 0.f, 0.f};

    for (int kc = 0; kc < 2; ++kc) {
        __syncthreads();
        {
            int lp = t >> 3, pyl = t & 7;
            int patch = p0 + lp;
            int b = patch / NPATCH, n = patch % NPATCH;
            int ny = n / 14, nx = n % 14;
            const float4* s4 = (const float4*)(x +
                ((size_t)(b * 224) + ny * 16 + kc * 8 + pyl) * 224 + nx * 16);
            float4 v0 = s4[0], v1 = s4[1], v2 = s4[2], v3 = s4[3];
            half8 h0, h1;
            h0[0]=(_Float16)v0.x; h0[1]=(_Float16)v0.y; h0[2]=(_Float16)v0.z; h0[3]=(_Float16)v0.w;
            h0[4]=(_Float16)v1.x; h0[5]=(_Float16)v1.y; h0[6]=(_Float16)v1.z; h0[7]=(_Float16)v1.w;
            h1[0]=(_Float16)v2.x; h1[1]=(_Float16)v2.y; h1[2]=(_Float16)v2.z; h1[3]=(_Float16)v2.w;
            h1[4]=(_Float16)v3.x; h1[5]=(_Float16)v3.y; h1[6]=(_Float16)v3.z; h1[7]=(_Float16)v3.w;
            *(half8*)&Ah[lp * 136 + pyl * 16]     = h0;
            *(half8*)&Ah[lp * 136 + pyl * 16 + 8] = h1;
        }
        {
            const uint4* src = (const uint4*)(wph + (size_t)kc * 12288);
            for (int i = t; i < 1536; i += 256) {
                int e = i >> 4, s = i & 15;
                *(uint4*)&Wh[e * 136 + s * 8] = src[i];
            }
        }
        __syncthreads();
        half8 af[4];
        #pragma unroll
        for (int ks = 0; ks < 4; ++ks)
            af[ks] = *(const half8*)&Ah[(rt * 16 + lm) * 136 + ks * 32 + quad * 8];
        #pragma unroll
        for (int ks = 0; ks < 4; ++ks) {
            #pragma unroll
            for (int nt = 0; nt < 3; ++nt) {
                half8 bf = *(const half8*)&Wh[((nh * 3 + nt) * 16 + lm) * 136 + ks * 32 + quad * 8];
                acc[nt] = __builtin_amdgcn_mfma_f32_16x16x32_f16(af[ks], bf, acc[nt], 0, 0, 0);
            }
        }
    }

    #pragma unroll
    for (int nt = 0; nt < 3; ++nt) {
        #pragma unroll
        for (int r = 0; r < 4; ++r) {
            int e = (nh * 3 + nt) * 16 + lm;
            int lp = rt * 16 + quad * 4 + r;
            int patch = p0 + lp;
            int n = patch % NPATCH;
            int ny = n / 14, nx = n % 14;
            float yx = (float)(ny + nx);
            float v = acc[nt][r] + bp[e];
            float other = __shfl_xor(v, 1);
            float fi = (float)(e >> 1);
            float theta = expf(fi * (-2.f / 96.f) * 9.210340371976184f);
            float ang = theta * yx;
            float c = cosf(ang), s = sinf(ang);
            float outv = (lm & 1) ? (other * s + v * c) : (v * c - other * s);
            out[(size_t)patch * 96 + e] = outv;
        }
    }
}

// ---------------------------------------------------------------------------
// row LayerNorm over 96, wave per row — writes f16.
// ---------------------------------------------------------------------------
__global__ void __launch_bounds__(256) k_ln_row(const float* __restrict__ x,
                                                const float* __restrict__ g,
                                                const float* __restrict__ bv,
                                                _Float16* __restrict__ out, int M)
{
    int lane = threadIdx.x & 63;
    int gw = (blockIdx.x * 256 + threadIdx.x) >> 6;
    int nw = (gridDim.x * 256) >> 6;
    float g0 = g[lane], b0 = bv[lane];
    float g1 = 0.f, b1 = 0.f;
    if (lane < 32) { g1 = g[64 + lane]; b1 = bv[64 + lane]; }
    for (int r = gw; r < M; r += nw) {
        const float* xr = x + (size_t)r * 96;
        float a = xr[lane];
        float c = (lane < 32) ? xr[64 + lane] : 0.f;
        float s = a + c, q = a * a + c * c;
        #pragma unroll
        for (int off = 32; off; off >>= 1) {
            s += __shfl_xor(s, off);
            q += __shfl_xor(q, off);
        }
        float mu = s * (1.f / 96.f);
        float rstd = rsqrtf(q * (1.f / 96.f) - mu * mu + 1e-5f);
        _Float16* orow = out + (size_t)r * 96;
        orow[lane] = (_Float16)((a - mu) * rstd * g0 + b0);
        if (lane < 32) orow[64 + lane] = (_Float16)((c - mu) * rstd * g1 + b1);
    }
}

// ---------------------------------------------------------------------------
// MFMA row GEMM (r16, verified). AHALF: A f16. OUTMODE: 0=fp32, 1=f16.
// Chunks over blockIdx.y.
// ---------------------------------------------------------------------------
template<int NCHUNKS, int OUTMODE, bool SILU, bool RES, bool ADDTIME, bool AHALF>
__global__ void __launch_bounds__(256) k_gemm_mfma(const void* __restrict__ A,
                                                   const _Float16* __restrict__ Wt,
                                                   const float* __restrict__ bias,
                                                   const float* __restrict__ res,
                                                   const float* __restrict__ timev,
                                                   void* __restrict__ outp)
{
    __shared__ __align__(16) _Float16 Ah[64 * 96];
    __shared__ __align__(16) _Float16 Wh[96 * 96];
    constexpr int NTOT = NCHUNKS * 96;
    int t = threadIdx.x;
    size_t row0 = (size_t)blockIdx.x * 64;

    if constexpr (AHALF) {
        const uint4* a4 = (const uint4*)((const _Float16*)A + row0 * 96);
        uint4* dst = (uint4*)Ah;
        for (int i = t; i < 768; i += 256) dst[i] = a4[i];
    } else {
        const float4* a4 = (const float4*)((const float*)A + row0 * 96);
        for (int i = t; i < 1536; i += 256) {
            float4 v = a4[i];
            half4v hv;
            hv[0] = (_Float16)v.x; hv[1] = (_Float16)v.y;
            hv[2] = (_Float16)v.z; hv[3] = (_Float16)v.w;
            *(half4v*)&Ah[i * 4] = hv;
        }
    }

    int wave = t >> 6, lane = t & 63;
    int lm = lane & 15, quad = lane >> 4;
    const f32x4 vzero = {0.f, 0.f, 0.f, 0.f};

    for (int ch = blockIdx.y; ch < NCHUNKS; ch += gridDim.y) {
        __syncthreads();
        {
            const uint4* src = (const uint4*)(Wt + (size_t)ch * 9216);
            uint4* dst = (uint4*)Wh;
            for (int i = t; i < 1152; i += 256) dst[i] = src[i];
        }
        __syncthreads();

        half8 af[3];
        #pragma unroll
        for (int ks = 0; ks < 3; ++ks)
            af[ks] = *(const half8*)&Ah[(wave * 16 + lm) * 96 + ks * 32 + quad * 8];

        f32x4 acc[6];
        #pragma unroll
        for (int ct = 0; ct < 6; ++ct) acc[ct] = vzero;

        #pragma unroll
        for (int ct = 0; ct < 6; ++ct) {
            #pragma unroll
            for (int ks = 0; ks < 3; ++ks) {
                half8 bf = *(const half8*)&Wh[(ct * 16 + lm) * 96 + ks * 32 + quad * 8];
                acc[ct] = __builtin_amdgcn_mfma_f32_16x16x32_f16(af[ks], bf, acc[ct], 0, 0, 0);
            }
        }

        #pragma unroll
        for (int ct = 0; ct < 6; ++ct) {
            #pragma unroll
            for (int r = 0; r < 4; ++r) {
                int lr = wave * 16 + quad * 4 + r;
                size_t row = row0 + lr;
                int lc = ct * 16 + lm;
                int col = ch * 96 + lc;
                float v = acc[ct][r] + bias[col];
                if constexpr (RES)     v += res[row * 96 + lc];
                if constexpr (ADDTIME) v += timev[lc];
                if constexpr (SILU)    v = v / (1.f + __expf(-v));
                if constexpr (OUTMODE == 0) {
                    ((float*)outp)[row * NTOT + col] = v;
                } else {
                    ((_Float16*)outp)[row * NTOT + col] = (_Float16)v;
                }
            }
        }
    }
}

// ---------------------------------------------------------------------------
// fused MLP (f16 input): 3 chained 96x96 GEMMs + silu, one kernel.
// ---------------------------------------------------------------------------
__global__ void __launch_bounds__(256) k_mlp_fused(const _Float16* __restrict__ A,
                                                   const _Float16* __restrict__ W,
                                                   const float* __restrict__ b0,
                                                   const float* __restrict__ b1,
                                                   const float* __restrict__ b2,
                                                   _Float16* __restrict__ outh)
{
    __shared__ __align__(16) _Float16 Ah[2][64 * 96];
    __shared__ __align__(16) _Float16 Wh[3][96 * 96];
    int t = threadIdx.x;
    size_t row0 = (size_t)blockIdx.x * 64;

    {
        const uint4* a4 = (const uint4*)(A + row0 * 96);
        uint4* dst = (uint4*)&Ah[0][0];
        for (int i = t; i < 768; i += 256) dst[i] = a4[i];
    }
    {
        const uint4* src = (const uint4*)W;
        uint4* dst = (uint4*)&Wh[0][0];
        for (int i = t; i < 3456; i += 256) dst[i] = src[i];
    }

    int wave = t >> 6, lane = t & 63;
    int lm = lane & 15, quad = lane >> 4;
    const float* biases[3] = { b0, b1, b2 };
    int cur = 0;

    #pragma unroll
    for (int s = 0; s < 3; ++s) {
        __syncthreads();
        half8 af[3];
        #pragma unroll
        for (int ks = 0; ks < 3; ++ks)
            af[ks] = *(const half8*)&Ah[cur][(wave * 16 + lm) * 96 + ks * 32 + quad * 8];

        f32x4 acc[6];
        #pragma unroll
        for (int ct = 0; ct < 6; ++ct) acc[ct] = (f32x4){0.f, 0.f, 0.f, 0.f};

        #pragma unroll
        for (int ct = 0; ct < 6; ++ct) {
            #pragma unroll
            for (int ks = 0; ks < 3; ++ks) {
                half8 bf = *(const half8*)&Wh[s][(ct * 16 + lm) * 96 + ks * 32 + quad * 8];
                acc[ct] = __builtin_amdgcn_mfma_f32_16x16x32_f16(af[ks], bf, acc[ct], 0, 0, 0);
            }
        }

        const float* bias = biases[s];
        if (s < 2) {
            #pragma unroll
            for (int ct = 0; ct < 6; ++ct) {
                #pragma unroll
                for (int r = 0; r < 4; ++r) {
                    int lr = wave * 16 + quad * 4 + r;
                    int lc = ct * 16 + lm;
                    float v = acc[ct][r] + bias[lc];
                    v = v / (1.f + __expf(-v));
                    Ah[cur ^ 1][lr * 96 + lc] = (_Float16)v;
                }
            }
            cur ^= 1;
        } else {
            #pragma unroll
            for (int ct = 0; ct < 6; ++ct) {
                #pragma unroll
                for (int r = 0; r < 4; ++r) {
                    int lr = wave * 16 + quad * 4 + r;
                    size_t row = row0 + lr;
                    int lc = ct * 16 + lm;
                    float v = acc[ct][r] + bias[lc];
                    v = v / (1.f + __expf(-v));
                    size_t b = row / NPATCH; int n = (int)(row % NPATCH);
                    int ny = n / 14, nx = n % 14;
                    outh[((b * 256) + (1 + ny) * 16 + (1 + nx)) * 96 + lc] = (_Float16)v;
                }
            }
        }
    }
}

// ---------------------------------------------------------------------------
// MFMA attention (r11 structure): qkv input f16, output f16.
// ---------------------------------------------------------------------------
__global__ void __launch_bounds__(256) k_attn_mfma(const _Float16* __restrict__ qkv,
                                                   _Float16* __restrict__ o)
{
    __shared__ __align__(16) _Float16 Qs[208 * 40];
    __shared__ __align__(16) _Float16 Ks[208 * 40];
    __shared__ __align__(16) _Float16 Vt[32 * 232];
    __shared__ __align__(16) _Float16 Pw[4][16 * 232];

    int t = threadIdx.x;
    int bh = blockIdx.x;
    int b = bh >> 2, h = bh & 3;
    const _Float16* base = qkv + (size_t)b * NPATCH * 288 + h * 24;

    {
        const int4 z = {0, 0, 0, 0};
        int4* q4 = (int4*)Qs; int4* k4 = (int4*)Ks;
        for (int i = t; i < 1040; i += 256) { q4[i] = z; k4[i] = z; }
        int4* v4 = (int4*)Vt;
        for (int i = t; i < 928; i += 256) v4[i] = z;
        int4* p4 = (int4*)&Pw[0][0];
        for (int i = t; i < 1856; i += 256) p4[i] = z;
    }
    __syncthreads();

    for (int i = t; i < NPATCH * 24; i += 256) {
        int r = i / 24, d = i % 24;
        const _Float16* row = base + (size_t)r * 288;
        Qs[r * 40 + d]   = row[d];
        Ks[r * 40 + d]   = row[96 + d];
        Vt[d * 232 + r]  = row[192 + d];
    }
    __syncthreads();

    int wave = t >> 6, lane = t & 63;
    int lm = lane & 15, quad = lane >> 4;
    const float scale = 0.2041241452319315f;

    half8 bk[13];
    #pragma unroll
    for (int ct = 0; ct < 13; ++ct)
        bk[ct] = *(const half8*)&Ks[(ct * 16 + lm) * 40 + quad * 8];

    _Float16* pw = &Pw[wave][0];

    for (int rt = wave; rt < 13; rt += 4) {
        half8 aq = *(const half8*)&Qs[(rt * 16 + lm) * 40 + quad * 8];
        float rsum[4] = {0.f, 0.f, 0.f, 0.f};

        #pragma unroll
        for (int ct = 0; ct < 13; ++ct) {
            f32x4 s = (f32x4){0.f, 0.f, 0.f, 0.f};
            s = __builtin_amdgcn_mfma_f32_16x16x32_f16(aq, bk[ct], s, 0, 0, 0);
            #pragma unroll
            for (int r = 0; r < 4; ++r) {
                float p = __expf(fminf(s[r] * scale, 60.f));
                if (ct == 12 && lm >= 4) p = 0.f;   // keys 196..207 invalid
                rsum[r] += p;
                pw[(quad * 4 + r) * 232 + ct * 16 + lm] = (_Float16)p;
            }
        }

        #pragma unroll
        for (int r = 0; r < 4; ++r) {
            float s = rsum[r];
            s += __shfl_xor(s, 1);
            s += __shfl_xor(s, 2);
            s += __shfl_xor(s, 4);
            s += __shfl_xor(s, 8);
            rsum[r] = 1.f / s;
        }

        f32x4 ov0 = (f32x4){0.f, 0.f, 0.f, 0.f};
        f32x4 ov1 = (f32x4){0.f, 0.f, 0.f, 0.f};
        #pragma unroll
        for (int ks = 0; ks < 7; ++ks) {
            half8 ap = *(const half8*)&pw[lm * 232 + ks * 32 + quad * 8];
            half8 bv0 = *(const half8*)&Vt[(lm) * 232 + ks * 32 + quad * 8];
            half8 bv1 = *(const half8*)&Vt[(16 + lm) * 232 + ks * 32 + quad * 8];
            ov0 = __builtin_amdgcn_mfma_f32_16x16x32_f16(ap, bv0, ov0, 0, 0, 0);
            ov1 = __builtin_amdgcn_mfma_f32_16x16x32_f16(ap, bv1, ov1, 0, 0, 0);
        }

        #pragma unroll
        for (int r = 0; r < 4; ++r) {
            int row = rt * 16 + quad * 4 + r;
            if (row < NPATCH) {
                _Float16* orow = o + ((size_t)b * NPATCH + row) * 96 + h * 24;
                orow[lm] = (_Float16)(ov0[r] * rsum[r]);
                if (lm < 8) orow[16 + lm] = (_Float16)(ov1[r] * rsum[r]);
            }
        }
    }
}

// ---------------------------------------------------------------------------
// conv L1, tile-resident + fused LN partial stats (r16, verified).
// ---------------------------------------------------------------------------
__global__ void __launch_bounds__(256) k_conv1_tile(const _Float16* __restrict__ xinh,
                                                    const _Float16* __restrict__ wc,
                                                    const float* __restrict__ bias,
                                                    _Float16* __restrict__ c1,
                                                    float* __restrict__ pstat1)
{
    __shared__ __align__(16) _Float16 Xs[4 * 16 * 104];   // 13.3 KB
    __shared__ float bins[96];
    int t = threadIdx.x;
    int blk = blockIdx.x;
    int b = blk / 7, s = blk % 7;

    if (t < 96) bins[t] = 0.f;

    for (int i = t; i < 768; i += 256) {
        int r = i / 192, rem = i % 192;
        int c = rem / 12, ch = (rem % 12) * 8;
        *(uint4*)&Xs[(r * 16 + c) * 104 + ch] =
            *(const uint4*)(xinh + ((size_t)(b * 256) + (2 * s + r) * 16 + c) * 96 + ch);
    }

    int wave = t >> 6, lane = t & 63;
    int lm = lane & 15, quad = lane >> 4;
    int ry = wave >> 1, rx = wave & 1;

    __syncthreads();

    for (int nt = 0; nt < 3; ++nt) {
        half8 bf[12];
        #pragma unroll
        for (int ks = 0; ks < 12; ++ks)
            bf[ks] = *(const half8*)&wc[((size_t)(wave * 48 + nt * 16 + lm)) * 384
                                        + ks * 32 + quad * 8];

        float sl = 0.f, ql = 0.f;
        #pragma unroll
        for (int rt = 0; rt < 2; ++rt) {
            int pp = rt * 16 + lm;
            int ppc = pp < 28 ? pp : 27;
            int pyl = ppc / 14, px = ppc % 14;

            half8 af[12];
            #pragma unroll
            for (int ks = 0; ks < 12; ++ks) {
                int k0 = ks * 32 + quad * 8;
                int tap = k0 / 96, off = k0 % 96;
                int dy = tap >> 1, dx = tap & 1;
                af[ks] = *(const half8*)&Xs[((pyl + ry + dy) * 16 + (px + rx + dx)) * 104 + off];
            }

            f32x4 acc = (f32x4){0.f, 0.f, 0.f, 0.f};
            #pragma unroll
            for (int ks = 0; ks < 12; ++ks)
                acc = __builtin_amdgcn_mfma_f32_16x16x32_f16(af[ks], bf[ks], acc, 0, 0, 0);

            #pragma unroll
            for (int r = 0; r < 4; ++r) {
                int pw = rt * 16 + quad * 4 + r;
                if (pw < 28) {
                    int pylw = pw / 14, pxw = pw % 14;
                    int oy = 2 * (2 * s + pylw) + ry, ox = 2 * pxw + rx;
                    float v = acc[r] + bias[nt * 16 + lm];
                    sl += v; ql += v * v;
                    c1[((size_t)(b * 28 + oy) * 28 + ox) * 48 + nt * 16 + lm] = (_Float16)v;
                }
            }
        }
        atomicAdd(&bins[(nt * 16 + lm) * 2],     sl);
        atomicAdd(&bins[(nt * 16 + lm) * 2 + 1], ql);
    }
    __syncthreads();
    if (t < 96) atomicAdd(&pstat1[(size_t)b * 96 + t], bins[t]);
}

// ---------------------------------------------------------------------------
// conv L2, tile-resident, LN1 fused into staging: reads C1h + stat1 + l1g/b,
// applies LN+silu on the fly (identical rounding to old ln1_apply).
// ---------------------------------------------------------------------------
__global__ void __launch_bounds__(256) k_conv2_tile(const _Float16* __restrict__ c1,
                                                    const float* __restrict__ pstat1,
                                                    const float* __restrict__ g1,
                                                    const float* __restrict__ b1v,
                                                    const _Float16* __restrict__ wc,
                                                    const float* __restrict__ bias,
                                                    _Float16* __restrict__ c2,
                                                    float* __restrict__ pstat2)
{
    __shared__ __align__(16) _Float16 Xs[4 * 30 * 56];   // 13.1 KB
    __shared__ float bins[48];
    int t = threadIdx.x;
    int blk = blockIdx.x;
    int b = blk / 14, s = blk % 14;

    if (t < 48) bins[t] = 0.f;

    for (int i = t; i < 720; i += 256) {
        int r = i / 180, rem = i % 180;
        int c = rem / 6, ch0 = (rem % 6) * 8;
        int py = 2 * s + r, px = c;
        half8 hv;
        if (py >= 1 && py <= 28 && px >= 1 && px <= 28) {
            int j = (py - 1) * 28 + (px - 1);
            half8 v = *(const half8*)&c1[((size_t)b * 784 + j) * 48 + ch0];
            const float* ps = pstat1 + (size_t)b * 96 + ch0 * 2;
            float gj = g1[j], bj = b1v[j];
            #pragma unroll
            for (int k = 0; k < 8; ++k) {
                float mu = ps[2 * k] * (1.f / 784.f);
                float rstd = rsqrtf(ps[2 * k + 1] * (1.f / 784.f) - mu * mu + 1e-5f);
                float u = ((float)v[k] - mu) * rstd * gj + bj;
                hv[k] = (_Float16)(u / (1.f + __expf(-u)));
            }
        } else {
            #pragma unroll
            for (int k = 0; k < 8; ++k) hv[k] = (_Float16)0.f;
        }
        *(half8*)&Xs[(r * 30 + c) * 56 + ch0] = hv;
    }

    int wave = t >> 6, lane = t & 63;
    int lm = lane & 15, quad = lane >> 4;
    int ry = wave >> 1, rx = wave & 1;

    half8 bf0[6], bf1[6];
    #pragma unroll
    for (int ks = 0; ks < 6; ++ks) {
        bf0[ks] = *(const half8*)&wc[((size_t)(wave * 32 + lm)) * 192 + ks * 32 + quad * 8];
        bf1[ks] = *(const half8*)&wc[((size_t)(wave * 32 + 16 + lm)) * 192 + ks * 32 + quad * 8];
    }

    __syncthreads();

    float s0l = 0.f, q0l = 0.f, s1l = 0.f, q1l = 0.f;
    #pragma unroll
    for (int rt = 0; rt < 4; ++rt) {
        int pp = rt * 16 + lm;
        int ppc = pp < 56 ? pp : 55;
        int pyl = ppc / 28, px = ppc % 28;

        half8 af[6];
        #pragma unroll
        for (int ks = 0; ks < 6; ++ks) {
            int k0 = ks * 32 + quad * 8;
            int tap = k0 / 48, off = k0 % 48;
            int dy = tap >> 1, dx = tap & 1;
            af[ks] = *(const half8*)&Xs[((pyl + ry + dy) * 30 + (px + rx + dx)) * 56 + off];
        }

        f32x4 acc0 = (f32x4){0.f, 0.f, 0.f, 0.f};
        f32x4 acc1 = (f32x4){0.f, 0.f, 0.f, 0.f};
        #pragma unroll
        for (int ks = 0; ks < 6; ++ks) {
            acc0 = __builtin_amdgcn_mfma_f32_16x16x32_f16(af[ks], bf0[ks], acc0, 0, 0, 0);
            acc1 = __builtin_amdgcn_mfma_f32_16x16x32_f16(af[ks], bf1[ks], acc1, 0, 0, 0);
        }

        #pragma unroll
        for (int r = 0; r < 4; ++r) {
            int pw = rt * 16 + quad * 4 + r;
            if (pw < 56) {
                int pylw = pw / 28, pxw = pw % 28;
                int oy = 2 * (2 * s + pylw) + ry, ox = 2 * pxw + rx;
                _Float16* orow = c2 + ((size_t)(b * 56 + oy) * 56 + ox) * 24;
                float v0 = acc0[r] + bias[lm];
                orow[lm] = (_Float16)v0;
                s0l += v0; q0l += v0 * v0;
                if (lm < 8) {
                    float v1 = acc1[r] + bias[16 + lm];
                    orow[16 + lm] = (_Float16)v1;
                    s1l += v1; q1l += v1 * v1;
                }
            }
        }
    }
    atomicAdd(&bins[lm * 2],     s0l);
    atomicAdd(&bins[lm * 2 + 1], q0l);
    if (lm < 8) {
        atomicAdd(&bins[(16 + lm) * 2],     s1l);
        atomicAdd(&bins[(16 + lm) * 2 + 1], q1l);
    }
    __syncthreads();
    if (t < 48) atomicAdd(&pstat2[(size_t)b * 48 + t], bins[t]);
}

// ---------------------------------------------------------------------------
// conv L3, tile-resident, LN2 fused into staging.
// ---------------------------------------------------------------------------
__global__ void __launch_bounds__(256) k_conv3_tile(const _Float16* __restrict__ c2,
                                                    const float* __restrict__ pstat2,
                                                    const float* __restrict__ g2,
                                                    const float* __restrict__ b2v,
                                                    const _Float16* __restrict__ wc,
                                                    const float* __restrict__ bias,
                                                    _Float16* __restrict__ c3,
                                                    float* __restrict__ pstat3)
{
    __shared__ __align__(16) _Float16 Xs[3 * 58 * 40];   // 13.6 KB
    __shared__ float bins[24];
    int t = threadIdx.x;
    int blk = blockIdx.x;
    int b = blk / 56, s = blk % 56;

    if (t < 24) bins[t] = 0.f;

    for (int i = t; i < 522; i += 256) {
        int r = i / 174, rem = i % 174;
        int c = rem / 3, ch0 = (rem % 3) * 8;
        int py = s + r, px = c;
        half8 hv;
        if (py >= 1 && py <= 56 && px >= 1 && px <= 56) {
            int j = (py - 1) * 56 + (px - 1);
            half8 v = *(const half8*)&c2[((size_t)b * 3136 + j) * 24 + ch0];
            const float* ps = pstat2 + (size_t)b * 48 + ch0 * 2;
            float gj = g2[j], bj = b2v[j];
            #pragma unroll
            for (int k = 0; k < 8; ++k) {
                float mu = ps[2 * k] * (1.f / 3136.f);
                float rstd = rsqrtf(ps[2 * k + 1] * (1.f / 3136.f) - mu * mu + 1e-5f);
                float u = ((float)v[k] - mu) * rstd * gj + bj;
                hv[k] = (_Float16)(u / (1.f + __expf(-u)));
            }
        } else {
            #pragma unroll
            for (int k = 0; k < 8; ++k) hv[k] = (_Float16)0.f;
        }
        *(half8*)&Xs[(r * 58 + c) * 40 + ch0] = hv;
    }

    int wave = t >> 6, lane = t & 63;
    int lm = lane & 15, quad = lane >> 4;
    int ry = wave >> 1, rx = wave & 1;

    half8 bf[3];
    #pragma unroll
    for (int ks = 0; ks < 3; ++ks)
        bf[ks] = *(const half8*)&wc[((size_t)(wave * 16 + lm)) * 96 + ks * 32 + quad * 8];

    __syncthreads();

    float sl = 0.f, ql = 0.f;
    #pragma unroll
    for (int rt = 0; rt < 4; ++rt) {
        int px = rt * 16 + lm;
        int pxc = px < 56 ? px : 55;

        half8 af[3];
        #pragma unroll
        for (int ks = 0; ks < 3; ++ks) {
            int k0 = ks * 32 + quad * 8;
            int tap = k0 / 24, off = k0 % 24;
            int dy = tap >> 1, dx = tap & 1;
            af[ks] = *(const half8*)&Xs[((ry + dy) * 58 + (pxc + rx + dx)) * 40 + off];
        }

        f32x4 acc = (f32x4){0.f, 0.f, 0.f, 0.f};
        #pragma unroll
        for (int ks = 0; ks < 3; ++ks)
            acc = __builtin_amdgcn_mfma_f32_16x16x32_f16(af[ks], bf[ks], acc, 0, 0, 0);

        if (lm < 12) {
            #pragma unroll
            for (int r = 0; r < 4; ++r) {
                int pw = rt * 16 + quad * 4 + r;
                if (pw < 56) {
                    int oy = 2 * s + ry, ox = 2 * pw + rx;
                    float v = acc[r] + bias[lm];
                    sl += v; ql += v * v;
                    c3[((size_t)(b * 112 + oy) * 112 + ox) * 12 + lm] = (_Float16)v;
                }
            }
        }
    }
    if (lm < 12) {
        atomicAdd(&bins[lm * 2],     sl);
        atomicAdd(&bins[lm * 2 + 1], ql);
    }
    __syncthreads();
    if (t < 24) atomicAdd(&pstat3[(size_t)b * 24 + t], bins[t]);
}

// ---------------------------------------------------------------------------
// final convT 12->1, LN3 fused into staging: reads C3h + stat3 + l3g/b,
// applies LN+silu while filling the LDS strip; then fdot2 as r19.
// grid 7168.
// ---------------------------------------------------------------------------
__global__ void __launch_bounds__(256) k_conv_final3(const _Float16* __restrict__ c3,
                                                     const float* __restrict__ pstat3,
                                                     const float* __restrict__ g3,
                                                     const float* __restrict__ b3v,
                                                     const _Float16* __restrict__ wcf,
                                                     const float* __restrict__ bias,
                                                     float* __restrict__ out)
{
    constexpr int HIN = 112, CIN = 12;
    __shared__ __align__(16) _Float16 Xs[4 * 114 * 12];   // 10.9 KB
    __shared__ __align__(16) _Float16 Wl[192];
    int t = threadIdx.x;
    int blk = blockIdx.x;
    int b = blk / 56, s = blk % 56;
    int py0 = 2 * s;

    {
        const int4 z = {0, 0, 0, 0};
        int4* p4 = (int4*)Xs;
        for (int i = t; i < 684; i += 256) p4[i] = z;
        if (t < 24) *(int4*)&Wl[t * 8] = *(const int4*)&wcf[t * 8];
    }
    __syncthreads();
    // stage rows py0-1 .. py0+2, 2 pixels (24 halves) per item, LN+silu fused
    if (t < 224) {
        int r = t / 56, u = t % 56;
        int row = py0 - 1 + r;
        if (row >= 0 && row < HIN) {
            size_t base = ((size_t)b * 12544 + (size_t)row * 112 + 2 * u) * 12;
            half4v v0 = *(const half4v*)&c3[base];
            half4v v1 = *(const half4v*)&c3[base + 4];
            half4v v2 = *(const half4v*)&c3[base + 8];
            half4v v3 = *(const half4v*)&c3[base + 12];
            half4v v4 = *(const half4v*)&c3[base + 16];
            half4v v5 = *(const half4v*)&c3[base + 20];
            int j0 = row * 112 + 2 * u;
            float ga = g3[j0], ba = b3v[j0];
            float gb = g3[j0 + 1], bb2 = b3v[j0 + 1];
            const float* ps = pstat3 + (size_t)b * 24;
            _Float16 ov[24];
            #pragma unroll
            for (int k = 0; k < 24; ++k) {
                int ch = (k < 12) ? k : k - 12;
                float mu = ps[2 * ch] * (1.f / 12544.f);
                float rstd = rsqrtf(ps[2 * ch + 1] * (1.f / 12544.f) - mu * mu + 1e-5f);
                float vv;
                if      (k < 4)  vv = (float)v0[k];
                else if (k < 8)  vv = (float)v1[k - 4];
                else if (k < 12) vv = (float)v2[k - 8];
                else if (k < 16) vv = (float)v3[k - 12];
                else if (k < 20) vv = (float)v4[k - 16];
                else             vv = (float)v5[k - 20];
                float gk = (k < 12) ? ga : gb;
                float bk = (k < 12) ? ba : bb2;
                float u2 = (vv - mu) * rstd * gk + bk;
                ov[k] = (_Float16)(u2 / (1.f + __expf(-u2)));
            }
            _Float16* dst = &Xs[(size_t)r * 1368 + u * 24];
            *(half8*)&dst[0]  = *(half8*)&ov[0];
            *(half8*)&dst[8]  = *(half8*)&ov[8];
            *(half8*)&dst[16] = *(half8*)&ov[16];
        }
    }
    __syncthreads();

    if (t >= 224) return;
    int pyl = t / 112;
    int px = t % 112;
    int py = py0 + pyl;

    half2v tvp[9][6];
    #pragma unroll
    for (int a = 0; a < 3; ++a) {
        int lr = pyl + a;
        #pragma unroll
        for (int c = 0; c < 3; ++c) {
            int col = px - 1 + c;
            int cs = (col < 0) ? 113 : col;
            const _Float16* p = &Xs[((size_t)lr * 114 + cs) * 12];
            half4v h0 = *(const half4v*)&p[0];
            half4v h1 = *(const half4v*)&p[4];
            half4v h2 = *(const half4v*)&p[8];
            int ti = a * 3 + c;
            tvp[ti][0] = (half2v){h0[0], h0[1]};
            tvp[ti][1] = (half2v){h0[2], h0[3]};
            tvp[ti][2] = (half2v){h1[0], h1[1]};
            tvp[ti][3] = (half2v){h1[2], h1[3]};
            tvp[ti][4] = (half2v){h2[0], h2[1]};
            tvp[ti][5] = (half2v){h2[2], h2[3]};
        }
    }

    float bb = bias[0];
    float* ob = out + (size_t)b * 50176;
    #pragma unroll
    for (int ry = 0; ry < 2; ++ry) {
        float res[2];
        #pragma unroll
        for (int rx = 0; rx < 2; ++rx) {
            int p = ry * 2 + rx;
            float acc = 0.f;
            #pragma unroll
            for (int dy = 0; dy < 2; ++dy) {
                #pragma unroll
                for (int dx = 0; dx < 2; ++dx) {
                    int j = dy * 2 + dx;
                    int ti = (ry + dy) * 3 + (rx + dx);
                    const half2v* wp = (const half2v*)&Wl[(p * 4 + j) * 12];
                    #pragma unroll
                    for (int k = 0; k < 6; ++k)
                        acc = __builtin_amdgcn_fdot2(tvp[ti][k], wp[k], acc, false);
                }
            }
            float u = acc + bb;
            u = u / (1.f + __expf(-u));
            res[rx] = fminf(fmaxf(u, 0.f), 1.f);
        }
        float2 v; v.x = res[0]; v.y = res[1];
        *(float2*)(ob + (size_t)(2 * py + ry) * 224 + 2 * px) = v;
    }
}

// ---------------------------------------------------------------------------
// launch
// ---------------------------------------------------------------------------
extern "C" void kernel_launch(void* const* d_in, const int* in_sizes, int n_in,
                              void* d_out, int out_size, void* d_ws, size_t ws_size,
                              hipStream_t stream)
{
    const float* x       = (const float*)d_in[0];
    const float* ts      = (const float*)d_in[1];
    const float* Wp      = (const float*)d_in[2];
    const float* bp      = (const float*)d_in[3];
    const float* Wt1     = (const float*)d_in[4];
    const float* bt1     = (const float*)d_in[5];
    const float* Wt2     = (const float*)d_in[6];
    const float* bt2     = (const float*)d_in[7];
    const float* a0_g    = (const float*)d_in[8];
    const float* a0_b    = (const float*)d_in[9];
    const float* a0_Wqkv = (const float*)d_in[10];
    const float* a0_bqkv = (const float*)d_in[11];
    const float* a0_Wo   = (const float*)d_in[12];
    const float* a0_bo   = (const float*)d_in[13];
    const float* a1_g    = (const float*)d_in[14];
    const float* a1_b    = (const float*)d_in[15];
    const float* a1_Wqkv = (const float*)d_in[16];
    const float* a1_bqkv = (const float*)d_in[17];
    const float* a1_Wo   = (const float*)d_in[18];
    const float* a1_bo   = (const float*)d_in[19];
    const float* Wm0     = (const float*)d_in[20];
    const float* bm0     = (const float*)d_in[21];
    const float* Wm1     = (const float*)d_in[22];
    const float* bm1     = (const float*)d_in[23];
    const float* Wm2     = (const float*)d_in[24];
    const float* bm2     = (const float*)d_in[25];
    const float* Wd1     = (const float*)d_in[26];
    const float* bd1     = (const float*)d_in[27];
    const float* l1g     = (const float*)d_in[28];
    const float* l1b     = (const float*)d_in[29];
    const float* Wd2     = (const float*)d_in[30];
    const float* bd2     = (const float*)d_in[31];
    const float* l2g     = (const float*)d_in[32];
    const float* l2b     = (const float*)d_in[33];
    const float* Wd3     = (const float*)d_in[34];
    const float* bd3     = (const float*)d_in[35];
    const float* l3g     = (const float*)d_in[36];
    const float* l3b     = (const float*)d_in[37];
    const float* Wd4     = (const float*)d_in[38];
    const float* bd4     = (const float*)d_in[39];
    float* out = (float*)d_out;

    // arena (floats); R = 25088*96
    const size_t R = 2408448;
    float* ws   = (float*)d_ws;
    float* tvec = ws;                          // 96
    float* p0   = ws + 512;                    // R (fp32 residual; f16 alias p0h)
    _Float16* p0h  = (_Float16*)(ws + 512);           // f16 wo1 out (p0 region)
    _Float16* hh   = (_Float16*)(ws + 512 + R);       // f16 LN out (h region)
    _Float16* qkvh = (_Float16*)(ws + 512 + 2 * R);   // f16 qkv [M][288]
    _Float16* obh  = (_Float16*)(ws + 512 + 5 * R);   // f16 attn out (ob region)
    float* p1   = ws + 512 + 6 * R;            // R
    // decoder aliases:
    _Float16* xinh = (_Float16*)(ws + 512 + 2 * R);   // f16 NHWC (qkv region)
    _Float16* C1h  = (_Float16*)(ws + 512 + 5 * R);   // f16 NHWC [b][28][28][48]
    _Float16* C2h  = (_Float16*)(ws + 512);           // f16 NHWC [b][56][56][24]
    _Float16* C3h  = (_Float16*)(ws + 512 + 7 * R + 5529600); // f16 NHWC [b][112][112][12]
    float* Wr   = ws + 512 + 7 * R + 5529600 + 10334208;  // 96,960 floats
    _Float16* WH = (_Float16*)(Wr + 96960);                // 101,376 halves
    _Float16* Wc  = (_Float16*)Wr;
    _Float16* Wc2 = (_Float16*)(Wr + 36864);
    _Float16* Wc3 = (_Float16*)(Wr + 49152);
    float* stat = Wr + 96960 + 50688;          // 21,504 floats (raw LN sums)
    float* stat1 = stat;                       // 128*96
    float* stat2 = stat + 12288;               // 128*48
    float* stat3 = stat + 18432;               // 128*24
    _Float16* Wcf = (_Float16*)(stat + 21504); // 192 halves (conv_final f16 w)
    _Float16* Wph = (_Float16*)(stat + 21504 + 128); // 24576 halves (patch f16 w)
    const size_t NEED = (512 + 7 * R + 5529600 + 10334208 + 96960 + 50688 + 21504
                         + 128 + 12288 + 16) * sizeof(float);
    if (ws_size < NEED) return;

    _Float16* WHqkv0 = WH;
    _Float16* WHqkv1 = WH + 27648;
    _Float16* WHwo0  = WH + 55296;
    _Float16* WHwo1  = WH + 64512;
    _Float16* WHwm0  = WH + 73728;   // wm0,wm1,wm2 consecutive

    k_time<<<1, 128, 0, stream>>>(ts, Wt1, bt1, Wt2, bt2, tvec);
    k_zstat<<<84, 256, 0, stream>>>(stat);
    k_repack<<<379, 256, 0, stream>>>(Wd1, Wd2, Wd3, Wd4, Wr);
    k_wcvt4<<<1, 192, 0, stream>>>(Wr + 96768, Wcf);
    k_wcvtp<<<96, 256, 0, stream>>>(Wp, Wph);
    k_wcvtc<<<288, 256, 0, stream>>>(Wd1, Wc);
    k_wcvt2<<<96, 256, 0, stream>>>(Wd2, Wc2);
    k_wcvt3<<<24, 256, 0, stream>>>(Wd3, Wc3);
    k_wcvt<<<396, 256, 0, stream>>>(a0_Wqkv, a1_Wqkv, a0_Wo, a1_Wo,
                                    Wm0, Wm1, Wm2, WH);
    k_patch_mfma<<<M_ROWS / 32, 256, 0, stream>>>(x, Wph, bp, p0);

    // MHSA block 0
    k_ln_row<<<1024, 256, 0, stream>>>(p0, a0_g, a0_b, hh, M_ROWS);
    k_gemm_mfma<3, 1, false, false, false, true><<<dim3(M_ROWS / 64, 3), 256, 0, stream>>>(
        hh, WHqkv0, a0_bqkv, nullptr, nullptr, qkvh);
    k_attn_mfma<<<B_ * 4, 256, 0, stream>>>(qkvh, obh);
    k_gemm_mfma<1, 0, false, true, false, true><<<dim3(M_ROWS / 64, 1), 256, 0, stream>>>(
        obh, WHwo0, a0_bo, p0, nullptr, p1);

    // MHSA block 1 (+time)
    k_ln_row<<<1024, 256, 0, stream>>>(p1, a1_g, a1_b, hh, M_ROWS);
    k_gemm_mfma<3, 1, false, false, false, true><<<dim3(M_ROWS / 64, 3), 256, 0, stream>>>(
        hh, WHqkv1, a1_bqkv, nullptr, nullptr, qkvh);
    k_attn_mfma<<<B_ * 4, 256, 0, stream>>>(qkvh, obh);
    // wo1 + residual + time -> f16 p0h (only consumer: MLP)
    k_gemm_mfma<1, 1, false, true, true, true><<<dim3(M_ROWS / 64, 1), 256, 0, stream>>>(
        obh, WHwo1, a1_bo, p1, tvec, p0h);

    // qkv region free: zero xinh borders before MLP writes interior
    k_zb_h<<<2880, 256, 0, stream>>>(xinh);

    // fused MLP x3 (silu); writes f16 NHWC padded xinh
    k_mlp_fused<<<M_ROWS / 64, 256, 0, stream>>>(p0h, WHwm0, bm0, bm1, bm2, xinh);

    // decoder: conv chain with fused LN stats (producer) + LN apply (consumer)
    k_conv1_tile<<<B_ * 7, 256, 0, stream>>>(xinh, Wc, bd1, C1h, stat1);
    k_conv2_tile<<<B_ * 14, 256, 0, stream>>>(C1h, stat1, l1g, l1b, Wc2, bd2, C2h, stat2);
    k_conv3_tile<<<B_ * 56, 256, 0, stream>>>(C2h, stat2, l2g, l2b, Wc3, bd3, C3h, stat3);
    k_conv_final3<<<7168, 256, 0, stream>>>(C3h, stat3, l3g, l3b, Wcf, bd4, out);
}

// Round 14
// 408.442 us; speedup vs baseline: 1.1829x; 1.0484x over previous
//
#include <hip/hip_runtime.h>
#include <cmath>

// ---------------------------------------------------------------------------
// TimestepVisionTransformer — Round 22: VALU diet for fused-LN staging.
//   - conv2/conv3/conv_final: per-channel mu/rstd hoisted to an LDS table
//     computed ONCE per block (bitwise-identical values) instead of per
//     staged element.
//   - conv3: 2 output strips per block (grid 3584, stage 4 rows) ->
//     LN+silu recompute amplification 3x -> 2x, half the block overhead.
// Everything else = r21 (verified, 428.2us best).
// B=128, IMG=224, P=16, C_IN=1, E=96, H=4, d=24, NAX=14, N=196, M=B*N=25088
// ---------------------------------------------------------------------------

#define B_   128
#define NPATCH 196
#define M_ROWS (B_*NPATCH)     // 25088
#define E_   96

typedef _Float16 half8 __attribute__((ext_vector_type(8)));
typedef _Float16 half4v __attribute__((ext_vector_type(4)));
typedef _Float16 half2v __attribute__((ext_vector_type(2)));
typedef float f32x4 __attribute__((ext_vector_type(4)));

// ---------------------------------------------------------------------------
// time embedding
// ---------------------------------------------------------------------------
__global__ void k_time(const float* __restrict__ ts,
                       const float* __restrict__ Wt1, const float* __restrict__ bt1,
                       const float* __restrict__ Wt2, const float* __restrict__ bt2,
                       float* __restrict__ timev)
{
    __shared__ float h[128];
    float e = 0.69314718055994530942f * ts[0];
    float sv = sinf(e), cv = cosf(e);
    int t = threadIdx.x;
    float z = sv * Wt1[t] + cv * Wt1[128 + t] + bt1[t];
    h[t] = z / (1.f + expf(-z));
    __syncthreads();
    if (t < 96) {
        float acc = bt2[t];
        for (int j = 0; j < 128; ++j) acc += h[j] * Wt2[j * 96 + t];
        timev[t] = acc;
    }
}

// ---------------------------------------------------------------------------
// zero LN partial-stat table (21504 floats)
// ---------------------------------------------------------------------------
__global__ void __launch_bounds__(256) k_zstat(float* __restrict__ stat)
{
    int i = blockIdx.x * 256 + threadIdx.x;
    if (i < 21504) stat[i] = 0.f;
}

// ---------------------------------------------------------------------------
// weight repack (fp32 per-parity taps). L4 slice [96768,96960) feeds k_wcvt4;
// other slices overwritten by f16 packs.
// ---------------------------------------------------------------------------
__global__ void __launch_bounds__(256) k_repack(const float* __restrict__ w1,
                                                const float* __restrict__ w2,
                                                const float* __restrict__ w3,
                                                const float* __restrict__ w4f,
                                                float* __restrict__ wr)
{
    int i = blockIdx.x * 256 + threadIdx.x;
    const float* src; int CIN, COUT, e; float* dst;
    if      (i < 73728) { src = w1;  CIN = 96; COUT = 48; e = i;          dst = wr; }
    else if (i < 92160) { src = w2;  CIN = 48; COUT = 24; e = i - 73728;  dst = wr + 73728; }
    else if (i < 96768) { src = w3;  CIN = 24; COUT = 12; e = i - 92160;  dst = wr + 92160; }
    else if (i < 96960) { src = w4f; CIN = 12; COUT = 1;  e = i - 96768;  dst = wr + 96768; }
    else return;
    int per = CIN * COUT * 4;
    int par = e / per, rem = e % per;
    int ci = rem / (COUT * 4);
    int o  = (rem >> 2) % COUT;
    int j  = rem & 3;
    int ry = par >> 1, rx = par & 1;
    int wy = (j < 2)  ? (3 - ry) : (1 - ry);
    int wx = (j & 1)  ? (1 - rx) : (3 - rx);
    dst[e] = src[(ci * COUT + o) * 16 + wy * 4 + wx];
}

// ---------------------------------------------------------------------------
// conv_final weights -> f16 wcf[p][j][ci] (192 halves) from fp32 [p][ci][j]
// ---------------------------------------------------------------------------
__global__ void k_wcvt4(const float* __restrict__ wr4,
                        _Float16* __restrict__ wcf)
{
    int i = threadIdx.x;
    if (i >= 192) return;
    int p = i / 48, rem = i % 48;
    int j = rem / 12, ci = rem % 12;
    wcf[(p * 4 + j) * 12 + ci] = (_Float16)wr4[p * 48 + ci * 4 + j];
}

// ---------------------------------------------------------------------------
// patch weights -> f16 wph[kc][e][k] (24576 halves), k in [0,128)
// ---------------------------------------------------------------------------
__global__ void __launch_bounds__(256) k_wcvtp(const float* __restrict__ Wp,
                                               _Float16* __restrict__ wph)
{
    int i = blockIdx.x * 256 + threadIdx.x;
    if (i >= 24576) return;
    int kc = i / 12288, rem = i % 12288;
    int e = rem / 128, k = rem % 128;
    wph[i] = (_Float16)Wp[e * 256 + kc * 128 + k];
}

// ---------------------------------------------------------------------------
// conv1 weights -> f16 B-layout Wc[p][o][k=tap*96+ci]
// ---------------------------------------------------------------------------
__global__ void __launch_bounds__(256) k_wcvtc(const float* __restrict__ w1,
                                               _Float16* __restrict__ wc)
{
    int i = blockIdx.x * 256 + threadIdx.x;
    if (i >= 4 * 48 * 384) return;
    int p = i / 18432, rem = i % 18432;
    int o = rem / 384, k = rem % 384;
    int tap = k / 96, ci = k % 96;
    int ry = p >> 1, rx = p & 1;
    int wy = (tap < 2) ? (3 - ry) : (1 - ry);
    int wx = (tap & 1) ? (1 - rx) : (3 - rx);
    wc[i] = (_Float16)w1[(ci * 48 + o) * 16 + wy * 4 + wx];
}

// ---------------------------------------------------------------------------
// conv2 weights -> f16 B-layout Wc2[p][o(32, o>=24 zero)][k=tap*48+ci]
// ---------------------------------------------------------------------------
__global__ void __launch_bounds__(256) k_wcvt2(const float* __restrict__ w2,
                                               _Float16* __restrict__ wc2)
{
    int i = blockIdx.x * 256 + threadIdx.x;
    if (i >= 4 * 32 * 192) return;
    int p = i / 6144, rem = i % 6144;
    int o = rem / 192, k = rem % 192;
    int tap = k / 48, ci = k % 48;
    int ry = p >> 1, rx = p & 1;
    int wy = (tap < 2) ? (3 - ry) : (1 - ry);
    int wx = (tap & 1) ? (1 - rx) : (3 - rx);
    wc2[i] = (o < 24) ? (_Float16)w2[(ci * 24 + o) * 16 + wy * 4 + wx]
                      : (_Float16)0.f;
}

// ---------------------------------------------------------------------------
// conv3 weights -> f16 B-layout Wc3[p][o(16, o>=12 zero)][k=tap*24+ci]
// ---------------------------------------------------------------------------
__global__ void __launch_bounds__(256) k_wcvt3(const float* __restrict__ w3,
                                               _Float16* __restrict__ wc3)
{
    int i = blockIdx.x * 256 + threadIdx.x;
    if (i >= 4 * 16 * 96) return;
    int p = i / 1536, rem = i % 1536;
    int o = rem / 96, k = rem % 96;
    int tap = k / 24, ci = k % 24;
    int ry = p >> 1, rx = p & 1;
    int wy = (tap < 2) ? (3 - ry) : (1 - ry);
    int wx = (tap & 1) ? (1 - rx) : (3 - rx);
    wc3[i] = (o < 12) ? (_Float16)w3[(ci * 12 + o) * 16 + wy * 4 + wx]
                      : (_Float16)0.f;
}

// ---------------------------------------------------------------------------
// transformer weight convert+transpose to half: Wt[n][k] = W[k][n]
// ---------------------------------------------------------------------------
__global__ void __launch_bounds__(256) k_wcvt(const float* __restrict__ qkv0,
                                              const float* __restrict__ qkv1,
                                              const float* __restrict__ wo0,
                                              const float* __restrict__ wo1,
                                              const float* __restrict__ wm0,
                                              const float* __restrict__ wm1,
                                              const float* __restrict__ wm2,
                                              _Float16* __restrict__ wh)
{
    int i = blockIdx.x * 256 + threadIdx.x;
    const float* src; int N; int e;
    if      (i < 27648)  { src = qkv0; N = 288; e = i; }
    else if (i < 55296)  { src = qkv1; N = 288; e = i - 27648; }
    else if (i < 64512)  { src = wo0;  N = 96;  e = i - 55296; }
    else if (i < 73728)  { src = wo1;  N = 96;  e = i - 64512; }
    else if (i < 82944)  { src = wm0;  N = 96;  e = i - 73728; }
    else if (i < 92160)  { src = wm1;  N = 96;  e = i - 82944; }
    else if (i < 101376) { src = wm2;  N = 96;  e = i - 92160; }
    else return;
    int n = e / 96, k = e % 96;
    wh[i] = (_Float16)src[k * N + n];
}

// ---------------------------------------------------------------------------
// zero the borders of xinh NHWC f16 [b][16][16][96]
// ---------------------------------------------------------------------------
__global__ void __launch_bounds__(256) k_zb_h(_Float16* __restrict__ xinh)
{
    int i = blockIdx.x * 256 + threadIdx.x;
    if (i >= 128 * 60 * 96) return;
    int b = i / 5760, r = i % 5760;
    int pos = r / 96, ch = r % 96;
    int py, px;
    if      (pos < 16) { py = 0;        px = pos; }
    else if (pos < 32) { py = 15;       px = pos - 16; }
    else if (pos < 46) { py = pos - 31; px = 0; }
    else               { py = pos - 45; px = 15; }
    xinh[((size_t)(b * 256) + py * 16 + px) * 96 + ch] = (_Float16)0.f;
}

// ---------------------------------------------------------------------------
// patch embed GEMM, occupancy-fixed (r20, verified): 32 patches/block.
// ---------------------------------------------------------------------------
__global__ void __launch_bounds__(256) k_patch_mfma(const float* __restrict__ x,
                                                    const _Float16* __restrict__ wph,
                                                    const float* __restrict__ bp,
                                                    float* __restrict__ out)
{
    __shared__ __align__(16) _Float16 Ah[32 * 136];
    __shared__ __align__(16) _Float16 Wh[96 * 136];
    int t = threadIdx.x;
    int p0 = blockIdx.x * 32;
    int wave = t >> 6, lane = t & 63;
    int lm = lane & 15, quad = lane >> 4;
    int rt = wave >> 1, nh = wave & 1;
    f32x4 acc[3];
    #pragma unroll
    for (int nt = 0; nt < 3; ++nt) acc[nt] = (f32x4){0.f, 0.f, 0.f, 0.f};

    for (int kc = 0; kc < 2; ++kc) {
        __syncthreads();
        {
            int lp = t >> 3, pyl = t & 7;
            int patch = p0 + lp;
            int b = patch / NPATCH, n = patch % NPATCH;
            int ny = n / 14, nx = n % 14;
            const float4* s4 = (const float4*)(x +
                ((size_t)(b * 224) + ny * 16 + kc * 8 + pyl) * 224 + nx * 16);
            float4 v0 = s4[0], v1 = s4[1], v2 = s4[2], v3 = s4[3];
            half8 h0, h1;
            h0[0]=(_Float16)v0.x; h0[1]=(_Float16)v0.y; h0[2]=(_Float16)v0.z; h0[3]=(_Float16)v0.w;
            h0[4]=(_Float16)v1.x; h0[5]=(_Float16)v1.y; h0[6]=(_Float16)v1.z; h0[7]=(_Float16)v1.w;
            h1[0]=(_Float16)v2.x; h1[1]=(_Float16)v2.y; h1[2]=(_Float16)v2.z; h1[3]=(_Float16)v2.w;
            h1[4]=(_Float16)v3.x; h1[5]=(_Float16)v3.y; h1[6]=(_Float16)v3.z; h1[7]=(_Float16)v3.w;
            *(half8*)&Ah[lp * 136 + pyl * 16]     = h0;
            *(half8*)&Ah[lp * 136 + pyl * 16 + 8] = h1;
        }
        {
            const uint4* src = (const uint4*)(wph + (size_t)kc * 12288);
            for (int i = t; i < 1536; i += 256) {
                int e = i >> 4, s = i & 15;
                *(uint4*)&Wh[e * 136 + s * 8] = src[i];
            }
        }
        __syncthreads();
        half8 af[4];
        #pragma unroll
        for (int ks = 0; ks < 4; ++ks)
            af[ks] = *(const half8*)&Ah[(rt * 16 + lm) * 136 + ks * 32 + quad * 8];
        #pragma unroll
        for (int ks = 0; ks < 4; ++ks) {
            #pragma unroll
            for (int nt = 0; nt < 3; ++nt) {
                half8 bf = *(const half8*)&Wh[((nh * 3 + nt) * 16 + lm) * 136 + ks * 32 + quad * 8];
                acc[nt] = __builtin_amdgcn_mfma_f32_16x16x32_f16(af[ks], bf, acc[nt], 0, 0, 0);
            }
        }
    }

    #pragma unroll
    for (int nt = 0; nt < 3; ++nt) {
        #pragma unroll
        for (int r = 0; r < 4; ++r) {
            int e = (nh * 3 + nt) * 16 + lm;
            int lp = rt * 16 + quad * 4 + r;
            int patch = p0 + lp;
            int n = patch % NPATCH;
            int ny = n / 14, nx = n % 14;
            float yx = (float)(ny + nx);
            float v = acc[nt][r] + bp[e];
            float other = __shfl_xor(v, 1);
            float fi = (float)(e >> 1);
            float theta = expf(fi * (-2.f / 96.f) * 9.210340371976184f);
            float ang = theta * yx;
            float c = cosf(ang), s = sinf(ang);
            float outv = (lm & 1) ? (other * s + v * c) : (v * c - other * s);
            out[(size_t)patch * 96 + e] = outv;
        }
    }
}

// ---------------------------------------------------------------------------
// row LayerNorm over 96, wave per row — writes f16.
// ---------------------------------------------------------------------------
__global__ void __launch_bounds__(256) k_ln_row(const float* __restrict__ x,
                                                const float* __restrict__ g,
                                                const float* __restrict__ bv,
                                                _Float16* __restrict__ out, int M)
{
    int lane = threadIdx.x & 63;
    int gw = (blockIdx.x * 256 + threadIdx.x) >> 6;
    int nw = (gridDim.x * 256) >> 6;
    float g0 = g[lane], b0 = bv[lane];
    float g1 = 0.f, b1 = 0.f;
    if (lane < 32) { g1 = g[64 + lane]; b1 = bv[64 + lane]; }
    for (int r = gw; r < M; r += nw) {
        const float* xr = x + (size_t)r * 96;
        float a = xr[lane];
        float c = (lane < 32) ? xr[64 + lane] : 0.f;
        float s = a + c, q = a * a + c * c;
        #pragma unroll
        for (int off = 32; off; off >>= 1) {
            s += __shfl_xor(s, off);
            q += __shfl_xor(q, off);
        }
        float mu = s * (1.f / 96.f);
        float rstd = rsqrtf(q * (1.f / 96.f) - mu * mu + 1e-5f);
        _Float16* orow = out + (size_t)r * 96;
        orow[lane] = (_Float16)((a - mu) * rstd * g0 + b0);
        if (lane < 32) orow[64 + lane] = (_Float16)((c - mu) * rstd * g1 + b1);
    }
}

// ---------------------------------------------------------------------------
// MFMA row GEMM (r16, verified). AHALF: A f16. OUTMODE: 0=fp32, 1=f16.
// Chunks over blockIdx.y.
// ---------------------------------------------------------------------------
template<int NCHUNKS, int OUTMODE, bool SILU, bool RES, bool ADDTIME, bool AHALF>
__global__ void __launch_bounds__(256) k_gemm_mfma(const void* __restrict__ A,
                                                   const _Float16* __restrict__ Wt,
                                                   const float* __restrict__ bias,
                                                   const float* __restrict__ res,
                                                   const float* __restrict__ timev,
                                                   void* __restrict__ outp)
{
    __shared__ __align__(16) _Float16 Ah[64 * 96];
    __shared__ __align__(16) _Float16 Wh[96 * 96];
    constexpr int NTOT = NCHUNKS * 96;
    int t = threadIdx.x;
    size_t row0 = (size_t)blockIdx.x * 64;

    if constexpr (AHALF) {
        const uint4* a4 = (const uint4*)((const _Float16*)A + row0 * 96);
        uint4* dst = (uint4*)Ah;
        for (int i = t; i < 768; i += 256) dst[i] = a4[i];
    } else {
        const float4* a4 = (const float4*)((const float*)A + row0 * 96);
        for (int i = t; i < 1536; i += 256) {
            float4 v = a4[i];
            half4v hv;
            hv[0] = (_Float16)v.x; hv[1] = (_Float16)v.y;
            hv[2] = (_Float16)v.z; hv[3] = (_Float16)v.w;
            *(half4v*)&Ah[i * 4] = hv;
        }
    }

    int wave = t >> 6, lane = t & 63;
    int lm = lane & 15, quad = lane >> 4;
    const f32x4 vzero = {0.f, 0.f, 0.f, 0.f};

    for (int ch = blockIdx.y; ch < NCHUNKS; ch += gridDim.y) {
        __syncthreads();
        {
            const uint4* src = (const uint4*)(Wt + (size_t)ch * 9216);
            uint4* dst = (uint4*)Wh;
            for (int i = t; i < 1152; i += 256) dst[i] = src[i];
        }
        __syncthreads();

        half8 af[3];
        #pragma unroll
        for (int ks = 0; ks < 3; ++ks)
            af[ks] = *(const half8*)&Ah[(wave * 16 + lm) * 96 + ks * 32 + quad * 8];

        f32x4 acc[6];
        #pragma unroll
        for (int ct = 0; ct < 6; ++ct) acc[ct] = vzero;

        #pragma unroll
        for (int ct = 0; ct < 6; ++ct) {
            #pragma unroll
            for (int ks = 0; ks < 3; ++ks) {
                half8 bf = *(const half8*)&Wh[(ct * 16 + lm) * 96 + ks * 32 + quad * 8];
                acc[ct] = __builtin_amdgcn_mfma_f32_16x16x32_f16(af[ks], bf, acc[ct], 0, 0, 0);
            }
        }

        #pragma unroll
        for (int ct = 0; ct < 6; ++ct) {
            #pragma unroll
            for (int r = 0; r < 4; ++r) {
                int lr = wave * 16 + quad * 4 + r;
                size_t row = row0 + lr;
                int lc = ct * 16 + lm;
                int col = ch * 96 + lc;
                float v = acc[ct][r] + bias[col];
                if constexpr (RES)     v += res[row * 96 + lc];
                if constexpr (ADDTIME) v += timev[lc];
                if constexpr (SILU)    v = v / (1.f + __expf(-v));
                if constexpr (OUTMODE == 0) {
                    ((float*)outp)[row * NTOT + col] = v;
                } else {
                    ((_Float16*)outp)[row * NTOT + col] = (_Float16)v;
                }
            }
        }
    }
}

// ---------------------------------------------------------------------------
// fused MLP (f16 input): 3 chained 96x96 GEMMs + silu, one kernel.
// ---------------------------------------------------------------------------
__global__ void __launch_bounds__(256) k_mlp_fused(const _Float16* __restrict__ A,
                                                   const _Float16* __restrict__ W,
                                                   const float* __restrict__ b0,
                                                   const float* __restrict__ b1,
                                                   const float* __restrict__ b2,
                                                   _Float16* __restrict__ outh)
{
    __shared__ __align__(16) _Float16 Ah[2][64 * 96];
    __shared__ __align__(16) _Float16 Wh[3][96 * 96];
    int t = threadIdx.x;
    size_t row0 = (size_t)blockIdx.x * 64;

    {
        const uint4* a4 = (const uint4*)(A + row0 * 96);
        uint4* dst = (uint4*)&Ah[0][0];
        for (int i = t; i < 768; i += 256) dst[i] = a4[i];
    }
    {
        const uint4* src = (const uint4*)W;
        uint4* dst = (uint4*)&Wh[0][0];
        for (int i = t; i < 3456; i += 256) dst[i] = src[i];
    }

    int wave = t >> 6, lane = t & 63;
    int lm = lane & 15, quad = lane >> 4;
    const float* biases[3] = { b0, b1, b2 };
    int cur = 0;

    #pragma unroll
    for (int s = 0; s < 3; ++s) {
        __syncthreads();
        half8 af[3];
        #pragma unroll
        for (int ks = 0; ks < 3; ++ks)
            af[ks] = *(const half8*)&Ah[cur][(wave * 16 + lm) * 96 + ks * 32 + quad * 8];

        f32x4 acc[6];
        #pragma unroll
        for (int ct = 0; ct < 6; ++ct) acc[ct] = (f32x4){0.f, 0.f, 0.f, 0.f};

        #pragma unroll
        for (int ct = 0; ct < 6; ++ct) {
            #pragma unroll
            for (int ks = 0; ks < 3; ++ks) {
                half8 bf = *(const half8*)&Wh[s][(ct * 16 + lm) * 96 + ks * 32 + quad * 8];
                acc[ct] = __builtin_amdgcn_mfma_f32_16x16x32_f16(af[ks], bf, acc[ct], 0, 0, 0);
            }
        }

        const float* bias = biases[s];
        if (s < 2) {
            #pragma unroll
            for (int ct = 0; ct < 6; ++ct) {
                #pragma unroll
                for (int r = 0; r < 4; ++r) {
                    int lr = wave * 16 + quad * 4 + r;
                    int lc = ct * 16 + lm;
                    float v = acc[ct][r] + bias[lc];
                    v = v / (1.f + __expf(-v));
                    Ah[cur ^ 1][lr * 96 + lc] = (_Float16)v;
                }
            }
            cur ^= 1;
        } else {
            #pragma unroll
            for (int ct = 0; ct < 6; ++ct) {
                #pragma unroll
                for (int r = 0; r < 4; ++r) {
                    int lr = wave * 16 + quad * 4 + r;
                    size_t row = row0 + lr;
                    int lc = ct * 16 + lm;
                    float v = acc[ct][r] + bias[lc];
                    v = v / (1.f + __expf(-v));
                    size_t b = row / NPATCH; int n = (int)(row % NPATCH);
                    int ny = n / 14, nx = n % 14;
                    outh[((b * 256) + (1 + ny) * 16 + (1 + nx)) * 96 + lc] = (_Float16)v;
                }
            }
        }
    }
}

// ---------------------------------------------------------------------------
// MFMA attention (r11 structure): qkv input f16, output f16.
// ---------------------------------------------------------------------------
__global__ void __launch_bounds__(256) k_attn_mfma(const _Float16* __restrict__ qkv,
                                                   _Float16* __restrict__ o)
{
    __shared__ __align__(16) _Float16 Qs[208 * 40];
    __shared__ __align__(16) _Float16 Ks[208 * 40];
    __shared__ __align__(16) _Float16 Vt[32 * 232];
    __shared__ __align__(16) _Float16 Pw[4][16 * 232];

    int t = threadIdx.x;
    int bh = blockIdx.x;
    int b = bh >> 2, h = bh & 3;
    const _Float16* base = qkv + (size_t)b * NPATCH * 288 + h * 24;

    {
        const int4 z = {0, 0, 0, 0};
        int4* q4 = (int4*)Qs; int4* k4 = (int4*)Ks;
        for (int i = t; i < 1040; i += 256) { q4[i] = z; k4[i] = z; }
        int4* v4 = (int4*)Vt;
        for (int i = t; i < 928; i += 256) v4[i] = z;
        int4* p4 = (int4*)&Pw[0][0];
        for (int i = t; i < 1856; i += 256) p4[i] = z;
    }
    __syncthreads();

    for (int i = t; i < NPATCH * 24; i += 256) {
        int r = i / 24, d = i % 24;
        const _Float16* row = base + (size_t)r * 288;
        Qs[r * 40 + d]   = row[d];
        Ks[r * 40 + d]   = row[96 + d];
        Vt[d * 232 + r]  = row[192 + d];
    }
    __syncthreads();

    int wave = t >> 6, lane = t & 63;
    int lm = lane & 15, quad = lane >> 4;
    const float scale = 0.2041241452319315f;

    half8 bk[13];
    #pragma unroll
    for (int ct = 0; ct < 13; ++ct)
        bk[ct] = *(const half8*)&Ks[(ct * 16 + lm) * 40 + quad * 8];

    _Float16* pw = &Pw[wave][0];

    for (int rt = wave; rt < 13; rt += 4) {
        half8 aq = *(const half8*)&Qs[(rt * 16 + lm) * 40 + quad * 8];
        float rsum[4] = {0.f, 0.f, 0.f, 0.f};

        #pragma unroll
        for (int ct = 0; ct < 13; ++ct) {
            f32x4 s = (f32x4){0.f, 0.f, 0.f, 0.f};
            s = __builtin_amdgcn_mfma_f32_16x16x32_f16(aq, bk[ct], s, 0, 0, 0);
            #pragma unroll
            for (int r = 0; r < 4; ++r) {
                float p = __expf(fminf(s[r] * scale, 60.f));
                if (ct == 12 && lm >= 4) p = 0.f;   // keys 196..207 invalid
                rsum[r] += p;
                pw[(quad * 4 + r) * 232 + ct * 16 + lm] = (_Float16)p;
            }
        }

        #pragma unroll
        for (int r = 0; r < 4; ++r) {
            float s = rsum[r];
            s += __shfl_xor(s, 1);
            s += __shfl_xor(s, 2);
            s += __shfl_xor(s, 4);
            s += __shfl_xor(s, 8);
            rsum[r] = 1.f / s;
        }

        f32x4 ov0 = (f32x4){0.f, 0.f, 0.f, 0.f};
        f32x4 ov1 = (f32x4){0.f, 0.f, 0.f, 0.f};
        #pragma unroll
        for (int ks = 0; ks < 7; ++ks) {
            half8 ap = *(const half8*)&pw[lm * 232 + ks * 32 + quad * 8];
            half8 bv0 = *(const half8*)&Vt[(lm) * 232 + ks * 32 + quad * 8];
            half8 bv1 = *(const half8*)&Vt[(16 + lm) * 232 + ks * 32 + quad * 8];
            ov0 = __builtin_amdgcn_mfma_f32_16x16x32_f16(ap, bv0, ov0, 0, 0, 0);
            ov1 = __builtin_amdgcn_mfma_f32_16x16x32_f16(ap, bv1, ov1, 0, 0, 0);
        }

        #pragma unroll
        for (int r = 0; r < 4; ++r) {
            int row = rt * 16 + quad * 4 + r;
            if (row < NPATCH) {
                _Float16* orow = o + ((size_t)b * NPATCH + row) * 96 + h * 24;
                orow[lm] = (_Float16)(ov0[r] * rsum[r]);
                if (lm < 8) orow[16 + lm] = (_Float16)(ov1[r] * rsum[r]);
            }
        }
    }
}

// ---------------------------------------------------------------------------
// conv L1, tile-resident + fused LN partial stats (r16, verified).
// ---------------------------------------------------------------------------
__global__ void __launch_bounds__(256) k_conv1_tile(const _Float16* __restrict__ xinh,
                                                    const _Float16* __restrict__ wc,
                                                    const float* __restrict__ bias,
                                                    _Float16* __restrict__ c1,
                                                    float* __restrict__ pstat1)
{
    __shared__ __align__(16) _Float16 Xs[4 * 16 * 104];   // 13.3 KB
    __shared__ float bins[96];
    int t = threadIdx.x;
    int blk = blockIdx.x;
    int b = blk / 7, s = blk % 7;

    if (t < 96) bins[t] = 0.f;

    for (int i = t; i < 768; i += 256) {
        int r = i / 192, rem = i % 192;
        int c = rem / 12, ch = (rem % 12) * 8;
        *(uint4*)&Xs[(r * 16 + c) * 104 + ch] =
            *(const uint4*)(xinh + ((size_t)(b * 256) + (2 * s + r) * 16 + c) * 96 + ch);
    }

    int wave = t >> 6, lane = t & 63;
    int lm = lane & 15, quad = lane >> 4;
    int ry = wave >> 1, rx = wave & 1;

    __syncthreads();

    for (int nt = 0; nt < 3; ++nt) {
        half8 bf[12];
        #pragma unroll
        for (int ks = 0; ks < 12; ++ks)
            bf[ks] = *(const half8*)&wc[((size_t)(wave * 48 + nt * 16 + lm)) * 384
                                        + ks * 32 + quad * 8];

        float sl = 0.f, ql = 0.f;
        #pragma unroll
        for (int rt = 0; rt < 2; ++rt) {
            int pp = rt * 16 + lm;
            int ppc = pp < 28 ? pp : 27;
            int pyl = ppc / 14, px = ppc % 14;

            half8 af[12];
            #pragma unroll
            for (int ks = 0; ks < 12; ++ks) {
                int k0 = ks * 32 + quad * 8;
                int tap = k0 / 96, off = k0 % 96;
                int dy = tap >> 1, dx = tap & 1;
                af[ks] = *(const half8*)&Xs[((pyl + ry + dy) * 16 + (px + rx + dx)) * 104 + off];
            }

            f32x4 acc = (f32x4){0.f, 0.f, 0.f, 0.f};
            #pragma unroll
            for (int ks = 0; ks < 12; ++ks)
                acc = __builtin_amdgcn_mfma_f32_16x16x32_f16(af[ks], bf[ks], acc, 0, 0, 0);

            #pragma unroll
            for (int r = 0; r < 4; ++r) {
                int pw = rt * 16 + quad * 4 + r;
                if (pw < 28) {
                    int pylw = pw / 14, pxw = pw % 14;
                    int oy = 2 * (2 * s + pylw) + ry, ox = 2 * pxw + rx;
                    float v = acc[r] + bias[nt * 16 + lm];
                    sl += v; ql += v * v;
                    c1[((size_t)(b * 28 + oy) * 28 + ox) * 48 + nt * 16 + lm] = (_Float16)v;
                }
            }
        }
        atomicAdd(&bins[(nt * 16 + lm) * 2],     sl);
        atomicAdd(&bins[(nt * 16 + lm) * 2 + 1], ql);
    }
    __syncthreads();
    if (t < 96) atomicAdd(&pstat1[(size_t)b * 96 + t], bins[t]);
}

// ---------------------------------------------------------------------------
// conv L2, tile-resident, LN1 fused into staging with per-block mu/rstd
// LDS table (bitwise-identical values, computed once per channel).
// ---------------------------------------------------------------------------
__global__ void __launch_bounds__(256) k_conv2_tile(const _Float16* __restrict__ c1,
                                                    const float* __restrict__ pstat1,
                                                    const float* __restrict__ g1,
                                                    const float* __restrict__ b1v,
                                                    const _Float16* __restrict__ wc,
                                                    const float* __restrict__ bias,
                                                    _Float16* __restrict__ c2,
                                                    float* __restrict__ pstat2)
{
    __shared__ __align__(16) _Float16 Xs[4 * 30 * 56];   // 13.1 KB
    __shared__ float bins[48];
    __shared__ float mr[96];                              // mu,rstd x48
    int t = threadIdx.x;
    int blk = blockIdx.x;
    int b = blk / 14, s = blk % 14;

    if (t < 48) {
        bins[t] = 0.f;
        float su = pstat1[(size_t)b * 96 + t * 2];
        float sq = pstat1[(size_t)b * 96 + t * 2 + 1];
        float mu = su * (1.f / 784.f);
        mr[t * 2]     = mu;
        mr[t * 2 + 1] = rsqrtf(sq * (1.f / 784.f) - mu * mu + 1e-5f);
    }
    __syncthreads();

    for (int i = t; i < 720; i += 256) {
        int r = i / 180, rem = i % 180;
        int c = rem / 6, ch0 = (rem % 6) * 8;
        int py = 2 * s + r, px = c;
        half8 hv;
        if (py >= 1 && py <= 28 && px >= 1 && px <= 28) {
            int j = (py - 1) * 28 + (px - 1);
            half8 v = *(const half8*)&c1[((size_t)b * 784 + j) * 48 + ch0];
            float gj = g1[j], bj = b1v[j];
            #pragma unroll
            for (int k = 0; k < 8; ++k) {
                float mu = mr[(ch0 + k) * 2];
                float rstd = mr[(ch0 + k) * 2 + 1];
                float u = ((float)v[k] - mu) * rstd * gj + bj;
                hv[k] = (_Float16)(u / (1.f + __expf(-u)));
            }
        } else {
            #pragma unroll
            for (int k = 0; k < 8; ++k) hv[k] = (_Float16)0.f;
        }
        *(half8*)&Xs[(r * 30 + c) * 56 + ch0] = hv;
    }

    int wave = t >> 6, lane = t & 63;
    int lm = lane & 15, quad = lane >> 4;
    int ry = wave >> 1, rx = wave & 1;

    half8 bf0[6], bf1[6];
    #pragma unroll
    for (int ks = 0; ks < 6; ++ks) {
        bf0[ks] = *(const half8*)&wc[((size_t)(wave * 32 + lm)) * 192 + ks * 32 + quad * 8];
        bf1[ks] = *(const half8*)&wc[((size_t)(wave * 32 + 16 + lm)) * 192 + ks * 32 + quad * 8];
    }

    __syncthreads();

    float s0l = 0.f, q0l = 0.f, s1l = 0.f, q1l = 0.f;
    #pragma unroll
    for (int rt = 0; rt < 4; ++rt) {
        int pp = rt * 16 + lm;
        int ppc = pp < 56 ? pp : 55;
        int pyl = ppc / 28, px = ppc % 28;

        half8 af[6];
        #pragma unroll
        for (int ks = 0; ks < 6; ++ks) {
            int k0 = ks * 32 + quad * 8;
            int tap = k0 / 48, off = k0 % 48;
            int dy = tap >> 1, dx = tap & 1;
            af[ks] = *(const half8*)&Xs[((pyl + ry + dy) * 30 + (px + rx + dx)) * 56 + off];
        }

        f32x4 acc0 = (f32x4){0.f, 0.f, 0.f, 0.f};
        f32x4 acc1 = (f32x4){0.f, 0.f, 0.f, 0.f};
        #pragma unroll
        for (int ks = 0; ks < 6; ++ks) {
            acc0 = __builtin_amdgcn_mfma_f32_16x16x32_f16(af[ks], bf0[ks], acc0, 0, 0, 0);
            acc1 = __builtin_amdgcn_mfma_f32_16x16x32_f16(af[ks], bf1[ks], acc1, 0, 0, 0);
        }

        #pragma unroll
        for (int r = 0; r < 4; ++r) {
            int pw = rt * 16 + quad * 4 + r;
            if (pw < 56) {
                int pylw = pw / 28, pxw = pw % 28;
                int oy = 2 * (2 * s + pylw) + ry, ox = 2 * pxw + rx;
                _Float16* orow = c2 + ((size_t)(b * 56 + oy) * 56 + ox) * 24;
                float v0 = acc0[r] + bias[lm];
                orow[lm] = (_Float16)v0;
                s0l += v0; q0l += v0 * v0;
                if (lm < 8) {
                    float v1 = acc1[r] + bias[16 + lm];
                    orow[16 + lm] = (_Float16)v1;
                    s1l += v1; q1l += v1 * v1;
                }
            }
        }
    }
    atomicAdd(&bins[lm * 2],     s0l);
    atomicAdd(&bins[lm * 2 + 1], q0l);
    if (lm < 8) {
        atomicAdd(&bins[(16 + lm) * 2],     s1l);
        atomicAdd(&bins[(16 + lm) * 2 + 1], q1l);
    }
    __syncthreads();
    if (t < 48) atomicAdd(&pstat2[(size_t)b * 48 + t], bins[t]);
}

// ---------------------------------------------------------------------------
// conv L3, tile-resident, LN2 fused into staging: 2 output strips/block
// (grid B*28), stage 4 rows, per-block mu/rstd LDS table.
// ---------------------------------------------------------------------------
__global__ void __launch_bounds__(256) k_conv3_tile(const _Float16* __restrict__ c2,
                                                    const float* __restrict__ pstat2,
                                                    const float* __restrict__ g2,
                                                    const float* __restrict__ b2v,
                                                    const _Float16* __restrict__ wc,
                                                    const float* __restrict__ bias,
                                                    _Float16* __restrict__ c3,
                                                    float* __restrict__ pstat3)
{
    __shared__ __align__(16) _Float16 Xs[4 * 58 * 40];   // 18.6 KB
    __shared__ float bins[24];
    __shared__ float mr[48];                              // mu,rstd x24
    int t = threadIdx.x;
    int blk = blockIdx.x;
    int b = blk / 28, s = blk % 28;   // conv-center rows 2s, 2s+1

    if (t < 24) {
        bins[t] = 0.f;
        float su = pstat2[(size_t)b * 48 + t * 2];
        float sq = pstat2[(size_t)b * 48 + t * 2 + 1];
        float mu = su * (1.f / 3136.f);
        mr[t * 2]     = mu;
        mr[t * 2 + 1] = rsqrtf(sq * (1.f / 3136.f) - mu * mu + 1e-5f);
    }
    __syncthreads();

    // stage rows 2s..2s+3, 58 cols, 24 ch: 696 items (8 ch each)
    for (int i = t; i < 696; i += 256) {
        int r = i / 174, rem = i % 174;
        int c = rem / 3, ch0 = (rem % 3) * 8;
        int py = 2 * s + r, px = c;
        half8 hv;
        if (py >= 1 && py <= 56 && px >= 1 && px <= 56) {
            int j = (py - 1) * 56 + (px - 1);
            half8 v = *(const half8*)&c2[((size_t)b * 3136 + j) * 24 + ch0];
            float gj = g2[j], bj = b2v[j];
            #pragma unroll
            for (int k = 0; k < 8; ++k) {
                float mu = mr[(ch0 + k) * 2];
                float rstd = mr[(ch0 + k) * 2 + 1];
                float u = ((float)v[k] - mu) * rstd * gj + bj;
                hv[k] = (_Float16)(u / (1.f + __expf(-u)));
            }
        } else {
            #pragma unroll
            for (int k = 0; k < 8; ++k) hv[k] = (_Float16)0.f;
        }
        *(half8*)&Xs[(r * 58 + c) * 40 + ch0] = hv;
    }

    int wave = t >> 6, lane = t & 63;
    int lm = lane & 15, quad = lane >> 4;
    int ry = wave >> 1, rx = wave & 1;

    half8 bf[3];
    #pragma unroll
    for (int ks = 0; ks < 3; ++ks)
        bf[ks] = *(const half8*)&wc[((size_t)(wave * 16 + lm)) * 96 + ks * 32 + quad * 8];

    __syncthreads();

    float sl = 0.f, ql = 0.f;
    #pragma unroll
    for (int orow = 0; orow < 2; ++orow) {
        #pragma unroll
        for (int rt = 0; rt < 4; ++rt) {
            int px = rt * 16 + lm;
            int pxc = px < 56 ? px : 55;

            half8 af[3];
            #pragma unroll
            for (int ks = 0; ks < 3; ++ks) {
                int k0 = ks * 32 + quad * 8;
                int tap = k0 / 24, off = k0 % 24;
                int dy = tap >> 1, dx = tap & 1;
                af[ks] = *(const half8*)&Xs[((orow + ry + dy) * 58 + (pxc + rx + dx)) * 40 + off];
            }

            f32x4 acc = (f32x4){0.f, 0.f, 0.f, 0.f};
            #pragma unroll
            for (int ks = 0; ks < 3; ++ks)
                acc = __builtin_amdgcn_mfma_f32_16x16x32_f16(af[ks], bf[ks], acc, 0, 0, 0);

            if (lm < 12) {
                #pragma unroll
                for (int r = 0; r < 4; ++r) {
                    int pw = rt * 16 + quad * 4 + r;
                    if (pw < 56) {
                        int oy = 2 * (2 * s + orow) + ry, ox = 2 * pw + rx;
                        float v = acc[r] + bias[lm];
                        sl += v; ql += v * v;
                        c3[((size_t)(b * 112 + oy) * 112 + ox) * 12 + lm] = (_Float16)v;
                    }
                }
            }
        }
    }
    if (lm < 12) {
        atomicAdd(&bins[lm * 2],     sl);
        atomicAdd(&bins[lm * 2 + 1], ql);
    }
    __syncthreads();
    if (t < 24) atomicAdd(&pstat3[(size_t)b * 24 + t], bins[t]);
}

// ---------------------------------------------------------------------------
// final convT 12->1, LN3 fused into staging with per-block mu/rstd table.
// grid 7168.
// ---------------------------------------------------------------------------
__global__ void __launch_bounds__(256) k_conv_final3(const _Float16* __restrict__ c3,
                                                     const float* __restrict__ pstat3,
                                                     const float* __restrict__ g3,
                                                     const float* __restrict__ b3v,
                                                     const _Float16* __restrict__ wcf,
                                                     const float* __restrict__ bias,
                                                     float* __restrict__ out)
{
    constexpr int HIN = 112, CIN = 12;
    __shared__ __align__(16) _Float16 Xs[4 * 114 * 12];   // 10.9 KB
    __shared__ __align__(16) _Float16 Wl[192];
    __shared__ float mr[24];                               // mu,rstd x12
    int t = threadIdx.x;
    int blk = blockIdx.x;
    int b = blk / 56, s = blk % 56;
    int py0 = 2 * s;

    {
        const int4 z = {0, 0, 0, 0};
        int4* p4 = (int4*)Xs;
        for (int i = t; i < 684; i += 256) p4[i] = z;
        if (t < 24) *(int4*)&Wl[t * 8] = *(const int4*)&wcf[t * 8];
        if (t >= 32 && t < 44) {
            int ch = t - 32;
            float su = pstat3[(size_t)b * 24 + ch * 2];
            float sq = pstat3[(size_t)b * 24 + ch * 2 + 1];
            float mu = su * (1.f / 12544.f);
            mr[ch * 2]     = mu;
            mr[ch * 2 + 1] = rsqrtf(sq * (1.f / 12544.f) - mu * mu + 1e-5f);
        }
    }
    __syncthreads();
    // stage rows py0-1 .. py0+2, 2 pixels (24 halves) per item, LN+silu fused
    if (t < 224) {
        int r = t / 56, u = t % 56;
        int row = py0 - 1 + r;
        if (row >= 0 && row < HIN) {
            size_t base = ((size_t)b * 12544 + (size_t)row * 112 + 2 * u) * 12;
            half4v v0 = *(const half4v*)&c3[base];
            half4v v1 = *(const half4v*)&c3[base + 4];
            half4v v2 = *(const half4v*)&c3[base + 8];
            half4v v3 = *(const half4v*)&c3[base + 12];
            half4v v4 = *(const half4v*)&c3[base + 16];
            half4v v5 = *(const half4v*)&c3[base + 20];
            int j0 = row * 112 + 2 * u;
            float ga = g3[j0], ba = b3v[j0];
            float gb = g3[j0 + 1], bb2 = b3v[j0 + 1];
            _Float16 ov[24];
            #pragma unroll
            for (int k = 0; k < 24; ++k) {
                int ch = (k < 12) ? k : k - 12;
                float mu = mr[ch * 2];
                float rstd = mr[ch * 2 + 1];
                float vv;
                if      (k < 4)  vv = (float)v0[k];
                else if (k < 8)  vv = (float)v1[k - 4];
                else if (k < 12) vv = (float)v2[k - 8];
                else if (k < 16) vv = (float)v3[k - 12];
                else if (k < 20) vv = (float)v4[k - 16];
                else             vv = (float)v5[k - 20];
                float gk = (k < 12) ? ga : gb;
                float bk = (k < 12) ? ba : bb2;
                float u2 = (vv - mu) * rstd * gk + bk;
                ov[k] = (_Float16)(u2 / (1.f + __expf(-u2)));
            }
            _Float16* dst = &Xs[(size_t)r * 1368 + u * 24];
            *(half8*)&dst[0]  = *(half8*)&ov[0];
            *(half8*)&dst[8]  = *(half8*)&ov[8];
            *(half8*)&dst[16] = *(half8*)&ov[16];
        }
    }
    __syncthreads();

    if (t >= 224) return;
    int pyl = t / 112;
    int px = t % 112;
    int py = py0 + pyl;

    half2v tvp[9][6];
    #pragma unroll
    for (int a = 0; a < 3; ++a) {
        int lr = pyl + a;
        #pragma unroll
        for (int c = 0; c < 3; ++c) {
            int col = px - 1 + c;
            int cs = (col < 0) ? 113 : col;
            const _Float16* p = &Xs[((size_t)lr * 114 + cs) * 12];
            half4v h0 = *(const half4v*)&p[0];
            half4v h1 = *(const half4v*)&p[4];
            half4v h2 = *(const half4v*)&p[8];
            int ti = a * 3 + c;
            tvp[ti][0] = (half2v){h0[0], h0[1]};
            tvp[ti][1] = (half2v){h0[2], h0[3]};
            tvp[ti][2] = (half2v){h1[0], h1[1]};
            tvp[ti][3] = (half2v){h1[2], h1[3]};
            tvp[ti][4] = (half2v){h2[0], h2[1]};
            tvp[ti][5] = (half2v){h2[2], h2[3]};
        }
    }

    float bb = bias[0];
    float* ob = out + (size_t)b * 50176;
    #pragma unroll
    for (int ry = 0; ry < 2; ++ry) {
        float res[2];
        #pragma unroll
        for (int rx = 0; rx < 2; ++rx) {
            int p = ry * 2 + rx;
            float acc = 0.f;
            #pragma unroll
            for (int dy = 0; dy < 2; ++dy) {
                #pragma unroll
                for (int dx = 0; dx < 2; ++dx) {
                    int j = dy * 2 + dx;
                    int ti = (ry + dy) * 3 + (rx + dx);
                    const half2v* wp = (const half2v*)&Wl[(p * 4 + j) * 12];
                    #pragma unroll
                    for (int k = 0; k < 6; ++k)
                        acc = __builtin_amdgcn_fdot2(tvp[ti][k], wp[k], acc, false);
                }
            }
            float u = acc + bb;
            u = u / (1.f + __expf(-u));
            res[rx] = fminf(fmaxf(u, 0.f), 1.f);
        }
        float2 v; v.x = res[0]; v.y = res[1];
        *(float2*)(ob + (size_t)(2 * py + ry) * 224 + 2 * px) = v;
    }
}

// ---------------------------------------------------------------------------
// launch
// ---------------------------------------------------------------------------
extern "C" void kernel_launch(void* const* d_in, const int* in_sizes, int n_in,
                              void* d_out, int out_size, void* d_ws, size_t ws_size,
                              hipStream_t stream)
{
    const float* x       = (const float*)d_in[0];
    const float* ts      = (const float*)d_in[1];
    const float* Wp      = (const float*)d_in[2];
    const float* bp      = (const float*)d_in[3];
    const float* Wt1     = (const float*)d_in[4];
    const float* bt1     = (const float*)d_in[5];
    const float* Wt2     = (const float*)d_in[6];
    const float* bt2     = (const float*)d_in[7];
    const float* a0_g    = (const float*)d_in[8];
    const float* a0_b    = (const float*)d_in[9];
    const float* a0_Wqkv = (const float*)d_in[10];
    const float* a0_bqkv = (const float*)d_in[11];
    const float* a0_Wo   = (const float*)d_in[12];
    const float* a0_bo   = (const float*)d_in[13];
    const float* a1_g    = (const float*)d_in[14];
    const float* a1_b    = (const float*)d_in[15];
    const float* a1_Wqkv = (const float*)d_in[16];
    const float* a1_bqkv = (const float*)d_in[17];
    const float* a1_Wo   = (const float*)d_in[18];
    const float* a1_bo   = (const float*)d_in[19];
    const float* Wm0     = (const float*)d_in[20];
    const float* bm0     = (const float*)d_in[21];
    const float* Wm1     = (const float*)d_in[22];
    const float* bm1     = (const float*)d_in[23];
    const float* Wm2     = (const float*)d_in[24];
    const float* bm2     = (const float*)d_in[25];
    const float* Wd1     = (const float*)d_in[26];
    const float* bd1     = (const float*)d_in[27];
    const float* l1g     = (const float*)d_in[28];
    const float* l1b     = (const float*)d_in[29];
    const float* Wd2     = (const float*)d_in[30];
    const float* bd2     = (const float*)d_in[31];
    const float* l2g     = (const float*)d_in[32];
    const float* l2b     = (const float*)d_in[33];
    const float* Wd3     = (const float*)d_in[34];
    const float* bd3     = (const float*)d_in[35];
    const float* l3g     = (const float*)d_in[36];
    const float* l3b     = (const float*)d_in[37];
    const float* Wd4     = (const float*)d_in[38];
    const float* bd4     = (const float*)d_in[39];
    float* out = (float*)d_out;

    // arena (floats); R = 25088*96
    const size_t R = 2408448;
    float* ws   = (float*)d_ws;
    float* tvec = ws;                          // 96
    float* p0   = ws + 512;                    // R (fp32 residual; f16 alias p0h)
    _Float16* p0h  = (_Float16*)(ws + 512);           // f16 wo1 out (p0 region)
    _Float16* hh   = (_Float16*)(ws + 512 + R);       // f16 LN out (h region)
    _Float16* qkvh = (_Float16*)(ws + 512 + 2 * R);   // f16 qkv [M][288]
    _Float16* obh  = (_Float16*)(ws + 512 + 5 * R);   // f16 attn out (ob region)
    float* p1   = ws + 512 + 6 * R;            // R
    // decoder aliases:
    _Float16* xinh = (_Float16*)(ws + 512 + 2 * R);   // f16 NHWC (qkv region)
    _Float16* C1h  = (_Float16*)(ws + 512 + 5 * R);   // f16 NHWC [b][28][28][48]
    _Float16* C2h  = (_Float16*)(ws + 512);           // f16 NHWC [b][56][56][24]
    _Float16* C3h  = (_Float16*)(ws + 512 + 7 * R + 5529600); // f16 NHWC [b][112][112][12]
    float* Wr   = ws + 512 + 7 * R + 5529600 + 10334208;  // 96,960 floats
    _Float16* WH = (_Float16*)(Wr + 96960);                // 101,376 halves
    _Float16* Wc  = (_Float16*)Wr;
    _Float16* Wc2 = (_Float16*)(Wr + 36864);
    _Float16* Wc3 = (_Float16*)(Wr + 49152);
    float* stat = Wr + 96960 + 50688;          // 21,504 floats (raw LN sums)
    float* stat1 = stat;                       // 128*96
    float* stat2 = stat + 12288;               // 128*48
    float* stat3 = stat + 18432;               // 128*24
    _Float16* Wcf = (_Float16*)(stat + 21504); // 192 halves (conv_final f16 w)
    _Float16* Wph = (_Float16*)(stat + 21504 + 128); // 24576 halves (patch f16 w)
    const size_t NEED = (512 + 7 * R + 5529600 + 10334208 + 96960 + 50688 + 21504
                         + 128 + 12288 + 16) * sizeof(float);
    if (ws_size < NEED) return;

    _Float16* WHqkv0 = WH;
    _Float16* WHqkv1 = WH + 27648;
    _Float16* WHwo0  = WH + 55296;
    _Float16* WHwo1  = WH + 64512;
    _Float16* WHwm0  = WH + 73728;   // wm0,wm1,wm2 consecutive

    k_time<<<1, 128, 0, stream>>>(ts, Wt1, bt1, Wt2, bt2, tvec);
    k_zstat<<<84, 256, 0, stream>>>(stat);
    k_repack<<<379, 256, 0, stream>>>(Wd1, Wd2, Wd3, Wd4, Wr);
    k_wcvt4<<<1, 192, 0, stream>>>(Wr + 96768, Wcf);
    k_wcvtp<<<96, 256, 0, stream>>>(Wp, Wph);
    k_wcvtc<<<288, 256, 0, stream>>>(Wd1, Wc);
    k_wcvt2<<<96, 256, 0, stream>>>(Wd2, Wc2);
    k_wcvt3<<<24, 256, 0, stream>>>(Wd3, Wc3);
    k_wcvt<<<396, 256, 0, stream>>>(a0_Wqkv, a1_Wqkv, a0_Wo, a1_Wo,
                                    Wm0, Wm1, Wm2, WH);
    k_patch_mfma<<<M_ROWS / 32, 256, 0, stream>>>(x, Wph, bp, p0);

    // MHSA block 0
    k_ln_row<<<1024, 256, 0, stream>>>(p0, a0_g, a0_b, hh, M_ROWS);
    k_gemm_mfma<3, 1, false, false, false, true><<<dim3(M_ROWS / 64, 3), 256, 0, stream>>>(
        hh, WHqkv0, a0_bqkv, nullptr, nullptr, qkvh);
    k_attn_mfma<<<B_ * 4, 256, 0, stream>>>(qkvh, obh);
    k_gemm_mfma<1, 0, false, true, false, true><<<dim3(M_ROWS / 64, 1), 256, 0, stream>>>(
        obh, WHwo0, a0_bo, p0, nullptr, p1);

    // MHSA block 1 (+time)
    k_ln_row<<<1024, 256, 0, stream>>>(p1, a1_g, a1_b, hh, M_ROWS);
    k_gemm_mfma<3, 1, false, false, false, true><<<dim3(M_ROWS / 64, 3), 256, 0, stream>>>(
        hh, WHqkv1, a1_bqkv, nullptr, nullptr, qkvh);
    k_attn_mfma<<<B_ * 4, 256, 0, stream>>>(qkvh, obh);
    // wo1 + residual + time -> f16 p0h (only consumer: MLP)
    k_gemm_mfma<1, 1, false, true, true, true><<<dim3(M_ROWS / 64, 1), 256, 0, stream>>>(
        obh, WHwo1, a1_bo, p1, tvec, p0h);

    // qkv region free: zero xinh borders before MLP writes interior
    k_zb_h<<<2880, 256, 0, stream>>>(xinh);

    // fused MLP x3 (silu); writes f16 NHWC padded xinh
    k_mlp_fused<<<M_ROWS / 64, 256, 0, stream>>>(p0h, WHwm0, bm0, bm1, bm2, xinh);

    // decoder: conv chain with fused LN stats (producer) + LN apply (consumer)
    k_conv1_tile<<<B_ * 7, 256, 0, stream>>>(xinh, Wc, bd1, C1h, stat1);
    k_conv2_tile<<<B_ * 14, 256, 0, stream>>>(C1h, stat1, l1g, l1b, Wc2, bd2, C2h, stat2);
    k_conv3_tile<<<B_ * 28, 256, 0, stream>>>(C2h, stat2, l2g, l2b, Wc3, bd3, C3h, stat3);
    k_conv_final3<<<7168, 256, 0, stream>>>(C3h, stat3, l3g, l3b, Wcf, bd4, out);
}

// Round 15
// 400.894 us; speedup vs baseline: 1.2052x; 1.0188x over previous
//
#include <hip/hip_runtime.h>
#include <cmath>

// ---------------------------------------------------------------------------
// TimestepVisionTransformer — Round 23: conv_final VALU diet.
//   - k_conv_final4: 4 output rows/block (grid 3584), stage 6 rows ->
//     LN+silu amplification 2x -> 1.5x, half the block overhead.
//   - rcp-based silu (u * v_rcp(1+exp(-u))) in conv2/conv3/final staging
//     and final epilogue (error ~1e-7 << f16 ulp).
// Everything else = r22 (verified, 408.4us best).
// B=128, IMG=224, P=16, C_IN=1, E=96, H=4, d=24, NAX=14, N=196, M=B*N=25088
// ---------------------------------------------------------------------------

#define B_   128
#define NPATCH 196
#define M_ROWS (B_*NPATCH)     // 25088
#define E_   96

typedef _Float16 half8 __attribute__((ext_vector_type(8)));
typedef _Float16 half4v __attribute__((ext_vector_type(4)));
typedef _Float16 half2v __attribute__((ext_vector_type(2)));
typedef float f32x4 __attribute__((ext_vector_type(4)));

__device__ __forceinline__ float silu_fast(float u)
{
    return u * __builtin_amdgcn_rcpf(1.f + __expf(-u));
}

// ---------------------------------------------------------------------------
// time embedding
// ---------------------------------------------------------------------------
__global__ void k_time(const float* __restrict__ ts,
                       const float* __restrict__ Wt1, const float* __restrict__ bt1,
                       const float* __restrict__ Wt2, const float* __restrict__ bt2,
                       float* __restrict__ timev)
{
    __shared__ float h[128];
    float e = 0.69314718055994530942f * ts[0];
    float sv = sinf(e), cv = cosf(e);
    int t = threadIdx.x;
    float z = sv * Wt1[t] + cv * Wt1[128 + t] + bt1[t];
    h[t] = z / (1.f + expf(-z));
    __syncthreads();
    if (t < 96) {
        float acc = bt2[t];
        for (int j = 0; j < 128; ++j) acc += h[j] * Wt2[j * 96 + t];
        timev[t] = acc;
    }
}

// ---------------------------------------------------------------------------
// zero LN partial-stat table (21504 floats)
// ---------------------------------------------------------------------------
__global__ void __launch_bounds__(256) k_zstat(float* __restrict__ stat)
{
    int i = blockIdx.x * 256 + threadIdx.x;
    if (i < 21504) stat[i] = 0.f;
}

// ---------------------------------------------------------------------------
// weight repack (fp32 per-parity taps). L4 slice [96768,96960) feeds k_wcvt4;
// other slices overwritten by f16 packs.
// ---------------------------------------------------------------------------
__global__ void __launch_bounds__(256) k_repack(const float* __restrict__ w1,
                                                const float* __restrict__ w2,
                                                const float* __restrict__ w3,
                                                const float* __restrict__ w4f,
                                                float* __restrict__ wr)
{
    int i = blockIdx.x * 256 + threadIdx.x;
    const float* src; int CIN, COUT, e; float* dst;
    if      (i < 73728) { src = w1;  CIN = 96; COUT = 48; e = i;          dst = wr; }
    else if (i < 92160) { src = w2;  CIN = 48; COUT = 24; e = i - 73728;  dst = wr + 73728; }
    else if (i < 96768) { src = w3;  CIN = 24; COUT = 12; e = i - 92160;  dst = wr + 92160; }
    else if (i < 96960) { src = w4f; CIN = 12; COUT = 1;  e = i - 96768;  dst = wr + 96768; }
    else return;
    int per = CIN * COUT * 4;
    int par = e / per, rem = e % per;
    int ci = rem / (COUT * 4);
    int o  = (rem >> 2) % COUT;
    int j  = rem & 3;
    int ry = par >> 1, rx = par & 1;
    int wy = (j < 2)  ? (3 - ry) : (1 - ry);
    int wx = (j & 1)  ? (1 - rx) : (3 - rx);
    dst[e] = src[(ci * COUT + o) * 16 + wy * 4 + wx];
}

// ---------------------------------------------------------------------------
// conv_final weights -> f16 wcf[p][j][ci] (192 halves) from fp32 [p][ci][j]
// ---------------------------------------------------------------------------
__global__ void k_wcvt4(const float* __restrict__ wr4,
                        _Float16* __restrict__ wcf)
{
    int i = threadIdx.x;
    if (i >= 192) return;
    int p = i / 48, rem = i % 48;
    int j = rem / 12, ci = rem % 12;
    wcf[(p * 4 + j) * 12 + ci] = (_Float16)wr4[p * 48 + ci * 4 + j];
}

// ---------------------------------------------------------------------------
// patch weights -> f16 wph[kc][e][k] (24576 halves), k in [0,128)
// ---------------------------------------------------------------------------
__global__ void __launch_bounds__(256) k_wcvtp(const float* __restrict__ Wp,
                                               _Float16* __restrict__ wph)
{
    int i = blockIdx.x * 256 + threadIdx.x;
    if (i >= 24576) return;
    int kc = i / 12288, rem = i % 12288;
    int e = rem / 128, k = rem % 128;
    wph[i] = (_Float16)Wp[e * 256 + kc * 128 + k];
}

// ---------------------------------------------------------------------------
// conv1 weights -> f16 B-layout Wc[p][o][k=tap*96+ci]
// ---------------------------------------------------------------------------
__global__ void __launch_bounds__(256) k_wcvtc(const float* __restrict__ w1,
                                               _Float16* __restrict__ wc)
{
    int i = blockIdx.x * 256 + threadIdx.x;
    if (i >= 4 * 48 * 384) return;
    int p = i / 18432, rem = i % 18432;
    int o = rem / 384, k = rem % 384;
    int tap = k / 96, ci = k % 96;
    int ry = p >> 1, rx = p & 1;
    int wy = (tap < 2) ? (3 - ry) : (1 - ry);
    int wx = (tap & 1) ? (1 - rx) : (3 - rx);
    wc[i] = (_Float16)w1[(ci * 48 + o) * 16 + wy * 4 + wx];
}

// ---------------------------------------------------------------------------
// conv2 weights -> f16 B-layout Wc2[p][o(32, o>=24 zero)][k=tap*48+ci]
// ---------------------------------------------------------------------------
__global__ void __launch_bounds__(256) k_wcvt2(const float* __restrict__ w2,
                                               _Float16* __restrict__ wc2)
{
    int i = blockIdx.x * 256 + threadIdx.x;
    if (i >= 4 * 32 * 192) return;
    int p = i / 6144, rem = i % 6144;
    int o = rem / 192, k = rem % 192;
    int tap = k / 48, ci = k % 48;
    int ry = p >> 1, rx = p & 1;
    int wy = (tap < 2) ? (3 - ry) : (1 - ry);
    int wx = (tap & 1) ? (1 - rx) : (3 - rx);
    wc2[i] = (o < 24) ? (_Float16)w2[(ci * 24 + o) * 16 + wy * 4 + wx]
                      : (_Float16)0.f;
}

// ---------------------------------------------------------------------------
// conv3 weights -> f16 B-layout Wc3[p][o(16, o>=12 zero)][k=tap*24+ci]
// ---------------------------------------------------------------------------
__global__ void __launch_bounds__(256) k_wcvt3(const float* __restrict__ w3,
                                               _Float16* __restrict__ wc3)
{
    int i = blockIdx.x * 256 + threadIdx.x;
    if (i >= 4 * 16 * 96) return;
    int p = i / 1536, rem = i % 1536;
    int o = rem / 96, k = rem % 96;
    int tap = k / 24, ci = k % 24;
    int ry = p >> 1, rx = p & 1;
    int wy = (tap < 2) ? (3 - ry) : (1 - ry);
    int wx = (tap & 1) ? (1 - rx) : (3 - rx);
    wc3[i] = (o < 12) ? (_Float16)w3[(ci * 12 + o) * 16 + wy * 4 + wx]
                      : (_Float16)0.f;
}

// ---------------------------------------------------------------------------
// transformer weight convert+transpose to half: Wt[n][k] = W[k][n]
// ---------------------------------------------------------------------------
__global__ void __launch_bounds__(256) k_wcvt(const float* __restrict__ qkv0,
                                              const float* __restrict__ qkv1,
                                              const float* __restrict__ wo0,
                                              const float* __restrict__ wo1,
                                              const float* __restrict__ wm0,
                                              const float* __restrict__ wm1,
                                              const float* __restrict__ wm2,
                                              _Float16* __restrict__ wh)
{
    int i = blockIdx.x * 256 + threadIdx.x;
    const float* src; int N; int e;
    if      (i < 27648)  { src = qkv0; N = 288; e = i; }
    else if (i < 55296)  { src = qkv1; N = 288; e = i - 27648; }
    else if (i < 64512)  { src = wo0;  N = 96;  e = i - 55296; }
    else if (i < 73728)  { src = wo1;  N = 96;  e = i - 64512; }
    else if (i < 82944)  { src = wm0;  N = 96;  e = i - 73728; }
    else if (i < 92160)  { src = wm1;  N = 96;  e = i - 82944; }
    else if (i < 101376) { src = wm2;  N = 96;  e = i - 92160; }
    else return;
    int n = e / 96, k = e % 96;
    wh[i] = (_Float16)src[k * N + n];
}

// ---------------------------------------------------------------------------
// zero the borders of xinh NHWC f16 [b][16][16][96]
// ---------------------------------------------------------------------------
__global__ void __launch_bounds__(256) k_zb_h(_Float16* __restrict__ xinh)
{
    int i = blockIdx.x * 256 + threadIdx.x;
    if (i >= 128 * 60 * 96) return;
    int b = i / 5760, r = i % 5760;
    int pos = r / 96, ch = r % 96;
    int py, px;
    if      (pos < 16) { py = 0;        px = pos; }
    else if (pos < 32) { py = 15;       px = pos - 16; }
    else if (pos < 46) { py = pos - 31; px = 0; }
    else               { py = pos - 45; px = 15; }
    xinh[((size_t)(b * 256) + py * 16 + px) * 96 + ch] = (_Float16)0.f;
}

// ---------------------------------------------------------------------------
// patch embed GEMM, occupancy-fixed (r20, verified): 32 patches/block.
// ---------------------------------------------------------------------------
__global__ void __launch_bounds__(256) k_patch_mfma(const float* __restrict__ x,
                                                    const _Float16* __restrict__ wph,
                                                    const float* __restrict__ bp,
                                                    float* __restrict__ out)
{
    __shared__ __align__(16) _Float16 Ah[32 * 136];
    __shared__ __align__(16) _Float16 Wh[96 * 136];
    int t = threadIdx.x;
    int p0 = blockIdx.x * 32;
    int wave = t >> 6, lane = t & 63;
    int lm = lane & 15, quad = lane >> 4;
    int rt = wave >> 1, nh = wave & 1;
    f32x4 acc[3];
    #pragma unroll
    for (int nt = 0; nt < 3; ++nt) acc[nt] = (f32x4){0.f, 0.f, 0.f, 0.f};

    for (int kc = 0; kc < 2; ++kc) {
        __syncthreads();
        {
            int lp = t >> 3, pyl = t & 7;
            int patch = p0 + lp;
            int b = patch / NPATCH, n = patch % NPATCH;
            int ny = n / 14, nx = n % 14;
            const float4* s4 = (const float4*)(x +
                ((size_t)(b * 224) + ny * 16 + kc * 8 + pyl) * 224 + nx * 16);
            float4 v0 = s4[0], v1 = s4[1], v2 = s4[2], v3 = s4[3];
            half8 h0, h1;
            h0[0]=(_Float16)v0.x; h0[1]=(_Float16)v0.y; h0[2]=(_Float16)v0.z; h0[3]=(_Float16)v0.w;
            h0[4]=(_Float16)v1.x; h0[5]=(_Float16)v1.y; h0[6]=(_Float16)v1.z; h0[7]=(_Float16)v1.w;
            h1[0]=(_Float16)v2.x; h1[1]=(_Float16)v2.y; h1[2]=(_Float16)v2.z; h1[3]=(_Float16)v2.w;
            h1[4]=(_Float16)v3.x; h1[5]=(_Float16)v3.y; h1[6]=(_Float16)v3.z; h1[7]=(_Float16)v3.w;
            *(half8*)&Ah[lp * 136 + pyl * 16]     = h0;
            *(half8*)&Ah[lp * 136 + pyl * 16 + 8] = h1;
        }
        {
            const uint4* src = (const uint4*)(wph + (size_t)kc * 12288);
            for (int i = t; i < 1536; i += 256) {
                int e = i >> 4, s = i & 15;
                *(uint4*)&Wh[e * 136 + s * 8] = src[i];
            }
        }
        __syncthreads();
        half8 af[4];
        #pragma unroll
        for (int ks = 0; ks < 4; ++ks)
            af[ks] = *(const half8*)&Ah[(rt * 16 + lm) * 136 + ks * 32 + quad * 8];
        #pragma unroll
        for (int ks = 0; ks < 4; ++ks) {
            #pragma unroll
            for (int nt = 0; nt < 3; ++nt) {
                half8 bf = *(const half8*)&Wh[((nh * 3 + nt) * 16 + lm) * 136 + ks * 32 + quad * 8];
                acc[nt] = __builtin_amdgcn_mfma_f32_16x16x32_f16(af[ks], bf, acc[nt], 0, 0, 0);
            }
        }
    }

    #pragma unroll
    for (int nt = 0; nt < 3; ++nt) {
        #pragma unroll
        for (int r = 0; r < 4; ++r) {
            int e = (nh * 3 + nt) * 16 + lm;
            int lp = rt * 16 + quad * 4 + r;
            int patch = p0 + lp;
            int n = patch % NPATCH;
            int ny = n / 14, nx = n % 14;
            float yx = (float)(ny + nx);
            float v = acc[nt][r] + bp[e];
            float other = __shfl_xor(v, 1);
            float fi = (float)(e >> 1);
            float theta = expf(fi * (-2.f / 96.f) * 9.210340371976184f);
            float ang = theta * yx;
            float c = cosf(ang), s = sinf(ang);
            float outv = (lm & 1) ? (other * s + v * c) : (v * c - other * s);
            out[(size_t)patch * 96 + e] = outv;
        }
    }
}

// ---------------------------------------------------------------------------
// row LayerNorm over 96, wave per row — writes f16.
// ---------------------------------------------------------------------------
__global__ void __launch_bounds__(256) k_ln_row(const float* __restrict__ x,
                                                const float* __restrict__ g,
                                                const float* __restrict__ bv,
                                                _Float16* __restrict__ out, int M)
{
    int lane = threadIdx.x & 63;
    int gw = (blockIdx.x * 256 + threadIdx.x) >> 6;
    int nw = (gridDim.x * 256) >> 6;
    float g0 = g[lane], b0 = bv[lane];
    float g1 = 0.f, b1 = 0.f;
    if (lane < 32) { g1 = g[64 + lane]; b1 = bv[64 + lane]; }
    for (int r = gw; r < M; r += nw) {
        const float* xr = x + (size_t)r * 96;
        float a = xr[lane];
        float c = (lane < 32) ? xr[64 + lane] : 0.f;
        float s = a + c, q = a * a + c * c;
        #pragma unroll
        for (int off = 32; off; off >>= 1) {
            s += __shfl_xor(s, off);
            q += __shfl_xor(q, off);
        }
        float mu = s * (1.f / 96.f);
        float rstd = rsqrtf(q * (1.f / 96.f) - mu * mu + 1e-5f);
        _Float16* orow = out + (size_t)r * 96;
        orow[lane] = (_Float16)((a - mu) * rstd * g0 + b0);
        if (lane < 32) orow[64 + lane] = (_Float16)((c - mu) * rstd * g1 + b1);
    }
}

// ---------------------------------------------------------------------------
// MFMA row GEMM (r16, verified). AHALF: A f16. OUTMODE: 0=fp32, 1=f16.
// Chunks over blockIdx.y.
// ---------------------------------------------------------------------------
template<int NCHUNKS, int OUTMODE, bool SILU, bool RES, bool ADDTIME, bool AHALF>
__global__ void __launch_bounds__(256) k_gemm_mfma(const void* __restrict__ A,
                                                   const _Float16* __restrict__ Wt,
                                                   const float* __restrict__ bias,
                                                   const float* __restrict__ res,
                                                   const float* __restrict__ timev,
                                                   void* __restrict__ outp)
{
    __shared__ __align__(16) _Float16 Ah[64 * 96];
    __shared__ __align__(16) _Float16 Wh[96 * 96];
    constexpr int NTOT = NCHUNKS * 96;
    int t = threadIdx.x;
    size_t row0 = (size_t)blockIdx.x * 64;

    if constexpr (AHALF) {
        const uint4* a4 = (const uint4*)((const _Float16*)A + row0 * 96);
        uint4* dst = (uint4*)Ah;
        for (int i = t; i < 768; i += 256) dst[i] = a4[i];
    } else {
        const float4* a4 = (const float4*)((const float*)A + row0 * 96);
        for (int i = t; i < 1536; i += 256) {
            float4 v = a4[i];
            half4v hv;
            hv[0] = (_Float16)v.x; hv[1] = (_Float16)v.y;
            hv[2] = (_Float16)v.z; hv[3] = (_Float16)v.w;
            *(half4v*)&Ah[i * 4] = hv;
        }
    }

    int wave = t >> 6, lane = t & 63;
    int lm = lane & 15, quad = lane >> 4;
    const f32x4 vzero = {0.f, 0.f, 0.f, 0.f};

    for (int ch = blockIdx.y; ch < NCHUNKS; ch += gridDim.y) {
        __syncthreads();
        {
            const uint4* src = (const uint4*)(Wt + (size_t)ch * 9216);
            uint4* dst = (uint4*)Wh;
            for (int i = t; i < 1152; i += 256) dst[i] = src[i];
        }
        __syncthreads();

        half8 af[3];
        #pragma unroll
        for (int ks = 0; ks < 3; ++ks)
            af[ks] = *(const half8*)&Ah[(wave * 16 + lm) * 96 + ks * 32 + quad * 8];

        f32x4 acc[6];
        #pragma unroll
        for (int ct = 0; ct < 6; ++ct) acc[ct] = vzero;

        #pragma unroll
        for (int ct = 0; ct < 6; ++ct) {
            #pragma unroll
            for (int ks = 0; ks < 3; ++ks) {
                half8 bf = *(const half8*)&Wh[(ct * 16 + lm) * 96 + ks * 32 + quad * 8];
                acc[ct] = __builtin_amdgcn_mfma_f32_16x16x32_f16(af[ks], bf, acc[ct], 0, 0, 0);
            }
        }

        #pragma unroll
        for (int ct = 0; ct < 6; ++ct) {
            #pragma unroll
            for (int r = 0; r < 4; ++r) {
                int lr = wave * 16 + quad * 4 + r;
                size_t row = row0 + lr;
                int lc = ct * 16 + lm;
                int col = ch * 96 + lc;
                float v = acc[ct][r] + bias[col];
                if constexpr (RES)     v += res[row * 96 + lc];
                if constexpr (ADDTIME) v += timev[lc];
                if constexpr (SILU)    v = v / (1.f + __expf(-v));
                if constexpr (OUTMODE == 0) {
                    ((float*)outp)[row * NTOT + col] = v;
                } else {
                    ((_Float16*)outp)[row * NTOT + col] = (_Float16)v;
                }
            }
        }
    }
}

// ---------------------------------------------------------------------------
// fused MLP (f16 input): 3 chained 96x96 GEMMs + silu, one kernel.
// ---------------------------------------------------------------------------
__global__ void __launch_bounds__(256) k_mlp_fused(const _Float16* __restrict__ A,
                                                   const _Float16* __restrict__ W,
                                                   const float* __restrict__ b0,
                                                   const float* __restrict__ b1,
                                                   const float* __restrict__ b2,
                                                   _Float16* __restrict__ outh)
{
    __shared__ __align__(16) _Float16 Ah[2][64 * 96];
    __shared__ __align__(16) _Float16 Wh[3][96 * 96];
    int t = threadIdx.x;
    size_t row0 = (size_t)blockIdx.x * 64;

    {
        const uint4* a4 = (const uint4*)(A + row0 * 96);
        uint4* dst = (uint4*)&Ah[0][0];
        for (int i = t; i < 768; i += 256) dst[i] = a4[i];
    }
    {
        const uint4* src = (const uint4*)W;
        uint4* dst = (uint4*)&Wh[0][0];
        for (int i = t; i < 3456; i += 256) dst[i] = src[i];
    }

    int wave = t >> 6, lane = t & 63;
    int lm = lane & 15, quad = lane >> 4;
    const float* biases[3] = { b0, b1, b2 };
    int cur = 0;

    #pragma unroll
    for (int s = 0; s < 3; ++s) {
        __syncthreads();
        half8 af[3];
        #pragma unroll
        for (int ks = 0; ks < 3; ++ks)
            af[ks] = *(const half8*)&Ah[cur][(wave * 16 + lm) * 96 + ks * 32 + quad * 8];

        f32x4 acc[6];
        #pragma unroll
        for (int ct = 0; ct < 6; ++ct) acc[ct] = (f32x4){0.f, 0.f, 0.f, 0.f};

        #pragma unroll
        for (int ct = 0; ct < 6; ++ct) {
            #pragma unroll
            for (int ks = 0; ks < 3; ++ks) {
                half8 bf = *(const half8*)&Wh[s][(ct * 16 + lm) * 96 + ks * 32 + quad * 8];
                acc[ct] = __builtin_amdgcn_mfma_f32_16x16x32_f16(af[ks], bf, acc[ct], 0, 0, 0);
            }
        }

        const float* bias = biases[s];
        if (s < 2) {
            #pragma unroll
            for (int ct = 0; ct < 6; ++ct) {
                #pragma unroll
                for (int r = 0; r < 4; ++r) {
                    int lr = wave * 16 + quad * 4 + r;
                    int lc = ct * 16 + lm;
                    float v = acc[ct][r] + bias[lc];
                    v = v / (1.f + __expf(-v));
                    Ah[cur ^ 1][lr * 96 + lc] = (_Float16)v;
                }
            }
            cur ^= 1;
        } else {
            #pragma unroll
            for (int ct = 0; ct < 6; ++ct) {
                #pragma unroll
                for (int r = 0; r < 4; ++r) {
                    int lr = wave * 16 + quad * 4 + r;
                    size_t row = row0 + lr;
                    int lc = ct * 16 + lm;
                    float v = acc[ct][r] + bias[lc];
                    v = v / (1.f + __expf(-v));
                    size_t b = row / NPATCH; int n = (int)(row % NPATCH);
                    int ny = n / 14, nx = n % 14;
                    outh[((b * 256) + (1 + ny) * 16 + (1 + nx)) * 96 + lc] = (_Float16)v;
                }
            }
        }
    }
}

// ---------------------------------------------------------------------------
// MFMA attention (r11 structure): qkv input f16, output f16.
// ---------------------------------------------------------------------------
__global__ void __launch_bounds__(256) k_attn_mfma(const _Float16* __restrict__ qkv,
                                                   _Float16* __restrict__ o)
{
    __shared__ __align__(16) _Float16 Qs[208 * 40];
    __shared__ __align__(16) _Float16 Ks[208 * 40];
    __shared__ __align__(16) _Float16 Vt[32 * 232];
    __shared__ __align__(16) _Float16 Pw[4][16 * 232];

    int t = threadIdx.x;
    int bh = blockIdx.x;
    int b = bh >> 2, h = bh & 3;
    const _Float16* base = qkv + (size_t)b * NPATCH * 288 + h * 24;

    {
        const int4 z = {0, 0, 0, 0};
        int4* q4 = (int4*)Qs; int4* k4 = (int4*)Ks;
        for (int i = t; i < 1040; i += 256) { q4[i] = z; k4[i] = z; }
        int4* v4 = (int4*)Vt;
        for (int i = t; i < 928; i += 256) v4[i] = z;
        int4* p4 = (int4*)&Pw[0][0];
        for (int i = t; i < 1856; i += 256) p4[i] = z;
    }
    __syncthreads();

    for (int i = t; i < NPATCH * 24; i += 256) {
        int r = i / 24, d = i % 24;
        const _Float16* row = base + (size_t)r * 288;
        Qs[r * 40 + d]   = row[d];
        Ks[r * 40 + d]   = row[96 + d];
        Vt[d * 232 + r]  = row[192 + d];
    }
    __syncthreads();

    int wave = t >> 6, lane = t & 63;
    int lm = lane & 15, quad = lane >> 4;
    const float scale = 0.2041241452319315f;

    half8 bk[13];
    #pragma unroll
    for (int ct = 0; ct < 13; ++ct)
        bk[ct] = *(const half8*)&Ks[(ct * 16 + lm) * 40 + quad * 8];

    _Float16* pw = &Pw[wave][0];

    for (int rt = wave; rt < 13; rt += 4) {
        half8 aq = *(const half8*)&Qs[(rt * 16 + lm) * 40 + quad * 8];
        float rsum[4] = {0.f, 0.f, 0.f, 0.f};

        #pragma unroll
        for (int ct = 0; ct < 13; ++ct) {
            f32x4 s = (f32x4){0.f, 0.f, 0.f, 0.f};
            s = __builtin_amdgcn_mfma_f32_16x16x32_f16(aq, bk[ct], s, 0, 0, 0);
            #pragma unroll
            for (int r = 0; r < 4; ++r) {
                float p = __expf(fminf(s[r] * scale, 60.f));
                if (ct == 12 && lm >= 4) p = 0.f;   // keys 196..207 invalid
                rsum[r] += p;
                pw[(quad * 4 + r) * 232 + ct * 16 + lm] = (_Float16)p;
            }
        }

        #pragma unroll
        for (int r = 0; r < 4; ++r) {
            float s = rsum[r];
            s += __shfl_xor(s, 1);
            s += __shfl_xor(s, 2);
            s += __shfl_xor(s, 4);
            s += __shfl_xor(s, 8);
            rsum[r] = 1.f / s;
        }

        f32x4 ov0 = (f32x4){0.f, 0.f, 0.f, 0.f};
        f32x4 ov1 = (f32x4){0.f, 0.f, 0.f, 0.f};
        #pragma unroll
        for (int ks = 0; ks < 7; ++ks) {
            half8 ap = *(const half8*)&pw[lm * 232 + ks * 32 + quad * 8];
            half8 bv0 = *(const half8*)&Vt[(lm) * 232 + ks * 32 + quad * 8];
            half8 bv1 = *(const half8*)&Vt[(16 + lm) * 232 + ks * 32 + quad * 8];
            ov0 = __builtin_amdgcn_mfma_f32_16x16x32_f16(ap, bv0, ov0, 0, 0, 0);
            ov1 = __builtin_amdgcn_mfma_f32_16x16x32_f16(ap, bv1, ov1, 0, 0, 0);
        }

        #pragma unroll
        for (int r = 0; r < 4; ++r) {
            int row = rt * 16 + quad * 4 + r;
            if (row < NPATCH) {
                _Float16* orow = o + ((size_t)b * NPATCH + row) * 96 + h * 24;
                orow[lm] = (_Float16)(ov0[r] * rsum[r]);
                if (lm < 8) orow[16 + lm] = (_Float16)(ov1[r] * rsum[r]);
            }
        }
    }
}

// ---------------------------------------------------------------------------
// conv L1, tile-resident + fused LN partial stats (r16, verified).
// ---------------------------------------------------------------------------
__global__ void __launch_bounds__(256) k_conv1_tile(const _Float16* __restrict__ xinh,
                                                    const _Float16* __restrict__ wc,
                                                    const float* __restrict__ bias,
                                                    _Float16* __restrict__ c1,
                                                    float* __restrict__ pstat1)
{
    __shared__ __align__(16) _Float16 Xs[4 * 16 * 104];   // 13.3 KB
    __shared__ float bins[96];
    int t = threadIdx.x;
    int blk = blockIdx.x;
    int b = blk / 7, s = blk % 7;

    if (t < 96) bins[t] = 0.f;

    for (int i = t; i < 768; i += 256) {
        int r = i / 192, rem = i % 192;
        int c = rem / 12, ch = (rem % 12) * 8;
        *(uint4*)&Xs[(r * 16 + c) * 104 + ch] =
            *(const uint4*)(xinh + ((size_t)(b * 256) + (2 * s + r) * 16 + c) * 96 + ch);
    }

    int wave = t >> 6, lane = t & 63;
    int lm = lane & 15, quad = lane >> 4;
    int ry = wave >> 1, rx = wave & 1;

    __syncthreads();

    for (int nt = 0; nt < 3; ++nt) {
        half8 bf[12];
        #pragma unroll
        for (int ks = 0; ks < 12; ++ks)
            bf[ks] = *(const half8*)&wc[((size_t)(wave * 48 + nt * 16 + lm)) * 384
                                        + ks * 32 + quad * 8];

        float sl = 0.f, ql = 0.f;
        #pragma unroll
        for (int rt = 0; rt < 2; ++rt) {
            int pp = rt * 16 + lm;
            int ppc = pp < 28 ? pp : 27;
            int pyl = ppc / 14, px = ppc % 14;

            half8 af[12];
            #pragma unroll
            for (int ks = 0; ks < 12; ++ks) {
                int k0 = ks * 32 + quad * 8;
                int tap = k0 / 96, off = k0 % 96;
                int dy = tap >> 1, dx = tap & 1;
                af[ks] = *(const half8*)&Xs[((pyl + ry + dy) * 16 + (px + rx + dx)) * 104 + off];
            }

            f32x4 acc = (f32x4){0.f, 0.f, 0.f, 0.f};
            #pragma unroll
            for (int ks = 0; ks < 12; ++ks)
                acc = __builtin_amdgcn_mfma_f32_16x16x32_f16(af[ks], bf[ks], acc, 0, 0, 0);

            #pragma unroll
            for (int r = 0; r < 4; ++r) {
                int pw = rt * 16 + quad * 4 + r;
                if (pw < 28) {
                    int pylw = pw / 14, pxw = pw % 14;
                    int oy = 2 * (2 * s + pylw) + ry, ox = 2 * pxw + rx;
                    float v = acc[r] + bias[nt * 16 + lm];
                    sl += v; ql += v * v;
                    c1[((size_t)(b * 28 + oy) * 28 + ox) * 48 + nt * 16 + lm] = (_Float16)v;
                }
            }
        }
        atomicAdd(&bins[(nt * 16 + lm) * 2],     sl);
        atomicAdd(&bins[(nt * 16 + lm) * 2 + 1], ql);
    }
    __syncthreads();
    if (t < 96) atomicAdd(&pstat1[(size_t)b * 96 + t], bins[t]);
}

// ---------------------------------------------------------------------------
// conv L2, tile-resident, LN1 fused into staging with per-block mu/rstd
// LDS table (r22, verified).
// ---------------------------------------------------------------------------
__global__ void __launch_bounds__(256) k_conv2_tile(const _Float16* __restrict__ c1,
                                                    const float* __restrict__ pstat1,
                                                    const float* __restrict__ g1,
                                                    const float* __restrict__ b1v,
                                                    const _Float16* __restrict__ wc,
                                                    const float* __restrict__ bias,
                                                    _Float16* __restrict__ c2,
                                                    float* __restrict__ pstat2)
{
    __shared__ __align__(16) _Float16 Xs[4 * 30 * 56];   // 13.1 KB
    __shared__ float bins[48];
    __shared__ float mr[96];                              // mu,rstd x48
    int t = threadIdx.x;
    int blk = blockIdx.x;
    int b = blk / 14, s = blk % 14;

    if (t < 48) {
        bins[t] = 0.f;
        float su = pstat1[(size_t)b * 96 + t * 2];
        float sq = pstat1[(size_t)b * 96 + t * 2 + 1];
        float mu = su * (1.f / 784.f);
        mr[t * 2]     = mu;
        mr[t * 2 + 1] = rsqrtf(sq * (1.f / 784.f) - mu * mu + 1e-5f);
    }
    __syncthreads();

    for (int i = t; i < 720; i += 256) {
        int r = i / 180, rem = i % 180;
        int c = rem / 6, ch0 = (rem % 6) * 8;
        int py = 2 * s + r, px = c;
        half8 hv;
        if (py >= 1 && py <= 28 && px >= 1 && px <= 28) {
            int j = (py - 1) * 28 + (px - 1);
            half8 v = *(const half8*)&c1[((size_t)b * 784 + j) * 48 + ch0];
            float gj = g1[j], bj = b1v[j];
            #pragma unroll
            for (int k = 0; k < 8; ++k) {
                float mu = mr[(ch0 + k) * 2];
                float rstd = mr[(ch0 + k) * 2 + 1];
                float u = ((float)v[k] - mu) * rstd * gj + bj;
                hv[k] = (_Float16)silu_fast(u);
            }
        } else {
            #pragma unroll
            for (int k = 0; k < 8; ++k) hv[k] = (_Float16)0.f;
        }
        *(half8*)&Xs[(r * 30 + c) * 56 + ch0] = hv;
    }

    int wave = t >> 6, lane = t & 63;
    int lm = lane & 15, quad = lane >> 4;
    int ry = wave >> 1, rx = wave & 1;

    half8 bf0[6], bf1[6];
    #pragma unroll
    for (int ks = 0; ks < 6; ++ks) {
        bf0[ks] = *(const half8*)&wc[((size_t)(wave * 32 + lm)) * 192 + ks * 32 + quad * 8];
        bf1[ks] = *(const half8*)&wc[((size_t)(wave * 32 + 16 + lm)) * 192 + ks * 32 + quad * 8];
    }

    __syncthreads();

    float s0l = 0.f, q0l = 0.f, s1l = 0.f, q1l = 0.f;
    #pragma unroll
    for (int rt = 0; rt < 4; ++rt) {
        int pp = rt * 16 + lm;
        int ppc = pp < 56 ? pp : 55;
        int pyl = ppc / 28, px = ppc % 28;

        half8 af[6];
        #pragma unroll
        for (int ks = 0; ks < 6; ++ks) {
            int k0 = ks * 32 + quad * 8;
            int tap = k0 / 48, off = k0 % 48;
            int dy = tap >> 1, dx = tap & 1;
            af[ks] = *(const half8*)&Xs[((pyl + ry + dy) * 30 + (px + rx + dx)) * 56 + off];
        }

        f32x4 acc0 = (f32x4){0.f, 0.f, 0.f, 0.f};
        f32x4 acc1 = (f32x4){0.f, 0.f, 0.f, 0.f};
        #pragma unroll
        for (int ks = 0; ks < 6; ++ks) {
            acc0 = __builtin_amdgcn_mfma_f32_16x16x32_f16(af[ks], bf0[ks], acc0, 0, 0, 0);
            acc1 = __builtin_amdgcn_mfma_f32_16x16x32_f16(af[ks], bf1[ks], acc1, 0, 0, 0);
        }

        #pragma unroll
        for (int r = 0; r < 4; ++r) {
            int pw = rt * 16 + quad * 4 + r;
            if (pw < 56) {
                int pylw = pw / 28, pxw = pw % 28;
                int oy = 2 * (2 * s + pylw) + ry, ox = 2 * pxw + rx;
                _Float16* orow = c2 + ((size_t)(b * 56 + oy) * 56 + ox) * 24;
                float v0 = acc0[r] + bias[lm];
                orow[lm] = (_Float16)v0;
                s0l += v0; q0l += v0 * v0;
                if (lm < 8) {
                    float v1 = acc1[r] + bias[16 + lm];
                    orow[16 + lm] = (_Float16)v1;
                    s1l += v1; q1l += v1 * v1;
                }
            }
        }
    }
    atomicAdd(&bins[lm * 2],     s0l);
    atomicAdd(&bins[lm * 2 + 1], q0l);
    if (lm < 8) {
        atomicAdd(&bins[(16 + lm) * 2],     s1l);
        atomicAdd(&bins[(16 + lm) * 2 + 1], q1l);
    }
    __syncthreads();
    if (t < 48) atomicAdd(&pstat2[(size_t)b * 48 + t], bins[t]);
}

// ---------------------------------------------------------------------------
// conv L3, tile-resident, LN2 fused into staging: 2 output strips/block
// (grid B*28), stage 4 rows, per-block mu/rstd LDS table (r22, verified).
// ---------------------------------------------------------------------------
__global__ void __launch_bounds__(256) k_conv3_tile(const _Float16* __restrict__ c2,
                                                    const float* __restrict__ pstat2,
                                                    const float* __restrict__ g2,
                                                    const float* __restrict__ b2v,
                                                    const _Float16* __restrict__ wc,
                                                    const float* __restrict__ bias,
                                                    _Float16* __restrict__ c3,
                                                    float* __restrict__ pstat3)
{
    __shared__ __align__(16) _Float16 Xs[4 * 58 * 40];   // 18.6 KB
    __shared__ float bins[24];
    __shared__ float mr[48];                              // mu,rstd x24
    int t = threadIdx.x;
    int blk = blockIdx.x;
    int b = blk / 28, s = blk % 28;   // conv-center rows 2s, 2s+1

    if (t < 24) {
        bins[t] = 0.f;
        float su = pstat2[(size_t)b * 48 + t * 2];
        float sq = pstat2[(size_t)b * 48 + t * 2 + 1];
        float mu = su * (1.f / 3136.f);
        mr[t * 2]     = mu;
        mr[t * 2 + 1] = rsqrtf(sq * (1.f / 3136.f) - mu * mu + 1e-5f);
    }
    __syncthreads();

    for (int i = t; i < 696; i += 256) {
        int r = i / 174, rem = i % 174;
        int c = rem / 3, ch0 = (rem % 3) * 8;
        int py = 2 * s + r, px = c;
        half8 hv;
        if (py >= 1 && py <= 56 && px >= 1 && px <= 56) {
            int j = (py - 1) * 56 + (px - 1);
            half8 v = *(const half8*)&c2[((size_t)b * 3136 + j) * 24 + ch0];
            float gj = g2[j], bj = b2v[j];
            #pragma unroll
            for (int k = 0; k < 8; ++k) {
                float mu = mr[(ch0 + k) * 2];
                float rstd = mr[(ch0 + k) * 2 + 1];
                float u = ((float)v[k] - mu) * rstd * gj + bj;
                hv[k] = (_Float16)silu_fast(u);
            }
        } else {
            #pragma unroll
            for (int k = 0; k < 8; ++k) hv[k] = (_Float16)0.f;
        }
        *(half8*)&Xs[(r * 58 + c) * 40 + ch0] = hv;
    }

    int wave = t >> 6, lane = t & 63;
    int lm = lane & 15, quad = lane >> 4;
    int ry = wave >> 1, rx = wave & 1;

    half8 bf[3];
    #pragma unroll
    for (int ks = 0; ks < 3; ++ks)
        bf[ks] = *(const half8*)&wc[((size_t)(wave * 16 + lm)) * 96 + ks * 32 + quad * 8];

    __syncthreads();

    float sl = 0.f, ql = 0.f;
    #pragma unroll
    for (int orow = 0; orow < 2; ++orow) {
        #pragma unroll
        for (int rt = 0; rt < 4; ++rt) {
            int px = rt * 16 + lm;
            int pxc = px < 56 ? px : 55;

            half8 af[3];
            #pragma unroll
            for (int ks = 0; ks < 3; ++ks) {
                int k0 = ks * 32 + quad * 8;
                int tap = k0 / 24, off = k0 % 24;
                int dy = tap >> 1, dx = tap & 1;
                af[ks] = *(const half8*)&Xs[((orow + ry + dy) * 58 + (pxc + rx + dx)) * 40 + off];
            }

            f32x4 acc = (f32x4){0.f, 0.f, 0.f, 0.f};
            #pragma unroll
            for (int ks = 0; ks < 3; ++ks)
                acc = __builtin_amdgcn_mfma_f32_16x16x32_f16(af[ks], bf[ks], acc, 0, 0, 0);

            if (lm < 12) {
                #pragma unroll
                for (int r = 0; r < 4; ++r) {
                    int pw = rt * 16 + quad * 4 + r;
                    if (pw < 56) {
                        int oy = 2 * (2 * s + orow) + ry, ox = 2 * pw + rx;
                        float v = acc[r] + bias[lm];
                        sl += v; ql += v * v;
                        c3[((size_t)(b * 112 + oy) * 112 + ox) * 12 + lm] = (_Float16)v;
                    }
                }
            }
        }
    }
    if (lm < 12) {
        atomicAdd(&bins[lm * 2],     sl);
        atomicAdd(&bins[lm * 2 + 1], ql);
    }
    __syncthreads();
    if (t < 24) atomicAdd(&pstat3[(size_t)b * 24 + t], bins[t]);
}

// ---------------------------------------------------------------------------
// final convT 12->1, LN3 fused: 4 output rows/block, stage 6 rows, fdot2.
// grid B*28 = 3584.
// ---------------------------------------------------------------------------
__global__ void __launch_bounds__(256) k_conv_final4(const _Float16* __restrict__ c3,
                                                     const float* __restrict__ pstat3,
                                                     const float* __restrict__ g3,
                                                     const float* __restrict__ b3v,
                                                     const _Float16* __restrict__ wcf,
                                                     const float* __restrict__ bias,
                                                     float* __restrict__ out)
{
    constexpr int HIN = 112, CIN = 12;
    __shared__ __align__(16) _Float16 Xs[6 * 114 * 12];   // 16.4 KB
    __shared__ __align__(16) _Float16 Wl[192];
    __shared__ float mr[24];                               // mu,rstd x12
    int t = threadIdx.x;
    int blk = blockIdx.x;
    int b = blk / 28, s = blk % 28;
    int py0 = 4 * s;                  // output pixel rows py0..py0+3

    {
        const int4 z = {0, 0, 0, 0};
        int4* p4 = (int4*)Xs;
        for (int i = t; i < 1026; i += 256) p4[i] = z;
        if (t < 24) *(int4*)&Wl[t * 8] = *(const int4*)&wcf[t * 8];
        if (t >= 32 && t < 44) {
            int ch = t - 32;
            float su = pstat3[(size_t)b * 24 + ch * 2];
            float sq = pstat3[(size_t)b * 24 + ch * 2 + 1];
            float mu = su * (1.f / 12544.f);
            mr[ch * 2]     = mu;
            mr[ch * 2 + 1] = rsqrtf(sq * (1.f / 12544.f) - mu * mu + 1e-5f);
        }
    }
    __syncthreads();
    // stage rows py0-1 .. py0+4 (6 rows), 2 pixels (24 halves) per item
    for (int i = t; i < 336; i += 256) {
        int r = i / 56, u = i % 56;
        int row = py0 - 1 + r;
        if (row >= 0 && row < HIN) {
            size_t base = ((size_t)b * 12544 + (size_t)row * 112 + 2 * u) * 12;
            half4v v0 = *(const half4v*)&c3[base];
            half4v v1 = *(const half4v*)&c3[base + 4];
            half4v v2 = *(const half4v*)&c3[base + 8];
            half4v v3 = *(const half4v*)&c3[base + 12];
            half4v v4 = *(const half4v*)&c3[base + 16];
            half4v v5 = *(const half4v*)&c3[base + 20];
            int j0 = row * 112 + 2 * u;
            float ga = g3[j0], ba = b3v[j0];
            float gb = g3[j0 + 1], bb2 = b3v[j0 + 1];
            _Float16 ov[24];
            #pragma unroll
            for (int k = 0; k < 24; ++k) {
                int ch = (k < 12) ? k : k - 12;
                float mu = mr[ch * 2];
                float rstd = mr[ch * 2 + 1];
                float vv;
                if      (k < 4)  vv = (float)v0[k];
                else if (k < 8)  vv = (float)v1[k - 4];
                else if (k < 12) vv = (float)v2[k - 8];
                else if (k < 16) vv = (float)v3[k - 12];
                else if (k < 20) vv = (float)v4[k - 16];
                else             vv = (float)v5[k - 20];
                float gk = (k < 12) ? ga : gb;
                float bk = (k < 12) ? ba : bb2;
                float u2 = (vv - mu) * rstd * gk + bk;
                ov[k] = (_Float16)silu_fast(u2);
            }
            _Float16* dst = &Xs[(size_t)r * 1368 + u * 24];
            *(half8*)&dst[0]  = *(half8*)&ov[0];
            *(half8*)&dst[8]  = *(half8*)&ov[8];
            *(half8*)&dst[16] = *(half8*)&ov[16];
        }
    }
    __syncthreads();

    if (t >= 224) return;
    int px = t % 112;
    float bb = bias[0];
    float* ob = out + (size_t)b * 50176;

    #pragma unroll
    for (int it = 0; it < 2; ++it) {
        int lr0 = it * 2 + (t / 112);    // local output row index 0..3
        int py = py0 + lr0;

        half2v tvp[9][6];
        #pragma unroll
        for (int a = 0; a < 3; ++a) {
            int lrow = lr0 + a;          // staged row (input row py-1+a)
            #pragma unroll
            for (int c = 0; c < 3; ++c) {
                int col = px - 1 + c;
                int cs = (col < 0) ? 113 : col;
                const _Float16* p = &Xs[((size_t)lrow * 114 + cs) * 12];
                half4v h0 = *(const half4v*)&p[0];
                half4v h1 = *(const half4v*)&p[4];
                half4v h2 = *(const half4v*)&p[8];
                int ti = a * 3 + c;
                tvp[ti][0] = (half2v){h0[0], h0[1]};
                tvp[ti][1] = (half2v){h0[2], h0[3]};
                tvp[ti][2] = (half2v){h1[0], h1[1]};
                tvp[ti][3] = (half2v){h1[2], h1[3]};
                tvp[ti][4] = (half2v){h2[0], h2[1]};
                tvp[ti][5] = (half2v){h2[2], h2[3]};
            }
        }

        #pragma unroll
        for (int ry = 0; ry < 2; ++ry) {
            float res[2];
            #pragma unroll
            for (int rx = 0; rx < 2; ++rx) {
                int p = ry * 2 + rx;
                float acc = 0.f;
                #pragma unroll
                for (int dy = 0; dy < 2; ++dy) {
                    #pragma unroll
                    for (int dx = 0; dx < 2; ++dx) {
                        int j = dy * 2 + dx;
                        int ti = (ry + dy) * 3 + (rx + dx);
                        const half2v* wp = (const half2v*)&Wl[(p * 4 + j) * 12];
                        #pragma unroll
                        for (int k = 0; k < 6; ++k)
                            acc = __builtin_amdgcn_fdot2(tvp[ti][k], wp[k], acc, false);
                    }
                }
                float u = silu_fast(acc + bb);
                res[rx] = fminf(fmaxf(u, 0.f), 1.f);
            }
            float2 v; v.x = res[0]; v.y = res[1];
            *(float2*)(ob + (size_t)(2 * py + ry) * 224 + 2 * px) = v;
        }
    }
}

// ---------------------------------------------------------------------------
// launch
// ---------------------------------------------------------------------------
extern "C" void kernel_launch(void* const* d_in, const int* in_sizes, int n_in,
                              void* d_out, int out_size, void* d_ws, size_t ws_size,
                              hipStream_t stream)
{
    const float* x       = (const float*)d_in[0];
    const float* ts      = (const float*)d_in[1];
    const float* Wp      = (const float*)d_in[2];
    const float* bp      = (const float*)d_in[3];
    const float* Wt1     = (const float*)d_in[4];
    const float* bt1     = (const float*)d_in[5];
    const float* Wt2     = (const float*)d_in[6];
    const float* bt2     = (const float*)d_in[7];
    const float* a0_g    = (const float*)d_in[8];
    const float* a0_b    = (const float*)d_in[9];
    const float* a0_Wqkv = (const float*)d_in[10];
    const float* a0_bqkv = (const float*)d_in[11];
    const float* a0_Wo   = (const float*)d_in[12];
    const float* a0_bo   = (const float*)d_in[13];
    const float* a1_g    = (const float*)d_in[14];
    const float* a1_b    = (const float*)d_in[15];
    const float* a1_Wqkv = (const float*)d_in[16];
    const float* a1_bqkv = (const float*)d_in[17];
    const float* a1_Wo   = (const float*)d_in[18];
    const float* a1_bo   = (const float*)d_in[19];
    const float* Wm0     = (const float*)d_in[20];
    const float* bm0     = (const float*)d_in[21];
    const float* Wm1     = (const float*)d_in[22];
    const float* bm1     = (const float*)d_in[23];
    const float* Wm2     = (const float*)d_in[24];
    const float* bm2     = (const float*)d_in[25];
    const float* Wd1     = (const float*)d_in[26];
    const float* bd1     = (const float*)d_in[27];
    const float* l1g     = (const float*)d_in[28];
    const float* l1b     = (const float*)d_in[29];
    const float* Wd2     = (const float*)d_in[30];
    const float* bd2     = (const float*)d_in[31];
    const float* l2g     = (const float*)d_in[32];
    const float* l2b     = (const float*)d_in[33];
    const float* Wd3     = (const float*)d_in[34];
    const float* bd3     = (const float*)d_in[35];
    const float* l3g     = (const float*)d_in[36];
    const float* l3b     = (const float*)d_in[37];
    const float* Wd4     = (const float*)d_in[38];
    const float* bd4     = (const float*)d_in[39];
    float* out = (float*)d_out;

    // arena (floats); R = 25088*96
    const size_t R = 2408448;
    float* ws   = (float*)d_ws;
    float* tvec = ws;                          // 96
    float* p0   = ws + 512;                    // R (fp32 residual; f16 alias p0h)
    _Float16* p0h  = (_Float16*)(ws + 512);           // f16 wo1 out (p0 region)
    _Float16* hh   = (_Float16*)(ws + 512 + R);       // f16 LN out (h region)
    _Float16* qkvh = (_Float16*)(ws + 512 + 2 * R);   // f16 qkv [M][288]
    _Float16* obh  = (_Float16*)(ws + 512 + 5 * R);   // f16 attn out (ob region)
    float* p1   = ws + 512 + 6 * R;            // R
    // decoder aliases:
    _Float16* xinh = (_Float16*)(ws + 512 + 2 * R);   // f16 NHWC (qkv region)
    _Float16* C1h  = (_Float16*)(ws + 512 + 5 * R);   // f16 NHWC [b][28][28][48]
    _Float16* C2h  = (_Float16*)(ws + 512);           // f16 NHWC [b][56][56][24]
    _Float16* C3h  = (_Float16*)(ws + 512 + 7 * R + 5529600); // f16 NHWC [b][112][112][12]
    float* Wr   = ws + 512 + 7 * R + 5529600 + 10334208;  // 96,960 floats
    _Float16* WH = (_Float16*)(Wr + 96960);                // 101,376 halves
    _Float16* Wc  = (_Float16*)Wr;
    _Float16* Wc2 = (_Float16*)(Wr + 36864);
    _Float16* Wc3 = (_Float16*)(Wr + 49152);
    float* stat = Wr + 96960 + 50688;          // 21,504 floats (raw LN sums)
    float* stat1 = stat;                       // 128*96
    float* stat2 = stat + 12288;               // 128*48
    float* stat3 = stat + 18432;               // 128*24
    _Float16* Wcf = (_Float16*)(stat + 21504); // 192 halves (conv_final f16 w)
    _Float16* Wph = (_Float16*)(stat + 21504 + 128); // 24576 halves (patch f16 w)
    const size_t NEED = (512 + 7 * R + 5529600 + 10334208 + 96960 + 50688 + 21504
                         + 128 + 12288 + 16) * sizeof(float);
    if (ws_size < NEED) return;

    _Float16* WHqkv0 = WH;
    _Float16* WHqkv1 = WH + 27648;
    _Float16* WHwo0  = WH + 55296;
    _Float16* WHwo1  = WH + 64512;
    _Float16* WHwm0  = WH + 73728;   // wm0,wm1,wm2 consecutive

    k_time<<<1, 128, 0, stream>>>(ts, Wt1, bt1, Wt2, bt2, tvec);
    k_zstat<<<84, 256, 0, stream>>>(stat);
    k_repack<<<379, 256, 0, stream>>>(Wd1, Wd2, Wd3, Wd4, Wr);
    k_wcvt4<<<1, 192, 0, stream>>>(Wr + 96768, Wcf);
    k_wcvtp<<<96, 256, 0, stream>>>(Wp, Wph);
    k_wcvtc<<<288, 256, 0, stream>>>(Wd1, Wc);
    k_wcvt2<<<96, 256, 0, stream>>>(Wd2, Wc2);
    k_wcvt3<<<24, 256, 0, stream>>>(Wd3, Wc3);
    k_wcvt<<<396, 256, 0, stream>>>(a0_Wqkv, a1_Wqkv, a0_Wo, a1_Wo,
                                    Wm0, Wm1, Wm2, WH);
    k_patch_mfma<<<M_ROWS / 32, 256, 0, stream>>>(x, Wph, bp, p0);

    // MHSA block 0
    k_ln_row<<<1024, 256, 0, stream>>>(p0, a0_g, a0_b, hh, M_ROWS);
    k_gemm_mfma<3, 1, false, false, false, true><<<dim3(M_ROWS / 64, 3), 256, 0, stream>>>(
        hh, WHqkv0, a0_bqkv, nullptr, nullptr, qkvh);
    k_attn_mfma<<<B_ * 4, 256, 0, stream>>>(qkvh, obh);
    k_gemm_mfma<1, 0, false, true, false, true><<<dim3(M_ROWS / 64, 1), 256, 0, stream>>>(
        obh, WHwo0, a0_bo, p0, nullptr, p1);

    // MHSA block 1 (+time)
    k_ln_row<<<1024, 256, 0, stream>>>(p1, a1_g, a1_b, hh, M_ROWS);
    k_gemm_mfma<3, 1, false, false, false, true><<<dim3(M_ROWS / 64, 3), 256, 0, stream>>>(
        hh, WHqkv1, a1_bqkv, nullptr, nullptr, qkvh);
    k_attn_mfma<<<B_ * 4, 256, 0, stream>>>(qkvh, obh);
    // wo1 + residual + time -> f16 p0h (only consumer: MLP)
    k_gemm_mfma<1, 1, false, true, true, true><<<dim3(M_ROWS / 64, 1), 256, 0, stream>>>(
        obh, WHwo1, a1_bo, p1, tvec, p0h);

    // qkv region free: zero xinh borders before MLP writes interior
    k_zb_h<<<2880, 256, 0, stream>>>(xinh);

    // fused MLP x3 (silu); writes f16 NHWC padded xinh
    k_mlp_fused<<<M_ROWS / 64, 256, 0, stream>>>(p0h, WHwm0, bm0, bm1, bm2, xinh);

    // decoder: conv chain with fused LN stats (producer) + LN apply (consumer)
    k_conv1_tile<<<B_ * 7, 256, 0, stream>>>(xinh, Wc, bd1, C1h, stat1);
    k_conv2_tile<<<B_ * 14, 256, 0, stream>>>(C1h, stat1, l1g, l1b, Wc2, bd2, C2h, stat2);
    k_conv3_tile<<<B_ * 28, 256, 0, stream>>>(C2h, stat2, l2g, l2b, Wc3, bd3, C3h, stat3);
    k_conv_final4<<<B_ * 28, 256, 0, stream>>>(C3h, stat3, l3g, l3b, Wcf, bd4, out);
}

// Round 16
// 392.621 us; speedup vs baseline: 1.2306x; 1.0211x over previous
//
#include <hip/hip_runtime.h>
#include <cmath>

// ---------------------------------------------------------------------------
// TimestepVisionTransformer — Round 24: launch-count diet.
//   - ONE k_prep kernel replaces k_time/k_zstat/k_repack/k_wcvt4/k_wcvtp/
//     k_wcvtc/k_wcvt2/k_wcvt3/k_wcvt (9 -> 1): L4 repack math inlined into
//     the f16 conv_final weight build, making all sections independent;
//     k_repack's dead fp32 stores deleted.
//   - k_zb_h folded into k_mlp_fused prologue (disjoint border writes).
// Everything else = r23 (verified, 400.9us best).
// B=128, IMG=224, P=16, C_IN=1, E=96, H=4, d=24, NAX=14, N=196, M=B*N=25088
// ---------------------------------------------------------------------------

#define B_   128
#define NPATCH 196
#define M_ROWS (B_*NPATCH)     // 25088
#define E_   96

typedef _Float16 half8 __attribute__((ext_vector_type(8)));
typedef _Float16 half4v __attribute__((ext_vector_type(4)));
typedef _Float16 half2v __attribute__((ext_vector_type(2)));
typedef float f32x4 __attribute__((ext_vector_type(4)));

__device__ __forceinline__ float silu_fast(float u)
{
    return u * __builtin_amdgcn_rcpf(1.f + __expf(-u));
}

// ---------------------------------------------------------------------------
// unified prep: stat-zero + all weight converts + time embedding.
// grid 986 x 256; block 985 = time embedding; blocks 0..984 = item ranges:
//   [0,21504)          stat zero
//   [21504,21696)      conv_final weights f16 (L4 repack inlined from Wd4)
//   [21696,46272)      patch weights f16
//   [46272,120000)     conv1 weights f16
//   [120000,144576)    conv2 weights f16
//   [144576,150720)    conv3 weights f16
//   [150720,252096)    transformer weights f16 (transpose)
// ---------------------------------------------------------------------------
__global__ void __launch_bounds__(256) k_prep(
    const float* __restrict__ ts,
    const float* __restrict__ Wt1, const float* __restrict__ bt1,
    const float* __restrict__ Wt2, const float* __restrict__ bt2,
    float* __restrict__ timev,
    float* __restrict__ stat,
    const float* __restrict__ w4,  _Float16* __restrict__ wcf,
    const float* __restrict__ Wp,  _Float16* __restrict__ wph,
    const float* __restrict__ w1,  _Float16* __restrict__ wc,
    const float* __restrict__ w2,  _Float16* __restrict__ wc2,
    const float* __restrict__ w3,  _Float16* __restrict__ wc3,
    const float* __restrict__ qkv0, const float* __restrict__ qkv1,
    const float* __restrict__ wo0,  const float* __restrict__ wo1,
    const float* __restrict__ wm0,  const float* __restrict__ wm1,
    const float* __restrict__ wm2,  _Float16* __restrict__ wh)
{
    __shared__ float h[128];
    int t = threadIdx.x;
    if (blockIdx.x == 985) {
        // time embedding
        if (t < 128) {
            float e = 0.69314718055994530942f * ts[0];
            float sv = sinf(e), cv = cosf(e);
            float z = sv * Wt1[t] + cv * Wt1[128 + t] + bt1[t];
            h[t] = z / (1.f + expf(-z));
        }
        __syncthreads();
        if (t < 96) {
            float acc = bt2[t];
            for (int j = 0; j < 128; ++j) acc += h[j] * Wt2[j * 96 + t];
            timev[t] = acc;
        }
        return;
    }
    int i = blockIdx.x * 256 + t;
    if (i < 21504) { stat[i] = 0.f; return; }
    i -= 21504;
    if (i < 192) {          // conv_final f16 weights, L4 repack inlined
        int p = i / 48, rem = i % 48;
        int j = rem / 12, ci = rem % 12;
        int ry = p >> 1, rx = p & 1;
        int wy = (j < 2)  ? (3 - ry) : (1 - ry);
        int wx = (j & 1)  ? (1 - rx) : (3 - rx);
        wcf[(p * 4 + j) * 12 + ci] = (_Float16)w4[ci * 16 + wy * 4 + wx];
        return;
    }
    i -= 192;
    if (i < 24576) {        // patch weights f16: wph[kc][e][k]
        int kc = i / 12288, rem = i % 12288;
        int e = rem / 128, k = rem % 128;
        wph[i] = (_Float16)Wp[e * 256 + kc * 128 + k];
        return;
    }
    i -= 24576;
    if (i < 73728) {        // conv1 weights f16
        int p = i / 18432, rem = i % 18432;
        int o = rem / 384, k = rem % 384;
        int tap = k / 96, ci = k % 96;
        int ry = p >> 1, rx = p & 1;
        int wy = (tap < 2) ? (3 - ry) : (1 - ry);
        int wx = (tap & 1) ? (1 - rx) : (3 - rx);
        wc[i] = (_Float16)w1[(ci * 48 + o) * 16 + wy * 4 + wx];
        return;
    }
    i -= 73728;
    if (i < 24576) {        // conv2 weights f16
        int p = i / 6144, rem = i % 6144;
        int o = rem / 192, k = rem % 192;
        int tap = k / 48, ci = k % 48;
        int ry = p >> 1, rx = p & 1;
        int wy = (tap < 2) ? (3 - ry) : (1 - ry);
        int wx = (tap & 1) ? (1 - rx) : (3 - rx);
        wc2[i] = (o < 24) ? (_Float16)w2[(ci * 24 + o) * 16 + wy * 4 + wx]
                          : (_Float16)0.f;
        return;
    }
    i -= 24576;
    if (i < 6144) {         // conv3 weights f16
        int p = i / 1536, rem = i % 1536;
        int o = rem / 96, k = rem % 96;
        int tap = k / 24, ci = k % 24;
        int ry = p >> 1, rx = p & 1;
        int wy = (tap < 2) ? (3 - ry) : (1 - ry);
        int wx = (tap & 1) ? (1 - rx) : (3 - rx);
        wc3[i] = (o < 12) ? (_Float16)w3[(ci * 12 + o) * 16 + wy * 4 + wx]
                          : (_Float16)0.f;
        return;
    }
    i -= 6144;
    if (i < 101376) {       // transformer weights f16 transpose
        const float* src; int N; int e;
        if      (i < 27648)  { src = qkv0; N = 288; e = i; }
        else if (i < 55296)  { src = qkv1; N = 288; e = i - 27648; }
        else if (i < 64512)  { src = wo0;  N = 96;  e = i - 55296; }
        else if (i < 73728)  { src = wo1;  N = 96;  e = i - 64512; }
        else if (i < 82944)  { src = wm0;  N = 96;  e = i - 73728; }
        else if (i < 92160)  { src = wm1;  N = 96;  e = i - 82944; }
        else                 { src = wm2;  N = 96;  e = i - 92160; }
        int n = e / 96, k = e % 96;
        wh[i] = (_Float16)src[k * N + n];
    }
}

// ---------------------------------------------------------------------------
// patch embed GEMM, occupancy-fixed (r20, verified): 32 patches/block.
// ---------------------------------------------------------------------------
__global__ void __launch_bounds__(256) k_patch_mfma(const float* __restrict__ x,
                                                    const _Float16* __restrict__ wph,
                                                    const float* __restrict__ bp,
                                                    float* __restrict__ out)
{
    __shared__ __align__(16) _Float16 Ah[32 * 136];
    __shared__ __align__(16) _Float16 Wh[96 * 136];
    int t = threadIdx.x;
    int p0 = blockIdx.x * 32;
    int wave = t >> 6, lane = t & 63;
    int lm = lane & 15, quad = lane >> 4;
    int rt = wave >> 1, nh = wave & 1;
    f32x4 acc[3];
    #pragma unroll
    for (int nt = 0; nt < 3; ++nt) acc[nt] = (f32x4){0.f, 0.f, 0.f, 0.f};

    for (int kc = 0; kc < 2; ++kc) {
        __syncthreads();
        {
            int lp = t >> 3, pyl = t & 7;
            int patch = p0 + lp;
            int b = patch / NPATCH, n = patch % NPATCH;
            int ny = n / 14, nx = n % 14;
            const float4* s4 = (const float4*)(x +
                ((size_t)(b * 224) + ny * 16 + kc * 8 + pyl) * 224 + nx * 16);
            float4 v0 = s4[0], v1 = s4[1], v2 = s4[2], v3 = s4[3];
            half8 h0, h1;
            h0[0]=(_Float16)v0.x; h0[1]=(_Float16)v0.y; h0[2]=(_Float16)v0.z; h0[3]=(_Float16)v0.w;
            h0[4]=(_Float16)v1.x; h0[5]=(_Float16)v1.y; h0[6]=(_Float16)v1.z; h0[7]=(_Float16)v1.w;
            h1[0]=(_Float16)v2.x; h1[1]=(_Float16)v2.y; h1[2]=(_Float16)v2.z; h1[3]=(_Float16)v2.w;
            h1[4]=(_Float16)v3.x; h1[5]=(_Float16)v3.y; h1[6]=(_Float16)v3.z; h1[7]=(_Float16)v3.w;
            *(half8*)&Ah[lp * 136 + pyl * 16]     = h0;
            *(half8*)&Ah[lp * 136 + pyl * 16 + 8] = h1;
        }
        {
            const uint4* src = (const uint4*)(wph + (size_t)kc * 12288);
            for (int i = t; i < 1536; i += 256) {
                int e = i >> 4, s = i & 15;
                *(uint4*)&Wh[e * 136 + s * 8] = src[i];
            }
        }
        __syncthreads();
        half8 af[4];
        #pragma unroll
        for (int ks = 0; ks < 4; ++ks)
            af[ks] = *(const half8*)&Ah[(rt * 16 + lm) * 136 + ks * 32 + quad * 8];
        #pragma unroll
        for (int ks = 0; ks < 4; ++ks) {
            #pragma unroll
            for (int nt = 0; nt < 3; ++nt) {
                half8 bf = *(const half8*)&Wh[((nh * 3 + nt) * 16 + lm) * 136 + ks * 32 + quad * 8];
                acc[nt] = __builtin_amdgcn_mfma_f32_16x16x32_f16(af[ks], bf, acc[nt], 0, 0, 0);
            }
        }
    }

    #pragma unroll
    for (int nt = 0; nt < 3; ++nt) {
        #pragma unroll
        for (int r = 0; r < 4; ++r) {
            int e = (nh * 3 + nt) * 16 + lm;
            int lp = rt * 16 + quad * 4 + r;
            int patch = p0 + lp;
            int n = patch % NPATCH;
            int ny = n / 14, nx = n % 14;
            float yx = (float)(ny + nx);
            float v = acc[nt][r] + bp[e];
            float other = __shfl_xor(v, 1);
            float fi = (float)(e >> 1);
            float theta = expf(fi * (-2.f / 96.f) * 9.210340371976184f);
            float ang = theta * yx;
            float c = cosf(ang), s = sinf(ang);
            float outv = (lm & 1) ? (other * s + v * c) : (v * c - other * s);
            out[(size_t)patch * 96 + e] = outv;
        }
    }
}

// ---------------------------------------------------------------------------
// row LayerNorm over 96, wave per row — writes f16.
// ---------------------------------------------------------------------------
__global__ void __launch_bounds__(256) k_ln_row(const float* __restrict__ x,
                                                const float* __restrict__ g,
                                                const float* __restrict__ bv,
                                                _Float16* __restrict__ out, int M)
{
    int lane = threadIdx.x & 63;
    int gw = (blockIdx.x * 256 + threadIdx.x) >> 6;
    int nw = (gridDim.x * 256) >> 6;
    float g0 = g[lane], b0 = bv[lane];
    float g1 = 0.f, b1 = 0.f;
    if (lane < 32) { g1 = g[64 + lane]; b1 = bv[64 + lane]; }
    for (int r = gw; r < M; r += nw) {
        const float* xr = x + (size_t)r * 96;
        float a = xr[lane];
        float c = (lane < 32) ? xr[64 + lane] : 0.f;
        float s = a + c, q = a * a + c * c;
        #pragma unroll
        for (int off = 32; off; off >>= 1) {
            s += __shfl_xor(s, off);
            q += __shfl_xor(q, off);
        }
        float mu = s * (1.f / 96.f);
        float rstd = rsqrtf(q * (1.f / 96.f) - mu * mu + 1e-5f);
        _Float16* orow = out + (size_t)r * 96;
        orow[lane] = (_Float16)((a - mu) * rstd * g0 + b0);
        if (lane < 32) orow[64 + lane] = (_Float16)((c - mu) * rstd * g1 + b1);
    }
}

// ---------------------------------------------------------------------------
// MFMA row GEMM (r16, verified). AHALF: A f16. OUTMODE: 0=fp32, 1=f16.
// Chunks over blockIdx.y.
// ---------------------------------------------------------------------------
template<int NCHUNKS, int OUTMODE, bool SILU, bool RES, bool ADDTIME, bool AHALF>
__global__ void __launch_bounds__(256) k_gemm_mfma(const void* __restrict__ A,
                                                   const _Float16* __restrict__ Wt,
                                                   const float* __restrict__ bias,
                                                   const float* __restrict__ res,
                                                   const float* __restrict__ timev,
                                                   void* __restrict__ outp)
{
    __shared__ __align__(16) _Float16 Ah[64 * 96];
    __shared__ __align__(16) _Float16 Wh[96 * 96];
    constexpr int NTOT = NCHUNKS * 96;
    int t = threadIdx.x;
    size_t row0 = (size_t)blockIdx.x * 64;

    if constexpr (AHALF) {
        const uint4* a4 = (const uint4*)((const _Float16*)A + row0 * 96);
        uint4* dst = (uint4*)Ah;
        for (int i = t; i < 768; i += 256) dst[i] = a4[i];
    } else {
        const float4* a4 = (const float4*)((const float*)A + row0 * 96);
        for (int i = t; i < 1536; i += 256) {
            float4 v = a4[i];
            half4v hv;
            hv[0] = (_Float16)v.x; hv[1] = (_Float16)v.y;
            hv[2] = (_Float16)v.z; hv[3] = (_Float16)v.w;
            *(half4v*)&Ah[i * 4] = hv;
        }
    }

    int wave = t >> 6, lane = t & 63;
    int lm = lane & 15, quad = lane >> 4;
    const f32x4 vzero = {0.f, 0.f, 0.f, 0.f};

    for (int ch = blockIdx.y; ch < NCHUNKS; ch += gridDim.y) {
        __syncthreads();
        {
            const uint4* src = (const uint4*)(Wt + (size_t)ch * 9216);
            uint4* dst = (uint4*)Wh;
            for (int i = t; i < 1152; i += 256) dst[i] = src[i];
        }
        __syncthreads();

        half8 af[3];
        #pragma unroll
        for (int ks = 0; ks < 3; ++ks)
            af[ks] = *(const half8*)&Ah[(wave * 16 + lm) * 96 + ks * 32 + quad * 8];

        f32x4 acc[6];
        #pragma unroll
        for (int ct = 0; ct < 6; ++ct) acc[ct] = vzero;

        #pragma unroll
        for (int ct = 0; ct < 6; ++ct) {
            #pragma unroll
            for (int ks = 0; ks < 3; ++ks) {
                half8 bf = *(const half8*)&Wh[(ct * 16 + lm) * 96 + ks * 32 + quad * 8];
                acc[ct] = __builtin_amdgcn_mfma_f32_16x16x32_f16(af[ks], bf, acc[ct], 0, 0, 0);
            }
        }

        #pragma unroll
        for (int ct = 0; ct < 6; ++ct) {
            #pragma unroll
            for (int r = 0; r < 4; ++r) {
                int lr = wave * 16 + quad * 4 + r;
                size_t row = row0 + lr;
                int lc = ct * 16 + lm;
                int col = ch * 96 + lc;
                float v = acc[ct][r] + bias[col];
                if constexpr (RES)     v += res[row * 96 + lc];
                if constexpr (ADDTIME) v += timev[lc];
                if constexpr (SILU)    v = v / (1.f + __expf(-v));
                if constexpr (OUTMODE == 0) {
                    ((float*)outp)[row * NTOT + col] = v;
                } else {
                    ((_Float16*)outp)[row * NTOT + col] = (_Float16)v;
                }
            }
        }
    }
}

// ---------------------------------------------------------------------------
// fused MLP (f16 input): 3 chained 96x96 GEMMs + silu, one kernel.
// Prologue zeroes the xinh borders (folded k_zb_h; disjoint addresses).
// ---------------------------------------------------------------------------
__global__ void __launch_bounds__(256) k_mlp_fused(const _Float16* __restrict__ A,
                                                   const _Float16* __restrict__ W,
                                                   const float* __restrict__ b0,
                                                   const float* __restrict__ b1,
                                                   const float* __restrict__ b2,
                                                   _Float16* __restrict__ outh)
{
    __shared__ __align__(16) _Float16 Ah[2][64 * 96];
    __shared__ __align__(16) _Float16 Wh[3][96 * 96];
    int t = threadIdx.x;
    size_t row0 = (size_t)blockIdx.x * 64;

    {
        // border zeroing: 92160 half8 items across 392 blocks
        int idx = blockIdx.x * 256 + t;
        if (idx < 92160) {
            int b = idx / 720, r = idx % 720;
            int pos = r / 12, chunk = r % 12;
            int py, px;
            if      (pos < 16) { py = 0;        px = pos; }
            else if (pos < 32) { py = 15;       px = pos - 16; }
            else if (pos < 46) { py = pos - 31; px = 0; }
            else               { py = pos - 45; px = 15; }
            half8 z = (half8){(_Float16)0.f, (_Float16)0.f, (_Float16)0.f, (_Float16)0.f,
                              (_Float16)0.f, (_Float16)0.f, (_Float16)0.f, (_Float16)0.f};
            *(half8*)&outh[(((size_t)b * 256) + py * 16 + px) * 96 + chunk * 8] = z;
        }
    }

    {
        const uint4* a4 = (const uint4*)(A + row0 * 96);
        uint4* dst = (uint4*)&Ah[0][0];
        for (int i = t; i < 768; i += 256) dst[i] = a4[i];
    }
    {
        const uint4* src = (const uint4*)W;
        uint4* dst = (uint4*)&Wh[0][0];
        for (int i = t; i < 3456; i += 256) dst[i] = src[i];
    }

    int wave = t >> 6, lane = t & 63;
    int lm = lane & 15, quad = lane >> 4;
    const float* biases[3] = { b0, b1, b2 };
    int cur = 0;

    #pragma unroll
    for (int s = 0; s < 3; ++s) {
        __syncthreads();
        half8 af[3];
        #pragma unroll
        for (int ks = 0; ks < 3; ++ks)
            af[ks] = *(const half8*)&Ah[cur][(wave * 16 + lm) * 96 + ks * 32 + quad * 8];

        f32x4 acc[6];
        #pragma unroll
        for (int ct = 0; ct < 6; ++ct) acc[ct] = (f32x4){0.f, 0.f, 0.f, 0.f};

        #pragma unroll
        for (int ct = 0; ct < 6; ++ct) {
            #pragma unroll
            for (int ks = 0; ks < 3; ++ks) {
                half8 bf = *(const half8*)&Wh[s][(ct * 16 + lm) * 96 + ks * 32 + quad * 8];
                acc[ct] = __builtin_amdgcn_mfma_f32_16x16x32_f16(af[ks], bf, acc[ct], 0, 0, 0);
            }
        }

        const float* bias = biases[s];
        if (s < 2) {
            #pragma unroll
            for (int ct = 0; ct < 6; ++ct) {
                #pragma unroll
                for (int r = 0; r < 4; ++r) {
                    int lr = wave * 16 + quad * 4 + r;
                    int lc = ct * 16 + lm;
                    float v = acc[ct][r] + bias[lc];
                    v = v / (1.f + __expf(-v));
                    Ah[cur ^ 1][lr * 96 + lc] = (_Float16)v;
                }
            }
            cur ^= 1;
        } else {
            #pragma unroll
            for (int ct = 0; ct < 6; ++ct) {
                #pragma unroll
                for (int r = 0; r < 4; ++r) {
                    int lr = wave * 16 + quad * 4 + r;
                    size_t row = row0 + lr;
                    int lc = ct * 16 + lm;
                    float v = acc[ct][r] + bias[lc];
                    v = v / (1.f + __expf(-v));
                    size_t b = row / NPATCH; int n = (int)(row % NPATCH);
                    int ny = n / 14, nx = n % 14;
                    outh[((b * 256) + (1 + ny) * 16 + (1 + nx)) * 96 + lc] = (_Float16)v;
                }
            }
        }
    }
}

// ---------------------------------------------------------------------------
// MFMA attention (r11 structure): qkv input f16, output f16.
// ---------------------------------------------------------------------------
__global__ void __launch_bounds__(256) k_attn_mfma(const _Float16* __restrict__ qkv,
                                                   _Float16* __restrict__ o)
{
    __shared__ __align__(16) _Float16 Qs[208 * 40];
    __shared__ __align__(16) _Float16 Ks[208 * 40];
    __shared__ __align__(16) _Float16 Vt[32 * 232];
    __shared__ __align__(16) _Float16 Pw[4][16 * 232];

    int t = threadIdx.x;
    int bh = blockIdx.x;
    int b = bh >> 2, h = bh & 3;
    const _Float16* base = qkv + (size_t)b * NPATCH * 288 + h * 24;

    {
        const int4 z = {0, 0, 0, 0};
        int4* q4 = (int4*)Qs; int4* k4 = (int4*)Ks;
        for (int i = t; i < 1040; i += 256) { q4[i] = z; k4[i] = z; }
        int4* v4 = (int4*)Vt;
        for (int i = t; i < 928; i += 256) v4[i] = z;
        int4* p4 = (int4*)&Pw[0][0];
        for (int i = t; i < 1856; i += 256) p4[i] = z;
    }
    __syncthreads();

    for (int i = t; i < NPATCH * 24; i += 256) {
        int r = i / 24, d = i % 24;
        const _Float16* row = base + (size_t)r * 288;
        Qs[r * 40 + d]   = row[d];
        Ks[r * 40 + d]   = row[96 + d];
        Vt[d * 232 + r]  = row[192 + d];
    }
    __syncthreads();

    int wave = t >> 6, lane = t & 63;
    int lm = lane & 15, quad = lane >> 4;
    const float scale = 0.2041241452319315f;

    half8 bk[13];
    #pragma unroll
    for (int ct = 0; ct < 13; ++ct)
        bk[ct] = *(const half8*)&Ks[(ct * 16 + lm) * 40 + quad * 8];

    _Float16* pw = &Pw[wave][0];

    for (int rt = wave; rt < 13; rt += 4) {
        half8 aq = *(const half8*)&Qs[(rt * 16 + lm) * 40 + quad * 8];
        float rsum[4] = {0.f, 0.f, 0.f, 0.f};

        #pragma unroll
        for (int ct = 0; ct < 13; ++ct) {
            f32x4 s = (f32x4){0.f, 0.f, 0.f, 0.f};
            s = __builtin_amdgcn_mfma_f32_16x16x32_f16(aq, bk[ct], s, 0, 0, 0);
            #pragma unroll
            for (int r = 0; r < 4; ++r) {
                float p = __expf(fminf(s[r] * scale, 60.f));
                if (ct == 12 && lm >= 4) p = 0.f;   // keys 196..207 invalid
                rsum[r] += p;
                pw[(quad * 4 + r) * 232 + ct * 16 + lm] = (_Float16)p;
            }
        }

        #pragma unroll
        for (int r = 0; r < 4; ++r) {
            float s = rsum[r];
            s += __shfl_xor(s, 1);
            s += __shfl_xor(s, 2);
            s += __shfl_xor(s, 4);
            s += __shfl_xor(s, 8);
            rsum[r] = 1.f / s;
        }

        f32x4 ov0 = (f32x4){0.f, 0.f, 0.f, 0.f};
        f32x4 ov1 = (f32x4){0.f, 0.f, 0.f, 0.f};
        #pragma unroll
        for (int ks = 0; ks < 7; ++ks) {
            half8 ap = *(const half8*)&pw[lm * 232 + ks * 32 + quad * 8];
            half8 bv0 = *(const half8*)&Vt[(lm) * 232 + ks * 32 + quad * 8];
            half8 bv1 = *(const half8*)&Vt[(16 + lm) * 232 + ks * 32 + quad * 8];
            ov0 = __builtin_amdgcn_mfma_f32_16x16x32_f16(ap, bv0, ov0, 0, 0, 0);
            ov1 = __builtin_amdgcn_mfma_f32_16x16x32_f16(ap, bv1, ov1, 0, 0, 0);
        }

        #pragma unroll
        for (int r = 0; r < 4; ++r) {
            int row = rt * 16 + quad * 4 + r;
            if (row < NPATCH) {
                _Float16* orow = o + ((size_t)b * NPATCH + row) * 96 + h * 24;
                orow[lm] = (_Float16)(ov0[r] * rsum[r]);
                if (lm < 8) orow[16 + lm] = (_Float16)(ov1[r] * rsum[r]);
            }
        }
    }
}

// ---------------------------------------------------------------------------
// conv L1, tile-resident + fused LN partial stats (r16, verified).
// ---------------------------------------------------------------------------
__global__ void __launch_bounds__(256) k_conv1_tile(const _Float16* __restrict__ xinh,
                                                    const _Float16* __restrict__ wc,
                                                    const float* __restrict__ bias,
                                                    _Float16* __restrict__ c1,
                                                    float* __restrict__ pstat1)
{
    __shared__ __align__(16) _Float16 Xs[4 * 16 * 104];   // 13.3 KB
    __shared__ float bins[96];
    int t = threadIdx.x;
    int blk = blockIdx.x;
    int b = blk / 7, s = blk % 7;

    if (t < 96) bins[t] = 0.f;

    for (int i = t; i < 768; i += 256) {
        int r = i / 192, rem = i % 192;
        int c = rem / 12, ch = (rem % 12) * 8;
        *(uint4*)&Xs[(r * 16 + c) * 104 + ch] =
            *(const uint4*)(xinh + ((size_t)(b * 256) + (2 * s + r) * 16 + c) * 96 + ch);
    }

    int wave = t >> 6, lane = t & 63;
    int lm = lane & 15, quad = lane >> 4;
    int ry = wave >> 1, rx = wave & 1;

    __syncthreads();

    for (int nt = 0; nt < 3; ++nt) {
        half8 bf[12];
        #pragma unroll
        for (int ks = 0; ks < 12; ++ks)
            bf[ks] = *(const half8*)&wc[((size_t)(wave * 48 + nt * 16 + lm)) * 384
                                        + ks * 32 + quad * 8];

        float sl = 0.f, ql = 0.f;
        #pragma unroll
        for (int rt = 0; rt < 2; ++rt) {
            int pp = rt * 16 + lm;
            int ppc = pp < 28 ? pp : 27;
            int pyl = ppc / 14, px = ppc % 14;

            half8 af[12];
            #pragma unroll
            for (int ks = 0; ks < 12; ++ks) {
                int k0 = ks * 32 + quad * 8;
                int tap = k0 / 96, off = k0 % 96;
                int dy = tap >> 1, dx = tap & 1;
                af[ks] = *(const half8*)&Xs[((pyl + ry + dy) * 16 + (px + rx + dx)) * 104 + off];
            }

            f32x4 acc = (f32x4){0.f, 0.f, 0.f, 0.f};
            #pragma unroll
            for (int ks = 0; ks < 12; ++ks)
                acc = __builtin_amdgcn_mfma_f32_16x16x32_f16(af[ks], bf[ks], acc, 0, 0, 0);

            #pragma unroll
            for (int r = 0; r < 4; ++r) {
                int pw = rt * 16 + quad * 4 + r;
                if (pw < 28) {
                    int pylw = pw / 14, pxw = pw % 14;
                    int oy = 2 * (2 * s + pylw) + ry, ox = 2 * pxw + rx;
                    float v = acc[r] + bias[nt * 16 + lm];
                    sl += v; ql += v * v;
                    c1[((size_t)(b * 28 + oy) * 28 + ox) * 48 + nt * 16 + lm] = (_Float16)v;
                }
            }
        }
        atomicAdd(&bins[(nt * 16 + lm) * 2],     sl);
        atomicAdd(&bins[(nt * 16 + lm) * 2 + 1], ql);
    }
    __syncthreads();
    if (t < 96) atomicAdd(&pstat1[(size_t)b * 96 + t], bins[t]);
}

// ---------------------------------------------------------------------------
// conv L2, tile-resident, LN1 fused into staging with per-block mu/rstd
// LDS table (r22, verified).
// ---------------------------------------------------------------------------
__global__ void __launch_bounds__(256) k_conv2_tile(const _Float16* __restrict__ c1,
                                                    const float* __restrict__ pstat1,
                                                    const float* __restrict__ g1,
                                                    const float* __restrict__ b1v,
                                                    const _Float16* __restrict__ wc,
                                                    const float* __restrict__ bias,
                                                    _Float16* __restrict__ c2,
                                                    float* __restrict__ pstat2)
{
    __shared__ __align__(16) _Float16 Xs[4 * 30 * 56];   // 13.1 KB
    __shared__ float bins[48];
    __shared__ float mr[96];                              // mu,rstd x48
    int t = threadIdx.x;
    int blk = blockIdx.x;
    int b = blk / 14, s = blk % 14;

    if (t < 48) {
        bins[t] = 0.f;
        float su = pstat1[(size_t)b * 96 + t * 2];
        float sq = pstat1[(size_t)b * 96 + t * 2 + 1];
        float mu = su * (1.f / 784.f);
        mr[t * 2]     = mu;
        mr[t * 2 + 1] = rsqrtf(sq * (1.f / 784.f) - mu * mu + 1e-5f);
    }
    __syncthreads();

    for (int i = t; i < 720; i += 256) {
        int r = i / 180, rem = i % 180;
        int c = rem / 6, ch0 = (rem % 6) * 8;
        int py = 2 * s + r, px = c;
        half8 hv;
        if (py >= 1 && py <= 28 && px >= 1 && px <= 28) {
            int j = (py - 1) * 28 + (px - 1);
            half8 v = *(const half8*)&c1[((size_t)b * 784 + j) * 48 + ch0];
            float gj = g1[j], bj = b1v[j];
            #pragma unroll
            for (int k = 0; k < 8; ++k) {
                float mu = mr[(ch0 + k) * 2];
                float rstd = mr[(ch0 + k) * 2 + 1];
                float u = ((float)v[k] - mu) * rstd * gj + bj;
                hv[k] = (_Float16)silu_fast(u);
            }
        } else {
            #pragma unroll
            for (int k = 0; k < 8; ++k) hv[k] = (_Float16)0.f;
        }
        *(half8*)&Xs[(r * 30 + c) * 56 + ch0] = hv;
    }

    int wave = t >> 6, lane = t & 63;
    int lm = lane & 15, quad = lane >> 4;
    int ry = wave >> 1, rx = wave & 1;

    half8 bf0[6], bf1[6];
    #pragma unroll
    for (int ks = 0; ks < 6; ++ks) {
        bf0[ks] = *(const half8*)&wc[((size_t)(wave * 32 + lm)) * 192 + ks * 32 + quad * 8];
        bf1[ks] = *(const half8*)&wc[((size_t)(wave * 32 + 16 + lm)) * 192 + ks * 32 + quad * 8];
    }

    __syncthreads();

    float s0l = 0.f, q0l = 0.f, s1l = 0.f, q1l = 0.f;
    #pragma unroll
    for (int rt = 0; rt < 4; ++rt) {
        int pp = rt * 16 + lm;
        int ppc = pp < 56 ? pp : 55;
        int pyl = ppc / 28, px = ppc % 28;

        half8 af[6];
        #pragma unroll
        for (int ks = 0; ks < 6; ++ks) {
            int k0 = ks * 32 + quad * 8;
            int tap = k0 / 48, off = k0 % 48;
            int dy = tap >> 1, dx = tap & 1;
            af[ks] = *(const half8*)&Xs[((pyl + ry + dy) * 30 + (px + rx + dx)) * 56 + off];
        }

        f32x4 acc0 = (f32x4){0.f, 0.f, 0.f, 0.f};
        f32x4 acc1 = (f32x4){0.f, 0.f, 0.f, 0.f};
        #pragma unroll
        for (int ks = 0; ks < 6; ++ks) {
            acc0 = __builtin_amdgcn_mfma_f32_16x16x32_f16(af[ks], bf0[ks], acc0, 0, 0, 0);
            acc1 = __builtin_amdgcn_mfma_f32_16x16x32_f16(af[ks], bf1[ks], acc1, 0, 0, 0);
        }

        #pragma unroll
        for (int r = 0; r < 4; ++r) {
            int pw = rt * 16 + quad * 4 + r;
            if (pw < 56) {
                int pylw = pw / 28, pxw = pw % 28;
                int oy = 2 * (2 * s + pylw) + ry, ox = 2 * pxw + rx;
                _Float16* orow = c2 + ((size_t)(b * 56 + oy) * 56 + ox) * 24;
                float v0 = acc0[r] + bias[lm];
                orow[lm] = (_Float16)v0;
                s0l += v0; q0l += v0 * v0;
                if (lm < 8) {
                    float v1 = acc1[r] + bias[16 + lm];
                    orow[16 + lm] = (_Float16)v1;
                    s1l += v1; q1l += v1 * v1;
                }
            }
        }
    }
    atomicAdd(&bins[lm * 2],     s0l);
    atomicAdd(&bins[lm * 2 + 1], q0l);
    if (lm < 8) {
        atomicAdd(&bins[(16 + lm) * 2],     s1l);
        atomicAdd(&bins[(16 + lm) * 2 + 1], q1l);
    }
    __syncthreads();
    if (t < 48) atomicAdd(&pstat2[(size_t)b * 48 + t], bins[t]);
}

// ---------------------------------------------------------------------------
// conv L3, tile-resident, LN2 fused into staging: 2 output strips/block
// (grid B*28), stage 4 rows, per-block mu/rstd LDS table (r22, verified).
// ---------------------------------------------------------------------------
__global__ void __launch_bounds__(256) k_conv3_tile(const _Float16* __restrict__ c2,
                                                    const float* __restrict__ pstat2,
                                                    const float* __restrict__ g2,
                                                    const float* __restrict__ b2v,
                                                    const _Float16* __restrict__ wc,
                                                    const float* __restrict__ bias,
                                                    _Float16* __restrict__ c3,
                                                    float* __restrict__ pstat3)
{
    __shared__ __align__(16) _Float16 Xs[4 * 58 * 40];   // 18.6 KB
    __shared__ float bins[24];
    __shared__ float mr[48];                              // mu,rstd x24
    int t = threadIdx.x;
    int blk = blockIdx.x;
    int b = blk / 28, s = blk % 28;   // conv-center rows 2s, 2s+1

    if (t < 24) {
        bins[t] = 0.f;
        float su = pstat2[(size_t)b * 48 + t * 2];
        float sq = pstat2[(size_t)b * 48 + t * 2 + 1];
        float mu = su * (1.f / 3136.f);
        mr[t * 2]     = mu;
        mr[t * 2 + 1] = rsqrtf(sq * (1.f / 3136.f) - mu * mu + 1e-5f);
    }
    __syncthreads();

    for (int i = t; i < 696; i += 256) {
        int r = i / 174, rem = i % 174;
        int c = rem / 3, ch0 = (rem % 3) * 8;
        int py = 2 * s + r, px = c;
        half8 hv;
        if (py >= 1 && py <= 56 && px >= 1 && px <= 56) {
            int j = (py - 1) * 56 + (px - 1);
            half8 v = *(const half8*)&c2[((size_t)b * 3136 + j) * 24 + ch0];
            float gj = g2[j], bj = b2v[j];
            #pragma unroll
            for (int k = 0; k < 8; ++k) {
                float mu = mr[(ch0 + k) * 2];
                float rstd = mr[(ch0 + k) * 2 + 1];
                float u = ((float)v[k] - mu) * rstd * gj + bj;
                hv[k] = (_Float16)silu_fast(u);
            }
        } else {
            #pragma unroll
            for (int k = 0; k < 8; ++k) hv[k] = (_Float16)0.f;
        }
        *(half8*)&Xs[(r * 58 + c) * 40 + ch0] = hv;
    }

    int wave = t >> 6, lane = t & 63;
    int lm = lane & 15, quad = lane >> 4;
    int ry = wave >> 1, rx = wave & 1;

    half8 bf[3];
    #pragma unroll
    for (int ks = 0; ks < 3; ++ks)
        bf[ks] = *(const half8*)&wc[((size_t)(wave * 16 + lm)) * 96 + ks * 32 + quad * 8];

    __syncthreads();

    float sl = 0.f, ql = 0.f;
    #pragma unroll
    for (int orow = 0; orow < 2; ++orow) {
        #pragma unroll
        for (int rt = 0; rt < 4; ++rt) {
            int px = rt * 16 + lm;
            int pxc = px < 56 ? px : 55;

            half8 af[3];
            #pragma unroll
            for (int ks = 0; ks < 3; ++ks) {
                int k0 = ks * 32 + quad * 8;
                int tap = k0 / 24, off = k0 % 24;
                int dy = tap >> 1, dx = tap & 1;
                af[ks] = *(const half8*)&Xs[((orow + ry + dy) * 58 + (pxc + rx + dx)) * 40 + off];
            }

            f32x4 acc = (f32x4){0.f, 0.f, 0.f, 0.f};
            #pragma unroll
            for (int ks = 0; ks < 3; ++ks)
                acc = __builtin_amdgcn_mfma_f32_16x16x32_f16(af[ks], bf[ks], acc, 0, 0, 0);

            if (lm < 12) {
                #pragma unroll
                for (int r = 0; r < 4; ++r) {
                    int pw = rt * 16 + quad * 4 + r;
                    if (pw < 56) {
                        int oy = 2 * (2 * s + orow) + ry, ox = 2 * pw + rx;
                        float v = acc[r] + bias[lm];
                        sl += v; ql += v * v;
                        c3[((size_t)(b * 112 + oy) * 112 + ox) * 12 + lm] = (_Float16)v;
                    }
                }
            }
        }
    }
    if (lm < 12) {
        atomicAdd(&bins[lm * 2],     sl);
        atomicAdd(&bins[lm * 2 + 1], ql);
    }
    __syncthreads();
    if (t < 24) atomicAdd(&pstat3[(size_t)b * 24 + t], bins[t]);
}

// ---------------------------------------------------------------------------
// final convT 12->1, LN3 fused: 4 output rows/block, stage 6 rows, fdot2.
// grid B*28 = 3584 (r23, verified).
// ---------------------------------------------------------------------------
__global__ void __launch_bounds__(256) k_conv_final4(const _Float16* __restrict__ c3,
                                                     const float* __restrict__ pstat3,
                                                     const float* __restrict__ g3,
                                                     const float* __restrict__ b3v,
                                                     const _Float16* __restrict__ wcf,
                                                     const float* __restrict__ bias,
                                                     float* __restrict__ out)
{
    constexpr int HIN = 112, CIN = 12;
    __shared__ __align__(16) _Float16 Xs[6 * 114 * 12];   // 16.4 KB
    __shared__ __align__(16) _Float16 Wl[192];
    __shared__ float mr[24];                               // mu,rstd x12
    int t = threadIdx.x;
    int blk = blockIdx.x;
    int b = blk / 28, s = blk % 28;
    int py0 = 4 * s;                  // output pixel rows py0..py0+3

    {
        const int4 z = {0, 0, 0, 0};
        int4* p4 = (int4*)Xs;
        for (int i = t; i < 1026; i += 256) p4[i] = z;
        if (t < 24) *(int4*)&Wl[t * 8] = *(const int4*)&wcf[t * 8];
        if (t >= 32 && t < 44) {
            int ch = t - 32;
            float su = pstat3[(size_t)b * 24 + ch * 2];
            float sq = pstat3[(size_t)b * 24 + ch * 2 + 1];
            float mu = su * (1.f / 12544.f);
            mr[ch * 2]     = mu;
            mr[ch * 2 + 1] = rsqrtf(sq * (1.f / 12544.f) - mu * mu + 1e-5f);
        }
    }
    __syncthreads();
    // stage rows py0-1 .. py0+4 (6 rows), 2 pixels (24 halves) per item
    for (int i = t; i < 336; i += 256) {
        int r = i / 56, u = i % 56;
        int row = py0 - 1 + r;
        if (row >= 0 && row < HIN) {
            size_t base = ((size_t)b * 12544 + (size_t)row * 112 + 2 * u) * 12;
            half4v v0 = *(const half4v*)&c3[base];
            half4v v1 = *(const half4v*)&c3[base + 4];
            half4v v2 = *(const half4v*)&c3[base + 8];
            half4v v3 = *(const half4v*)&c3[base + 12];
            half4v v4 = *(const half4v*)&c3[base + 16];
            half4v v5 = *(const half4v*)&c3[base + 20];
            int j0 = row * 112 + 2 * u;
            float ga = g3[j0], ba = b3v[j0];
            float gb = g3[j0 + 1], bb2 = b3v[j0 + 1];
            _Float16 ov[24];
            #pragma unroll
            for (int k = 0; k < 24; ++k) {
                int ch = (k < 12) ? k : k - 12;
                float mu = mr[ch * 2];
                float rstd = mr[ch * 2 + 1];
                float vv;
                if      (k < 4)  vv = (float)v0[k];
                else if (k < 8)  vv = (float)v1[k - 4];
                else if (k < 12) vv = (float)v2[k - 8];
                else if (k < 16) vv = (float)v3[k - 12];
                else if (k < 20) vv = (float)v4[k - 16];
                else             vv = (float)v5[k - 20];
                float gk = (k < 12) ? ga : gb;
                float bk = (k < 12) ? ba : bb2;
                float u2 = (vv - mu) * rstd * gk + bk;
                ov[k] = (_Float16)silu_fast(u2);
            }
            _Float16* dst = &Xs[(size_t)r * 1368 + u * 24];
            *(half8*)&dst[0]  = *(half8*)&ov[0];
            *(half8*)&dst[8]  = *(half8*)&ov[8];
            *(half8*)&dst[16] = *(half8*)&ov[16];
        }
    }
    __syncthreads();

    if (t >= 224) return;
    int px = t % 112;
    float bb = bias[0];
    float* ob = out + (size_t)b * 50176;

    #pragma unroll
    for (int it = 0; it < 2; ++it) {
        int lr0 = it * 2 + (t / 112);    // local output row index 0..3
        int py = py0 + lr0;

        half2v tvp[9][6];
        #pragma unroll
        for (int a = 0; a < 3; ++a) {
            int lrow = lr0 + a;          // staged row (input row py-1+a)
            #pragma unroll
            for (int c = 0; c < 3; ++c) {
                int col = px - 1 + c;
                int cs = (col < 0) ? 113 : col;
                const _Float16* p = &Xs[((size_t)lrow * 114 + cs) * 12];
                half4v h0 = *(const half4v*)&p[0];
                half4v h1 = *(const half4v*)&p[4];
                half4v h2 = *(const half4v*)&p[8];
                int ti = a * 3 + c;
                tvp[ti][0] = (half2v){h0[0], h0[1]};
                tvp[ti][1] = (half2v){h0[2], h0[3]};
                tvp[ti][2] = (half2v){h1[0], h1[1]};
                tvp[ti][3] = (half2v){h1[2], h1[3]};
                tvp[ti][4] = (half2v){h2[0], h2[1]};
                tvp[ti][5] = (half2v){h2[2], h2[3]};
            }
        }

        #pragma unroll
        for (int ry = 0; ry < 2; ++ry) {
            float res[2];
            #pragma unroll
            for (int rx = 0; rx < 2; ++rx) {
                int p = ry * 2 + rx;
                float acc = 0.f;
                #pragma unroll
                for (int dy = 0; dy < 2; ++dy) {
                    #pragma unroll
                    for (int dx = 0; dx < 2; ++dx) {
                        int j = dy * 2 + dx;
                        int ti = (ry + dy) * 3 + (rx + dx);
                        const half2v* wp = (const half2v*)&Wl[(p * 4 + j) * 12];
                        #pragma unroll
                        for (int k = 0; k < 6; ++k)
                            acc = __builtin_amdgcn_fdot2(tvp[ti][k], wp[k], acc, false);
                    }
                }
                float u = silu_fast(acc + bb);
                res[rx] = fminf(fmaxf(u, 0.f), 1.f);
            }
            float2 v; v.x = res[0]; v.y = res[1];
            *(float2*)(ob + (size_t)(2 * py + ry) * 224 + 2 * px) = v;
        }
    }
}

// ---------------------------------------------------------------------------
// launch
// ---------------------------------------------------------------------------
extern "C" void kernel_launch(void* const* d_in, const int* in_sizes, int n_in,
                              void* d_out, int out_size, void* d_ws, size_t ws_size,
                              hipStream_t stream)
{
    const float* x       = (const float*)d_in[0];
    const float* ts      = (const float*)d_in[1];
    const float* Wp      = (const float*)d_in[2];
    const float* bp      = (const float*)d_in[3];
    const float* Wt1     = (const float*)d_in[4];
    const float* bt1     = (const float*)d_in[5];
    const float* Wt2     = (const float*)d_in[6];
    const float* bt2     = (const float*)d_in[7];
    const float* a0_g    = (const float*)d_in[8];
    const float* a0_b    = (const float*)d_in[9];
    const float* a0_Wqkv = (const float*)d_in[10];
    const float* a0_bqkv = (const float*)d_in[11];
    const float* a0_Wo   = (const float*)d_in[12];
    const float* a0_bo   = (const float*)d_in[13];
    const float* a1_g    = (const float*)d_in[14];
    const float* a1_b    = (const float*)d_in[15];
    const float* a1_Wqkv = (const float*)d_in[16];
    const float* a1_bqkv = (const float*)d_in[17];
    const float* a1_Wo   = (const float*)d_in[18];
    const float* a1_bo   = (const float*)d_in[19];
    const float* Wm0     = (const float*)d_in[20];
    const float* bm0     = (const float*)d_in[21];
    const float* Wm1     = (const float*)d_in[22];
    const float* bm1     = (const float*)d_in[23];
    const float* Wm2     = (const float*)d_in[24];
    const float* bm2     = (const float*)d_in[25];
    const float* Wd1     = (const float*)d_in[26];
    const float* bd1     = (const float*)d_in[27];
    const float* l1g     = (const float*)d_in[28];
    const float* l1b     = (const float*)d_in[29];
    const float* Wd2     = (const float*)d_in[30];
    const float* bd2     = (const float*)d_in[31];
    const float* l2g     = (const float*)d_in[32];
    const float* l2b     = (const float*)d_in[33];
    const float* Wd3     = (const float*)d_in[34];
    const float* bd3     = (const float*)d_in[35];
    const float* l3g     = (const float*)d_in[36];
    const float* l3b     = (const float*)d_in[37];
    const float* Wd4     = (const float*)d_in[38];
    const float* bd4     = (const float*)d_in[39];
    float* out = (float*)d_out;

    // arena (floats); R = 25088*96
    const size_t R = 2408448;
    float* ws   = (float*)d_ws;
    float* tvec = ws;                          // 96
    float* p0   = ws + 512;                    // R (fp32 residual; f16 alias p0h)
    _Float16* p0h  = (_Float16*)(ws + 512);           // f16 wo1 out (p0 region)
    _Float16* hh   = (_Float16*)(ws + 512 + R);       // f16 LN out (h region)
    _Float16* qkvh = (_Float16*)(ws + 512 + 2 * R);   // f16 qkv [M][288]
    _Float16* obh  = (_Float16*)(ws + 512 + 5 * R);   // f16 attn out (ob region)
    float* p1   = ws + 512 + 6 * R;            // R
    // decoder aliases:
    _Float16* xinh = (_Float16*)(ws + 512 + 2 * R);   // f16 NHWC (qkv region)
    _Float16* C1h  = (_Float16*)(ws + 512 + 5 * R);   // f16 NHWC [b][28][28][48]
    _Float16* C2h  = (_Float16*)(ws + 512);           // f16 NHWC [b][56][56][24]
    _Float16* C3h  = (_Float16*)(ws + 512 + 7 * R + 5529600); // f16 NHWC [b][112][112][12]
    float* Wr   = ws + 512 + 7 * R + 5529600 + 10334208;  // 96,960 floats (dead fp32; anchors)
    _Float16* WH = (_Float16*)(Wr + 96960);                // 101,376 halves
    _Float16* Wc  = (_Float16*)Wr;
    _Float16* Wc2 = (_Float16*)(Wr + 36864);
    _Float16* Wc3 = (_Float16*)(Wr + 49152);
    float* stat = Wr + 96960 + 50688;          // 21,504 floats (raw LN sums)
    float* stat1 = stat;                       // 128*96
    float* stat2 = stat + 12288;               // 128*48
    float* stat3 = stat + 18432;               // 128*24
    _Float16* Wcf = (_Float16*)(stat + 21504); // 192 halves (conv_final f16 w)
    _Float16* Wph = (_Float16*)(stat + 21504 + 128); // 24576 halves (patch f16 w)
    const size_t NEED = (512 + 7 * R + 5529600 + 10334208 + 96960 + 50688 + 21504
                         + 128 + 12288 + 16) * sizeof(float);
    if (ws_size < NEED) return;

    _Float16* WHqkv0 = WH;
    _Float16* WHqkv1 = WH + 27648;
    _Float16* WHwo0  = WH + 55296;
    _Float16* WHwo1  = WH + 64512;
    _Float16* WHwm0  = WH + 73728;   // wm0,wm1,wm2 consecutive

    // unified prep: stats zero + all weight converts + time embedding
    k_prep<<<986, 256, 0, stream>>>(ts, Wt1, bt1, Wt2, bt2, tvec,
                                    stat, Wd4, Wcf, Wp, Wph,
                                    Wd1, Wc, Wd2, Wc2, Wd3, Wc3,
                                    a0_Wqkv, a1_Wqkv, a0_Wo, a1_Wo,
                                    Wm0, Wm1, Wm2, WH);
    k_patch_mfma<<<M_ROWS / 32, 256, 0, stream>>>(x, Wph, bp, p0);

    // MHSA block 0
    k_ln_row<<<1024, 256, 0, stream>>>(p0, a0_g, a0_b, hh, M_ROWS);
    k_gemm_mfma<3, 1, false, false, false, true><<<dim3(M_ROWS / 64, 3), 256, 0, stream>>>(
        hh, WHqkv0, a0_bqkv, nullptr, nullptr, qkvh);
    k_attn_mfma<<<B_ * 4, 256, 0, stream>>>(qkvh, obh);
    k_gemm_mfma<1, 0, false, true, false, true><<<dim3(M_ROWS / 64, 1), 256, 0, stream>>>(
        obh, WHwo0, a0_bo, p0, nullptr, p1);

    // MHSA block 1 (+time)
    k_ln_row<<<1024, 256, 0, stream>>>(p1, a1_g, a1_b, hh, M_ROWS);
    k_gemm_mfma<3, 1, false, false, false, true><<<dim3(M_ROWS / 64, 3), 256, 0, stream>>>(
        hh, WHqkv1, a1_bqkv, nullptr, nullptr, qkvh);
    k_attn_mfma<<<B_ * 4, 256, 0, stream>>>(qkvh, obh);
    // wo1 + residual + time -> f16 p0h (only consumer: MLP)
    k_gemm_mfma<1, 1, false, true, true, true><<<dim3(M_ROWS / 64, 1), 256, 0, stream>>>(
        obh, WHwo1, a1_bo, p1, tvec, p0h);

    // fused MLP x3 (silu); prologue zeroes xinh borders; writes f16 NHWC xinh
    k_mlp_fused<<<M_ROWS / 64, 256, 0, stream>>>(p0h, WHwm0, bm0, bm1, bm2, xinh);

    // decoder: conv chain with fused LN stats (producer) + LN apply (consumer)
    k_conv1_tile<<<B_ * 7, 256, 0, stream>>>(xinh, Wc, bd1, C1h, stat1);
    k_conv2_tile<<<B_ * 14, 256, 0, stream>>>(C1h, stat1, l1g, l1b, Wc2, bd2, C2h, stat2);
    k_conv3_tile<<<B_ * 28, 256, 0, stream>>>(C2h, stat2, l2g, l2b, Wc3, bd3, C3h, stat3);
    k_conv_final4<<<B_ * 28, 256, 0, stream>>>(C3h, stat3, l3g, l3b, Wcf, bd4, out);
}